// Round 1
// baseline (2246.558 us; speedup 1.0000x reference)
//
#include <hip/hip_runtime.h>

#define NB 16
#define QL 512
#define KL 1024
#define DM 384
#define NH 3
#define DK 128

// workspace offsets (in floats)
static const size_t OFF_WT2Q = 0;          // repacked w_qs [13][384][128]
static const size_t OFF_WT2K = 638976;
static const size_t OFF_WT2V = 1277952;
static const size_t OFF_QH   = 1916928;    // [B][512][384]
static const size_t OFF_KH   = 5062656;    // [B][1024][384]
static const size_t OFF_VH   = 11354112;   // [B][1024][384]
static const size_t OFF_E    = 17645568;   // [3][16][512][1024]  (alpha_cv in place)
static const size_t OFF_AME  = 17645568;   // alpha_me [B][1024][512] (aliases e, dead by then)
static const size_t OFF_AFT  = 42811392;   // alpha_fc^T [B][1024][512]
static const size_t OFF_CVP  = 51200000;   // cv_pre [B][512][384]
static const size_t OFF_PART = 54345728;   // partial colmax sums [48][4]
static const size_t OFF_HIDX = 54345920;   // h_idx [16] ints

// d_out offsets (floats)
static const size_t OUT_CV    = 0;          // [16][512][384]
static const size_t OUT_ALPHA = 3145728;    // [16][512][1024]
static const size_t OUT_FR    = 11534336;   // scalar

// ---------------- weight repack: w[oc][ic][t] -> wT[t][oc][ic] ----------------
__global__ __launch_bounds__(256) void repack_w(const float* __restrict__ src,
                                                float* __restrict__ dst) {
  int tid = blockIdx.x * 256 + threadIdx.x;
  if (tid >= 384 * 128 * 13) return;
  int ic = tid & 127;
  int oc = (tid >> 7) % 384;
  int t  = tid / (384 * 128);
  dst[tid] = src[(size_t)oc * (128 * 13) + ic * 13 + t];
}

// ---------------- grouped conv1d (KW=13, pad 6), 3 groups of 128 ----------------
// out[b,l,oc] = bias[oc] + sum_{ic,t} x[b, l+t-6, g*128+ic] * w[oc,ic,t]
// tile: 128 l x 128 oc per block; ic in quarters of 32; 8x8 micro-tile
__global__ __launch_bounds__(256) void conv_grouped(
    const float* __restrict__ x, const float* __restrict__ wT,
    const float* __restrict__ bias, float* __restrict__ out, int L)
{
  __shared__ __align__(16) float xs[140][36];
  __shared__ __align__(16) float wt[128][36];
  const int l0 = blockIdx.x * 128;
  const int z = blockIdx.z;
  const int b = z / NH, g = z % NH;
  const int tid = threadIdx.x;
  const int ti = tid & 15, tj = tid >> 4;
  const int icl = tid & 31, rr0 = tid >> 5;

  float acc[8][8];
  #pragma unroll
  for (int i = 0; i < 8; ++i)
    #pragma unroll
    for (int j = 0; j < 8; ++j) acc[i][j] = 0.f;

  const float* xb = x + (size_t)b * L * DM + g * DK;

  for (int h = 0; h < 4; ++h) {
    __syncthreads();
    for (int r = rr0; r < 140; r += 8) {
      int l = l0 - 6 + r;
      xs[r][icl] = (l >= 0 && l < L) ? xb[(size_t)l * DM + h * 32 + icl] : 0.f;
    }
    for (int t = 0; t < 13; ++t) {
      __syncthreads();
      {
        const float* wsrc = wT + ((size_t)t * 384 + g * DK) * 128 + h * 32 + icl;
        for (int r = rr0; r < 128; r += 8) wt[r][icl] = wsrc[(size_t)r * 128];
      }
      __syncthreads();
      for (int kk = 0; kk < 32; kk += 4) {
        float4 a[8], bv[8];
        #pragma unroll
        for (int i = 0; i < 8; ++i) a[i] = *(const float4*)&xs[t + ti + 16 * i][kk];
        #pragma unroll
        for (int j = 0; j < 8; ++j) {
          int oc = (j < 4) ? (4 * tj + j) : (64 + 4 * tj + (j - 4));
          bv[j] = *(const float4*)&wt[oc][kk];
        }
        #pragma unroll
        for (int i = 0; i < 8; ++i)
          #pragma unroll
          for (int j = 0; j < 8; ++j)
            acc[i][j] += a[i].x * bv[j].x + a[i].y * bv[j].y +
                         a[i].z * bv[j].z + a[i].w * bv[j].w;
      }
    }
  }

  const float4 bl = *(const float4*)&bias[g * DK + 4 * tj];
  const float4 bh = *(const float4*)&bias[g * DK + 64 + 4 * tj];
  float* ob = out + (size_t)b * L * DM + g * DK;
  #pragma unroll
  for (int i = 0; i < 8; ++i) {
    int l = l0 + ti + 16 * i;
    float4 lo = make_float4(acc[i][0] + bl.x, acc[i][1] + bl.y,
                            acc[i][2] + bl.z, acc[i][3] + bl.w);
    float4 hi = make_float4(acc[i][4] + bh.x, acc[i][5] + bh.y,
                            acc[i][6] + bh.z, acc[i][7] + bh.w);
    *(float4*)&ob[(size_t)l * DM + 4 * tj] = lo;
    *(float4*)&ob[(size_t)l * DM + 64 + 4 * tj] = hi;
  }
}

// ---------------- e[h,b,q,k] = qh[b,q,h,:] . kh[b,k,h,:] / sqrt(128) ----------------
__global__ __launch_bounds__(256) void gemm_qk(
    const float* __restrict__ qh, const float* __restrict__ kh, float* __restrict__ e)
{
  __shared__ __align__(16) float As[128][36];
  __shared__ __align__(16) float Bs[128][36];
  const int z = blockIdx.z, hh = z >> 4, b = z & 15;
  const float* Ab = qh + ((size_t)b * QL + blockIdx.x * 128) * DM + hh * DK;
  const float* Bb = kh + ((size_t)b * KL + blockIdx.y * 128) * DM + hh * DK;
  float* Cb = e + (size_t)z * QL * KL + (size_t)blockIdx.x * 128 * KL + blockIdx.y * 128;
  const int tid = threadIdx.x, ti = tid & 15, tj = tid >> 4;
  const int kks = tid & 31, m8 = tid >> 5;

  float acc[8][8];
  #pragma unroll
  for (int i = 0; i < 8; ++i)
    #pragma unroll
    for (int j = 0; j < 8; ++j) acc[i][j] = 0.f;

  for (int k0 = 0; k0 < DK; k0 += 32) {
    __syncthreads();
    for (int m = m8; m < 128; m += 8) {
      As[m][kks] = Ab[(size_t)m * DM + k0 + kks];
      Bs[m][kks] = Bb[(size_t)m * DM + k0 + kks];
    }
    __syncthreads();
    for (int kq = 0; kq < 32; kq += 4) {
      float4 a[8], bv[8];
      #pragma unroll
      for (int i = 0; i < 8; ++i) a[i] = *(const float4*)&As[ti + 16 * i][kq];
      #pragma unroll
      for (int j = 0; j < 8; ++j) {
        int n = (j < 4) ? (4 * tj + j) : (64 + 4 * tj + (j - 4));
        bv[j] = *(const float4*)&Bs[n][kq];
      }
      #pragma unroll
      for (int i = 0; i < 8; ++i)
        #pragma unroll
        for (int j = 0; j < 8; ++j)
          acc[i][j] += a[i].x * bv[j].x + a[i].y * bv[j].y +
                       a[i].z * bv[j].z + a[i].w * bv[j].w;
    }
  }
  const float sc = 0.08838834764831845f; // 1/sqrt(128)
  #pragma unroll
  for (int i = 0; i < 8; ++i) {
    int r = ti + 16 * i;
    float4 lo = make_float4(acc[i][0] * sc, acc[i][1] * sc, acc[i][2] * sc, acc[i][3] * sc);
    float4 hi = make_float4(acc[i][4] * sc, acc[i][5] * sc, acc[i][6] * sc, acc[i][7] * sc);
    *(float4*)&Cb[(size_t)r * KL + 4 * tj] = lo;
    *(float4*)&Cb[(size_t)r * KL + 64 + 4 * tj] = hi;
  }
}

// ---------------- row softmax over k (1024), in place ----------------
__global__ __launch_bounds__(256) void softmax_rows(float* __restrict__ e) {
  float* p = e + (size_t)blockIdx.x * KL;
  const int tid = threadIdx.x;
  float4 v = *(const float4*)&p[tid * 4];
  float m = fmaxf(fmaxf(v.x, v.y), fmaxf(v.z, v.w));
  #pragma unroll
  for (int off = 32; off; off >>= 1) m = fmaxf(m, __shfl_xor(m, off));
  __shared__ float redm[4], reds[4];
  const int wid = tid >> 6, lane = tid & 63;
  if (lane == 0) redm[wid] = m;
  __syncthreads();
  m = fmaxf(fmaxf(redm[0], redm[1]), fmaxf(redm[2], redm[3]));
  float e0 = expf(v.x - m), e1 = expf(v.y - m), e2 = expf(v.z - m), e3 = expf(v.w - m);
  float s = e0 + e1 + e2 + e3;
  #pragma unroll
  for (int off = 32; off; off >>= 1) s += __shfl_xor(s, off);
  if (lane == 0) reds[wid] = s;
  __syncthreads();
  s = reds[0] + reds[1] + reds[2] + reds[3];
  float inv = 1.f / s;
  *(float4*)&p[tid * 4] = make_float4(e0 * inv, e1 * inv, e2 * inv, e3 * inv);
}

// ---------------- per (h,b): sum_k max_q alpha, split over 4 k-chunks ----------------
__global__ __launch_bounds__(256) void colmax_fr(const float* __restrict__ e,
                                                 float* __restrict__ part) {
  const int z = blockIdx.x;           // h*16+b
  const int c4 = blockIdx.y;          // k-chunk
  const float* base = e + (size_t)z * QL * KL + c4 * 256 + threadIdx.x;
  float cm = -1e30f;
  #pragma unroll 8
  for (int qq = 0; qq < QL; ++qq) cm = fmaxf(cm, base[(size_t)qq * KL]);
  float s = cm;
  #pragma unroll
  for (int off = 32; off; off >>= 1) s += __shfl_xor(s, off);
  __shared__ float red[4];
  if ((threadIdx.x & 63) == 0) red[threadIdx.x >> 6] = s;
  __syncthreads();
  if (threadIdx.x == 0) part[z * 4 + c4] = red[0] + red[1] + red[2] + red[3];
}

// ---------------- head select: fr, h_idx, fr_max ----------------
__global__ void select_head(const float* __restrict__ part, const int* __restrict__ mel,
                            int* __restrict__ hidx, float* __restrict__ fr_out) {
  __shared__ float bf[16];
  const int b = threadIdx.x;
  if (b < 16) {
    float best = -1e30f; int bh = 0;
    for (int h = 0; h < NH; ++h) {
      const float* pp = part + (h * 16 + b) * 4;
      float fr = (pp[0] + pp[1] + pp[2] + pp[3]) / (float)mel[b];
      if (fr > best) { best = fr; bh = h; }
    }
    hidx[b] = bh;
    bf[b] = best;
  }
  __syncthreads();
  if (threadIdx.x == 0) {
    float s = 0.f;
    for (int i = 0; i < 16; ++i) s += bf[i];
    *fr_out = s / 16.f;
  }
}

// ---------------- gather selected head -> d_out copy + transposed [b][k][q] ----------------
__global__ __launch_bounds__(256) void gather_alpha(
    const float* __restrict__ e, const int* __restrict__ hidx,
    float* __restrict__ afc, float* __restrict__ aft)
{
  __shared__ float tile[32][33];
  const int b = blockIdx.z, k0 = blockIdx.x * 32, q0 = blockIdx.y * 32;
  const int hb = hidx[b];
  const float* src = e + (size_t)(hb * 16 + b) * QL * KL;
  const int tx = threadIdx.x, ty = threadIdx.y;
  #pragma unroll
  for (int yy = 0; yy < 4; ++yy) {
    int r = ty + 8 * yy;
    float v = src[(size_t)(q0 + r) * KL + k0 + tx];
    afc[((size_t)b * QL + q0 + r) * KL + k0 + tx] = v;
    tile[r][tx] = v;
  }
  __syncthreads();
  #pragma unroll
  for (int yy = 0; yy < 4; ++yy) {
    int c = ty + 8 * yy;
    aft[((size_t)b * KL + k0 + c) * QL + q0 + tx] = tile[tx][c];
  }
}

// ---------------- stepwise monotonic scan over k (sequential), per batch ----------------
__global__ __launch_bounds__(512) void smma_scan(const float* __restrict__ aft,
                                                 float* __restrict__ ame) {
  __shared__ float aw_s[2][QL];
  const int b = blockIdx.x, qq = threadIdx.x;
  const float* pT = aft + (size_t)b * KL * QL;
  float* am = ame + (size_t)b * KL * QL;
  float aw = (qq == 0) ? 1.f : 0.f;
  aw_s[0][qq] = aw;
  __syncthreads();
  float g = pT[qq];
  float gm1 = (qq > 0) ? pT[qq - 1] : 0.f;
  int cur = 0;
  for (int kk = 0; kk < KL; ++kk) {
    float gn = 0.f, gnm1 = 0.f;
    if (kk < KL - 1) {
      gn = pT[(size_t)(kk + 1) * QL + qq];
      gnm1 = (qq > 0) ? pT[(size_t)(kk + 1) * QL + qq - 1] : 0.f;
    }
    float pv  = 1.f / (1.f + expf(-g));
    float pm1 = 1.f / (1.f + expf(-gm1));
    float left = (qq > 0) ? aw_s[cur][qq - 1] : 0.f;
    aw = aw * pv + left * (1.f - pm1);
    am[(size_t)kk * QL + qq] = aw;
    aw_s[cur ^ 1][qq] = aw;
    __syncthreads();
    cur ^= 1;
    g = gn; gm1 = gnm1;
  }
}

// ---------------- cv_pre[b,q,d] = sum_k ame[b,k,q] * vh[b,k,d]  (TN GEMM) ----------------
__global__ __launch_bounds__(256) void gemm_cv(
    const float* __restrict__ ame, const float* __restrict__ vh, float* __restrict__ cvp)
{
  __shared__ __align__(16) float As[32][132];
  __shared__ __align__(16) float Bs[32][132];
  const int b = blockIdx.z;
  const float* Ab = ame + (size_t)b * KL * QL + blockIdx.x * 128;  // [k][q]
  const float* Bb = vh + (size_t)b * KL * DM + blockIdx.y * 128;   // [k][d]
  float* Cb = cvp + (size_t)b * QL * DM + (size_t)blockIdx.x * 128 * DM + blockIdx.y * 128;
  const int tid = threadIdx.x, ti = tid & 15, tj = tid >> 4;
  const int ml = tid & 127, k2 = tid >> 7;

  float acc[8][8];
  #pragma unroll
  for (int i = 0; i < 8; ++i)
    #pragma unroll
    for (int j = 0; j < 8; ++j) acc[i][j] = 0.f;

  for (int k0 = 0; k0 < KL; k0 += 32) {
    __syncthreads();
    for (int kk = k2; kk < 32; kk += 2) {
      As[kk][ml] = Ab[(size_t)(k0 + kk) * QL + ml];
      Bs[kk][ml] = Bb[(size_t)(k0 + kk) * DM + ml];
    }
    __syncthreads();
    #pragma unroll 4
    for (int kk = 0; kk < 32; ++kk) {
      float4 a0 = *(const float4*)&As[kk][4 * ti];
      float4 a1 = *(const float4*)&As[kk][64 + 4 * ti];
      float4 b0 = *(const float4*)&Bs[kk][4 * tj];
      float4 b1 = *(const float4*)&Bs[kk][64 + 4 * tj];
      float av[8] = {a0.x, a0.y, a0.z, a0.w, a1.x, a1.y, a1.z, a1.w};
      float bw[8] = {b0.x, b0.y, b0.z, b0.w, b1.x, b1.y, b1.z, b1.w};
      #pragma unroll
      for (int i = 0; i < 8; ++i)
        #pragma unroll
        for (int j = 0; j < 8; ++j) acc[i][j] += av[i] * bw[j];
    }
  }
  #pragma unroll
  for (int i = 0; i < 8; ++i) {
    int mi = (i < 4) ? (4 * ti + i) : (64 + 4 * ti + (i - 4));
    float4 lo = make_float4(acc[i][0], acc[i][1], acc[i][2], acc[i][3]);
    float4 hi = make_float4(acc[i][4], acc[i][5], acc[i][6], acc[i][7]);
    *(float4*)&Cb[(size_t)mi * DM + 4 * tj] = lo;
    *(float4*)&Cb[(size_t)mi * DM + 64 + 4 * tj] = hi;
  }
}

// ---------------- out[i,m] = cv_pre[i,:] . w_last[m,:] + b_last[m]  (NT GEMM) ----------------
__global__ __launch_bounds__(256) void gemm_proj(
    const float* __restrict__ A, const float* __restrict__ W,
    const float* __restrict__ bias, float* __restrict__ C)
{
  __shared__ __align__(16) float As[128][36];
  __shared__ __align__(16) float Bs[128][36];
  const float* Ab = A + (size_t)blockIdx.x * 128 * DM;
  const float* Bb = W + (size_t)blockIdx.y * 128 * DM;
  float* Cb = C + (size_t)blockIdx.x * 128 * DM + blockIdx.y * 128;
  const int tid = threadIdx.x, ti = tid & 15, tj = tid >> 4;
  const int kks = tid & 31, m8 = tid >> 5;

  float acc[8][8];
  #pragma unroll
  for (int i = 0; i < 8; ++i)
    #pragma unroll
    for (int j = 0; j < 8; ++j) acc[i][j] = 0.f;

  for (int k0 = 0; k0 < DM; k0 += 32) {
    __syncthreads();
    for (int m = m8; m < 128; m += 8) {
      As[m][kks] = Ab[(size_t)m * DM + k0 + kks];
      Bs[m][kks] = Bb[(size_t)m * DM + k0 + kks];
    }
    __syncthreads();
    for (int kq = 0; kq < 32; kq += 4) {
      float4 a[8], bv[8];
      #pragma unroll
      for (int i = 0; i < 8; ++i) a[i] = *(const float4*)&As[ti + 16 * i][kq];
      #pragma unroll
      for (int j = 0; j < 8; ++j) {
        int n = (j < 4) ? (4 * tj + j) : (64 + 4 * tj + (j - 4));
        bv[j] = *(const float4*)&Bs[n][kq];
      }
      #pragma unroll
      for (int i = 0; i < 8; ++i)
        #pragma unroll
        for (int j = 0; j < 8; ++j)
          acc[i][j] += a[i].x * bv[j].x + a[i].y * bv[j].y +
                       a[i].z * bv[j].z + a[i].w * bv[j].w;
    }
  }
  const float4 bl = *(const float4*)&bias[blockIdx.y * 128 + 4 * tj];
  const float4 bh = *(const float4*)&bias[blockIdx.y * 128 + 64 + 4 * tj];
  #pragma unroll
  for (int i = 0; i < 8; ++i) {
    int r = ti + 16 * i;
    float4 lo = make_float4(acc[i][0] + bl.x, acc[i][1] + bl.y,
                            acc[i][2] + bl.z, acc[i][3] + bl.w);
    float4 hi = make_float4(acc[i][4] + bh.x, acc[i][5] + bh.y,
                            acc[i][6] + bh.z, acc[i][7] + bh.w);
    *(float4*)&Cb[(size_t)r * DM + 4 * tj] = lo;
    *(float4*)&Cb[(size_t)r * DM + 64 + 4 * tj] = hi;
  }
}

extern "C" void kernel_launch(void* const* d_in, const int* in_sizes, int n_in,
                              void* d_out, int out_size, void* d_ws, size_t ws_size,
                              hipStream_t stream) {
  const float* q      = (const float*)d_in[0];
  const float* k      = (const float*)d_in[1];
  const float* v      = (const float*)d_in[2];
  const int*   mel    = (const int*)d_in[3];
  const float* w_qs   = (const float*)d_in[4];
  const float* b_qs   = (const float*)d_in[5];
  const float* w_ks   = (const float*)d_in[6];
  const float* b_ks   = (const float*)d_in[7];
  const float* w_vs   = (const float*)d_in[8];
  const float* b_vs   = (const float*)d_in[9];
  const float* w_last = (const float*)d_in[10];
  const float* b_last = (const float*)d_in[11];

  float* ws  = (float*)d_ws;
  float* out = (float*)d_out;

  // 1. repack conv weights
  repack_w<<<2496, 256, 0, stream>>>(w_qs, ws + OFF_WT2Q);
  repack_w<<<2496, 256, 0, stream>>>(w_ks, ws + OFF_WT2K);
  repack_w<<<2496, 256, 0, stream>>>(w_vs, ws + OFF_WT2V);

  // 2. grouped convs
  conv_grouped<<<dim3(QL / 128, 1, NB * NH), 256, 0, stream>>>(q, ws + OFF_WT2Q, b_qs, ws + OFF_QH, QL);
  conv_grouped<<<dim3(KL / 128, 1, NB * NH), 256, 0, stream>>>(k, ws + OFF_WT2K, b_ks, ws + OFF_KH, KL);
  conv_grouped<<<dim3(KL / 128, 1, NB * NH), 256, 0, stream>>>(v, ws + OFF_WT2V, b_vs, ws + OFF_VH, KL);

  // 3. energies e[h,b,q,k]
  gemm_qk<<<dim3(QL / 128, KL / 128, NB * NH), 256, 0, stream>>>(ws + OFF_QH, ws + OFF_KH, ws + OFF_E);

  // 4. softmax over k (in place)
  softmax_rows<<<NH * NB * QL, 256, 0, stream>>>(ws + OFF_E);

  // 5. fr stats
  colmax_fr<<<dim3(NH * NB, 4), 256, 0, stream>>>(ws + OFF_E, ws + OFF_PART);

  // 6. head select + fr_max
  select_head<<<1, 64, 0, stream>>>(ws + OFF_PART, mel, (int*)(ws + OFF_HIDX), out + OUT_FR);

  // 7. gather alpha_fc -> d_out and transposed [b][k][q]
  gather_alpha<<<dim3(KL / 32, QL / 32, NB), dim3(32, 8), 0, stream>>>(
      ws + OFF_E, (const int*)(ws + OFF_HIDX), out + OUT_ALPHA, ws + OFF_AFT);

  // 8. sequential monotonic scan -> alpha_me [b][k][q] (aliases dead e buffer)
  smma_scan<<<NB, QL, 0, stream>>>(ws + OFF_AFT, ws + OFF_AME);

  // 9. cv_pre = alpha_me^T @ vh
  gemm_cv<<<dim3(QL / 128, DM / 128, NB), 256, 0, stream>>>(ws + OFF_AME, ws + OFF_VH, ws + OFF_CVP);

  // 10. final projection + bias -> d_out cv
  gemm_proj<<<dim3((NB * QL) / 128, DM / 128, 1), 256, 0, stream>>>(ws + OFF_CVP, w_last, b_last, out + OUT_CV);
}

// Round 2
// 551.442 us; speedup vs baseline: 4.0740x; 4.0740x over previous
//
#include <hip/hip_runtime.h>

#define NB 16
#define QL 512
#define KL 1024
#define DM 384
#define NH 3
#define DK 128

typedef unsigned short u16;
typedef __attribute__((ext_vector_type(8))) short bf16x8;
typedef __attribute__((ext_vector_type(4))) float f32x4;

// ---------------- workspace byte offsets ----------------
static const size_t B_WT3Q = 0;          // bf16 [384][1664]
static const size_t B_WT3K = 1277952;
static const size_t B_WT3V = 2555904;
static const size_t B_WLB  = 3833856;    // bf16 [384][384]
static const size_t B_QH   = 4128768;    // bf16 [16][512][384]
static const size_t B_KH   = 10420224;   // bf16 [16][1024][384]
static const size_t B_VH   = 23003136;   // bf16 [16][1024][384]
static const size_t B_VHT  = 35586048;   // bf16 [16][384][1024]
static const size_t B_E    = 48168960;   // f32 [3][16][512][1024]
static const size_t B_AME  = 48168960;   // bf16 [16][1024][512]   (aliases dead e)
static const size_t B_AMT  = 64946176;   // bf16 [16][512][1024]   (aliases dead e)
static const size_t B_PT   = 148832256;  // f32 [16][1024][512] + 64KB slack
static const size_t B_CVP  = 182452224;  // bf16 [16][512][384]
static const size_t B_PART = 188743680;  // f32 [48][4]
static const size_t B_HIDX = 188744448;  // int [16]

// d_out offsets (floats)
static const size_t OUT_CV    = 0;
static const size_t OUT_ALPHA = 3145728;
static const size_t OUT_FR    = 11534336;

__device__ __forceinline__ u16 f2b(float x) {
  union { float f; unsigned u; } q; q.f = x;
  unsigned r = q.u + 0x7fffu + ((q.u >> 16) & 1u);
  return (u16)(r >> 16);
}

// ---------------- weight repack: w[oc][ic][t] -> bf16 wT[oc][t*128+ic] ----------------
__global__ __launch_bounds__(256) void repack_w_bf16(const float* __restrict__ src,
                                                     u16* __restrict__ dst) {
  int tid = blockIdx.x * 256 + threadIdx.x;
  if (tid >= 384 * 1664) return;
  int oc = tid / 1664, kk = tid % 1664;
  int t = kk >> 7, ic = kk & 127;
  dst[tid] = f2b(src[(size_t)oc * 1664 + ic * 13 + t]);
}

__global__ __launch_bounds__(256) void cvt_bf16(const float* __restrict__ src,
                                                u16* __restrict__ dst, int n) {
  int i = blockIdx.x * 256 + threadIdx.x;
  if (i < n) dst[i] = f2b(src[i]);
}

// ---------------- universal NT MFMA GEMM: C[m][n] = alpha*sum_k A[m][k]*B[n][k] (+bias[n]) --
// CONV_A: A is virtual im2col of f32 x: A[row][k] = x[b, l + k/128 - 6, z0*128 + k%128]
template <bool OUT_BF16, bool BIAS, bool CONV_A>
__global__ __launch_bounds__(256) void gemm_nt(
    const void* __restrict__ Aptr, const u16* __restrict__ Bw,
    void* __restrict__ Cptr, const float* __restrict__ bias,
    int lda, int ldb, int ldc, int K, float alpha, int zdiv,
    long sA1, long sA0, long sB1, long sB0, long sC1, long sC0, long sb0, int lgL)
{
  __shared__ __align__(16) u16 As[128][72];
  __shared__ __align__(16) u16 Bs[128][72];
  const int tid = threadIdx.x;
  const int z = blockIdx.z;
  const int z1 = z / zdiv, z0 = z % zdiv;
  const int m0 = blockIdx.x * 128, n0 = blockIdx.y * 128;
  const u16* Bz = Bw + z1 * sB1 + z0 * sB0;
  const int Lmask = (1 << lgL) - 1;

  f32x4 acc[4][4];
  const f32x4 zero4 = {0.f, 0.f, 0.f, 0.f};
  #pragma unroll
  for (int m = 0; m < 4; ++m)
    #pragma unroll
    for (int n = 0; n < 4; ++n) acc[m][n] = zero4;

  const int rs = tid >> 3;            // 0..31
  const int k8 = (tid & 7) * 8;       // 0..56
  const int wv = tid >> 6, lane = tid & 63;
  const int wr = (wv >> 1) * 64, wc = (wv & 1) * 64;
  const int fr = lane & 15, fk = (lane >> 4) * 8;

  for (int k0 = 0; k0 < K; k0 += 64) {
    if constexpr (CONV_A) {
      const float* X = (const float*)Aptr + z1 * sA1 + z0 * sA0;
      const int t = k0 >> 7;
      const int ic = (k0 & 64) + k8;
      #pragma unroll
      for (int p = 0; p < 4; ++p) {
        int row = m0 + rs + p * 32;
        int l = (row & Lmask) + t - 6;
        union { u16 h[8]; uint4 v; } tmp;
        if ((unsigned)l <= (unsigned)Lmask) {
          const float* srcp = X + (size_t)((row & ~Lmask) + l) * lda + ic;
          float4 v0 = *(const float4*)srcp;
          float4 v1 = *(const float4*)(srcp + 4);
          tmp.h[0] = f2b(v0.x); tmp.h[1] = f2b(v0.y); tmp.h[2] = f2b(v0.z); tmp.h[3] = f2b(v0.w);
          tmp.h[4] = f2b(v1.x); tmp.h[5] = f2b(v1.y); tmp.h[6] = f2b(v1.z); tmp.h[7] = f2b(v1.w);
        } else {
          tmp.v = make_uint4(0, 0, 0, 0);
        }
        *(uint4*)&As[rs + p * 32][k8] = tmp.v;
      }
    } else {
      const u16* Ab = (const u16*)Aptr + z1 * sA1 + z0 * sA0;
      #pragma unroll
      for (int p = 0; p < 4; ++p)
        *(uint4*)&As[rs + p * 32][k8] =
            *(const uint4*)&Ab[(size_t)(m0 + rs + p * 32) * lda + k0 + k8];
    }
    #pragma unroll
    for (int p = 0; p < 4; ++p)
      *(uint4*)&Bs[rs + p * 32][k8] =
          *(const uint4*)&Bz[(size_t)(n0 + rs + p * 32) * ldb + k0 + k8];
    __syncthreads();
    #pragma unroll
    for (int ks = 0; ks < 2; ++ks) {
      bf16x8 av[4], bv[4];
      #pragma unroll
      for (int m = 0; m < 4; ++m)
        av[m] = *(const bf16x8*)&As[wr + m * 16 + fr][ks * 32 + fk];
      #pragma unroll
      for (int n = 0; n < 4; ++n)
        bv[n] = *(const bf16x8*)&Bs[wc + n * 16 + fr][ks * 32 + fk];
      #pragma unroll
      for (int m = 0; m < 4; ++m)
        #pragma unroll
        for (int n = 0; n < 4; ++n)
          acc[m][n] = __builtin_amdgcn_mfma_f32_16x16x32_bf16(av[m], bv[n], acc[m][n], 0, 0, 0);
    }
    __syncthreads();
  }

  // epilogue: C/D frag: col = lane&15, row = (lane>>4)*4 + j  (m89-verified)
  const int crow = (lane >> 4) * 4;
  const long cbase = z1 * sC1 + z0 * sC0;
  #pragma unroll
  for (int m = 0; m < 4; ++m) {
    #pragma unroll
    for (int n = 0; n < 4; ++n) {
      const int gm = m0 + wr + m * 16 + crow;
      const int gn = n0 + wc + n * 16 + fr;
      float bval = 0.f;
      if constexpr (BIAS) bval = bias[z0 * sb0 + gn];
      #pragma unroll
      for (int j = 0; j < 4; ++j) {
        float vv = acc[m][n][j] * alpha + bval;
        if constexpr (OUT_BF16)
          ((u16*)Cptr)[cbase + (size_t)(gm + j) * ldc + gn] = f2b(vv);
        else
          ((float*)Cptr)[cbase + (size_t)(gm + j) * ldc + gn] = vv;
      }
    }
  }
}

// ---------------- row softmax over k (1024), in place ----------------
__global__ __launch_bounds__(256) void softmax_rows(float* __restrict__ e) {
  float* p = e + (size_t)blockIdx.x * KL;
  const int tid = threadIdx.x;
  float4 v = *(const float4*)&p[tid * 4];
  float m = fmaxf(fmaxf(v.x, v.y), fmaxf(v.z, v.w));
  #pragma unroll
  for (int off = 32; off; off >>= 1) m = fmaxf(m, __shfl_xor(m, off));
  __shared__ float redm[4], reds[4];
  const int wid = tid >> 6, lane = tid & 63;
  if (lane == 0) redm[wid] = m;
  __syncthreads();
  m = fmaxf(fmaxf(redm[0], redm[1]), fmaxf(redm[2], redm[3]));
  float e0 = expf(v.x - m), e1 = expf(v.y - m), e2 = expf(v.z - m), e3 = expf(v.w - m);
  float s = e0 + e1 + e2 + e3;
  #pragma unroll
  for (int off = 32; off; off >>= 1) s += __shfl_xor(s, off);
  if (lane == 0) reds[wid] = s;
  __syncthreads();
  s = reds[0] + reds[1] + reds[2] + reds[3];
  float inv = 1.f / s;
  *(float4*)&p[tid * 4] = make_float4(e0 * inv, e1 * inv, e2 * inv, e3 * inv);
}

// ---------------- per (h,b): sum_k max_q alpha, split over 4 k-chunks ----------------
__global__ __launch_bounds__(256) void colmax_fr(const float* __restrict__ e,
                                                 float* __restrict__ part) {
  const int z = blockIdx.x;
  const int c4 = blockIdx.y;
  const float* base = e + (size_t)z * QL * KL + c4 * 256 + threadIdx.x;
  float cm = -1e30f;
  #pragma unroll 8
  for (int qq = 0; qq < QL; ++qq) cm = fmaxf(cm, base[(size_t)qq * KL]);
  float s = cm;
  #pragma unroll
  for (int off = 32; off; off >>= 1) s += __shfl_xor(s, off);
  __shared__ float red[4];
  if ((threadIdx.x & 63) == 0) red[threadIdx.x >> 6] = s;
  __syncthreads();
  if (threadIdx.x == 0) part[z * 4 + c4] = red[0] + red[1] + red[2] + red[3];
}

// ---------------- head select ----------------
__global__ void select_head(const float* __restrict__ part, const int* __restrict__ mel,
                            int* __restrict__ hidx, float* __restrict__ fr_out) {
  __shared__ float bf[16];
  const int b = threadIdx.x;
  if (b < 16) {
    float best = -1e30f; int bh = 0;
    for (int h = 0; h < NH; ++h) {
      const float* pp = part + (h * 16 + b) * 4;
      float fr = (pp[0] + pp[1] + pp[2] + pp[3]) / (float)mel[b];
      if (fr > best) { best = fr; bh = h; }
    }
    hidx[b] = bh;
    bf[b] = best;
  }
  __syncthreads();
  if (threadIdx.x == 0) {
    float s = 0.f;
    for (int i = 0; i < 16; ++i) s += bf[i];
    *fr_out = s / 16.f;
  }
}

// ---------------- gather selected head -> d_out alpha + sigmoid(alpha)^T ----------------
__global__ __launch_bounds__(256) void gather_alpha(
    const float* __restrict__ e, const int* __restrict__ hidx,
    float* __restrict__ afc, float* __restrict__ pT)
{
  __shared__ float tile[32][33];
  const int b = blockIdx.z, k0 = blockIdx.x * 32, q0 = blockIdx.y * 32;
  const int hb = hidx[b];
  const float* src = e + (size_t)(hb * 16 + b) * QL * KL;
  const int tx = threadIdx.x, ty = threadIdx.y;
  #pragma unroll
  for (int yy = 0; yy < 4; ++yy) {
    int r = ty + 8 * yy;
    float v = src[(size_t)(q0 + r) * KL + k0 + tx];
    afc[((size_t)b * QL + q0 + r) * KL + k0 + tx] = v;
    tile[r][tx] = v;
  }
  __syncthreads();
  #pragma unroll
  for (int yy = 0; yy < 4; ++yy) {
    int c = ty + 8 * yy;
    float v = tile[tx][c];
    pT[((size_t)b * KL + k0 + c) * QL + q0 + tx] = 1.f / (1.f + expf(-v));
  }
}

// ---------------- wave-per-batch monotonic scan, register-resident ----------------
#define DPF 16
__global__ __launch_bounds__(64) void smma_scan_wave(const float* __restrict__ pT,
                                                     u16* __restrict__ ame) {
  const int b = blockIdx.x, lane = threadIdx.x;
  const float* P = pT + (size_t)b * KL * QL + lane * 8;
  u16* outp = ame + (size_t)b * KL * QL + lane * 8;
  float aw[8];
  #pragma unroll
  for (int i = 0; i < 8; ++i) aw[i] = 0.f;
  if (lane == 0) aw[0] = 1.f;
  float4 pa[DPF], pb[DPF];
  #pragma unroll
  for (int j = 0; j < DPF; ++j) {
    pa[j] = *(const float4*)(P + (size_t)j * QL);
    pb[j] = *(const float4*)(P + (size_t)j * QL + 4);
  }
  for (int kb = 0; kb < KL; kb += DPF) {
    #pragma unroll
    for (int j = 0; j < DPF; ++j) {
      float p[8] = {pa[j].x, pa[j].y, pa[j].z, pa[j].w,
                    pb[j].x, pb[j].y, pb[j].z, pb[j].w};
      // prefetch (over-reads <= DPF rows past end: slack allocated after pT)
      pa[j] = *(const float4*)(P + (size_t)(kb + DPF + j) * QL);
      pb[j] = *(const float4*)(P + (size_t)(kb + DPF + j) * QL + 4);
      float awL = __shfl_up(aw[7], 1);
      float pL  = __shfl_up(p[7], 1);
      float nw[8];
      nw[0] = aw[0] * p[0] + (lane ? awL * (1.f - pL) : 0.f);
      #pragma unroll
      for (int i = 1; i < 8; ++i) nw[i] = aw[i] * p[i] + aw[i - 1] * (1.f - p[i - 1]);
      union { u16 h[8]; uint4 v; } ob;
      #pragma unroll
      for (int i = 0; i < 8; ++i) { ob.h[i] = f2b(nw[i]); aw[i] = nw[i]; }
      *(uint4*)(outp + (size_t)(kb + j) * QL) = ob.v;
    }
  }
}

// ---------------- batched bf16 transpose: dst[c][r] = src[r][c] ----------------
__global__ __launch_bounds__(256) void transpose_bf16(
    const u16* __restrict__ src, u16* __restrict__ dst, int R, int C, long sz)
{
  __shared__ __align__(16) u16 tile[64][72];
  src += (size_t)blockIdx.z * sz;
  dst += (size_t)blockIdx.z * sz;
  const int r0 = blockIdx.x * 64, c0 = blockIdx.y * 64;
  {
    const int rr = threadIdx.x >> 3, c8 = (threadIdx.x & 7) * 8;
    #pragma unroll
    for (int p = 0; p < 2; ++p)
      *(uint4*)&tile[rr + p * 32][c8] =
          *(const uint4*)&src[(size_t)(r0 + rr + p * 32) * C + c0 + c8];
  }
  __syncthreads();
  {
    const int cc = threadIdx.x & 31, r8 = (threadIdx.x >> 5) * 8;
    #pragma unroll
    for (int p = 0; p < 2; ++p) {
      union { u16 h[8]; uint4 v; } o;
      #pragma unroll
      for (int j = 0; j < 8; ++j) o.h[j] = tile[r8 + j][cc + p * 32];
      *(uint4*)&dst[(size_t)(c0 + cc + p * 32) * R + r0 + r8] = o.v;
    }
  }
}

extern "C" void kernel_launch(void* const* d_in, const int* in_sizes, int n_in,
                              void* d_out, int out_size, void* d_ws, size_t ws_size,
                              hipStream_t stream) {
  const float* q      = (const float*)d_in[0];
  const float* k      = (const float*)d_in[1];
  const float* v      = (const float*)d_in[2];
  const int*   mel    = (const int*)d_in[3];
  const float* w_qs   = (const float*)d_in[4];
  const float* b_qs   = (const float*)d_in[5];
  const float* w_ks   = (const float*)d_in[6];
  const float* b_ks   = (const float*)d_in[7];
  const float* w_vs   = (const float*)d_in[8];
  const float* b_vs   = (const float*)d_in[9];
  const float* w_last = (const float*)d_in[10];
  const float* b_last = (const float*)d_in[11];

  char* ws = (char*)d_ws;
  float* out = (float*)d_out;

  u16* WT3Q = (u16*)(ws + B_WT3Q);
  u16* WT3K = (u16*)(ws + B_WT3K);
  u16* WT3V = (u16*)(ws + B_WT3V);
  u16* WLB  = (u16*)(ws + B_WLB);
  u16* QH   = (u16*)(ws + B_QH);
  u16* KH   = (u16*)(ws + B_KH);
  u16* VH   = (u16*)(ws + B_VH);
  u16* VHT  = (u16*)(ws + B_VHT);
  float* E  = (float*)(ws + B_E);
  u16* AME  = (u16*)(ws + B_AME);
  u16* AMT  = (u16*)(ws + B_AMT);
  float* PT = (float*)(ws + B_PT);
  u16* CVP  = (u16*)(ws + B_CVP);
  float* PART = (float*)(ws + B_PART);
  int* HIDX = (int*)(ws + B_HIDX);

  // 1. repack conv weights + w_last to bf16
  repack_w_bf16<<<2496, 256, 0, stream>>>(w_qs, WT3Q);
  repack_w_bf16<<<2496, 256, 0, stream>>>(w_ks, WT3K);
  repack_w_bf16<<<2496, 256, 0, stream>>>(w_vs, WT3V);
  cvt_bf16<<<576, 256, 0, stream>>>(w_last, WLB, 384 * 384);

  // 2. grouped convs as virtual-im2col MFMA GEMMs (z = group)
  gemm_nt<true, true, true><<<dim3(64, 1, 3), 256, 0, stream>>>(
      q, WT3Q, QH, b_qs, DM, 1664, DM, 1664, 1.f, 3,
      0, 128, 0, 128L * 1664, 0, 128, 128, 9);
  gemm_nt<true, true, true><<<dim3(128, 1, 3), 256, 0, stream>>>(
      k, WT3K, KH, b_ks, DM, 1664, DM, 1664, 1.f, 3,
      0, 128, 0, 128L * 1664, 0, 128, 128, 10);
  gemm_nt<true, true, true><<<dim3(128, 1, 3), 256, 0, stream>>>(
      v, WT3V, VH, b_vs, DM, 1664, DM, 1664, 1.f, 3,
      0, 128, 0, 128L * 1664, 0, 128, 128, 10);

  // 3. e[h,b,q,k] = qh . kh / sqrt(128)   (z = h*16 + b)
  gemm_nt<false, false, false><<<dim3(4, 8, 48), 256, 0, stream>>>(
      QH, KH, E, nullptr, DM, DM, KL, DK, 0.08838834764831845f, 16,
      128, 512L * DM, 128, 1024L * DM, 8388608L, 524288L, 0, 0);

  // 4. softmax over k (in place)
  softmax_rows<<<NH * NB * QL, 256, 0, stream>>>(E);

  // 5-6. fr stats + head select
  colmax_fr<<<dim3(NH * NB, 4), 256, 0, stream>>>(E, PART);
  select_head<<<1, 64, 0, stream>>>(PART, mel, HIDX, out + OUT_FR);

  // 7. gather alpha_fc -> d_out, sigmoid -> pT [b][k][q]
  gather_alpha<<<dim3(KL / 32, QL / 32, NB), dim3(32, 8), 0, stream>>>(
      E, HIDX, out + OUT_ALPHA, PT);

  // 8. register scan -> ame bf16 [b][k][q]
  smma_scan_wave<<<NB, 64, 0, stream>>>(PT, AME);

  // 9. transposes: ame -> amT [b][q][k]; vh -> vhT [b][d][k]
  transpose_bf16<<<dim3(16, 8, NB), 256, 0, stream>>>(AME, AMT, KL, QL, 524288);
  transpose_bf16<<<dim3(16, 6, NB), 256, 0, stream>>>(VH, VHT, KL, DM, 393216);

  // 10. cv_pre[b][q][d] = sum_k amT[q][k] * vhT[d][k]
  gemm_nt<true, false, false><<<dim3(4, 3, NB), 256, 0, stream>>>(
      AMT, VHT, CVP, nullptr, KL, KL, DM, KL, 1.f, 1,
      524288L, 0, 393216L, 0, 196608L, 0, 0, 0);

  // 11. out = cv_pre @ w_last^T + b_last
  gemm_nt<false, true, false><<<dim3(64, 3, 1), 256, 0, stream>>>(
      CVP, WLB, out + OUT_CV, b_last, DM, DM, DM, DM, 1.f, 1,
      0, 0, 0, 0, 0, 0, 0, 0);
}

// Round 3
// 433.070 us; speedup vs baseline: 5.1875x; 1.2733x over previous
//
#include <hip/hip_runtime.h>

#define NB 16
#define QL 512
#define KL 1024
#define DM 384
#define NH 3
#define DK 128

typedef unsigned short u16;
typedef __attribute__((ext_vector_type(8))) short bf16x8;
typedef __attribute__((ext_vector_type(4))) float f32x4;

// ---------------- workspace byte offsets ----------------
static const size_t B_WT3Q = 0;          // bf16 [384][1664]
static const size_t B_WT3K = 1277952;
static const size_t B_WT3V = 2555904;
static const size_t B_WLB  = 3833856;    // bf16 [384][384]
static const size_t B_QH   = 4128768;    // bf16 [16][512][384]
static const size_t B_KH   = 10420224;   // bf16 [16][1024][384]
static const size_t B_VH   = 23003136;   // bf16 [16][1024][384]
static const size_t B_VHT  = 35586048;   // bf16 [16][384][1024] (written late)
// early-lifetime small buffers alias the VHT region (dead before transpose):
static const size_t B_MS    = 35586048;  // f32 [48*512][2]  (row max, 1/sum)
static const size_t B_CPART = 35782656;  // f32 [48][8][1024] colmax partials
static const size_t B_FRR   = 37355520;  // f32 [48]
static const size_t B_HIDX  = 37355712;  // int [16]
static const size_t B_E    = 48168960;   // f32 [3][16][512][1024]
static const size_t B_AME  = 48168960;   // f32 [16][1024][512]  (aliases dead e)
static const size_t B_AMT  = 81723392;   // bf16 [16][512][1024] (aliases dead e)
static const size_t B_PT   = 148832256;  // f32 [16][1024][512] + 64KB slack
static const size_t B_CVP  = 182452224;  // bf16 [16][512][384]

// d_out offsets (floats)
static const size_t OUT_CV    = 0;
static const size_t OUT_ALPHA = 3145728;
static const size_t OUT_FR    = 11534336;

__device__ __forceinline__ u16 f2b(float x) {
  union { float f; unsigned u; } q; q.f = x;
  unsigned r = q.u + 0x7fffu + ((q.u >> 16) & 1u);
  return (u16)(r >> 16);
}

// ---------------- weight repacks (one launch): conv w[oc][ic][t] -> bf16 [oc][t*128+ic];
// z==3: w_last f32 -> bf16 ----------------
__global__ __launch_bounds__(256) void repack_all(
    const float* __restrict__ wq, const float* __restrict__ wk,
    const float* __restrict__ wv, const float* __restrict__ wl,
    u16* __restrict__ dq, u16* __restrict__ dk, u16* __restrict__ dv,
    u16* __restrict__ dl) {
  const int z = blockIdx.z;
  const int tid = blockIdx.x * 256 + threadIdx.x;
  if (z < 3) {
    if (tid >= 384 * 1664) return;
    const float* src = (z == 0) ? wq : (z == 1) ? wk : wv;
    u16* dst = (z == 0) ? dq : (z == 1) ? dk : dv;
    int oc = tid / 1664, kk = tid % 1664;
    int t = kk >> 7, ic = kk & 127;
    dst[tid] = f2b(src[(size_t)oc * 1664 + ic * 13 + t]);
  } else {
    if (tid < 384 * 384) dl[tid] = f2b(wl[tid]);
  }
}

// ---------------- merged grouped conv1d as virtual-im2col MFMA GEMM ----------------
// z/3 selects tensor (0=q L=512, 1=k, 2=v L=1024); z%3 = group
__global__ __launch_bounds__(256) void conv_mfma(
    const float* __restrict__ xq, const float* __restrict__ xk, const float* __restrict__ xv,
    const u16* __restrict__ wq, const u16* __restrict__ wk, const u16* __restrict__ wv,
    const float* __restrict__ bq, const float* __restrict__ bk, const float* __restrict__ bv,
    u16* __restrict__ oq, u16* __restrict__ ok, u16* __restrict__ ov)
{
  __shared__ __align__(16) u16 As[128][72];
  __shared__ __align__(16) u16 Bs[128][72];
  const int z = blockIdx.z;
  const int which = z / 3, g = z % 3;
  const float* X; const u16* W; const float* bias; u16* out; int Lmask;
  if (which == 0)      { X = xq; W = wq; bias = bq; out = oq; Lmask = 511; }
  else if (which == 1) { X = xk; W = wk; bias = bk; out = ok; Lmask = 1023; }
  else                 { X = xv; W = wv; bias = bv; out = ov; Lmask = 1023; }
  const int m0 = blockIdx.x * 128;
  if (m0 >= NB * (Lmask + 1)) return;
  X += g * DK; W += (size_t)g * DK * 1664; bias += g * DK; out += g * DK;

  const int tid = threadIdx.x;
  const int rs = tid >> 3;
  const int k8 = (tid & 7) * 8;
  const int wv_ = tid >> 6, lane = tid & 63;
  const int wr = (wv_ >> 1) * 64, wc = (wv_ & 1) * 64;
  const int fr = lane & 15, fk = (lane >> 4) * 8;

  f32x4 acc[4][4];
  const f32x4 zero4 = {0.f, 0.f, 0.f, 0.f};
  #pragma unroll
  for (int m = 0; m < 4; ++m)
    #pragma unroll
    for (int n = 0; n < 4; ++n) acc[m][n] = zero4;

  for (int k0 = 0; k0 < 1664; k0 += 64) {
    const int t = k0 >> 7;
    const int ic = (k0 & 64) + k8;
    #pragma unroll
    for (int p = 0; p < 4; ++p) {
      int row = m0 + rs + p * 32;
      int l = (row & Lmask) + t - 6;
      union { u16 h[8]; uint4 v; } tmp;
      if ((unsigned)l <= (unsigned)Lmask) {
        const float* srcp = X + (size_t)((row & ~Lmask) + l) * DM + ic;
        float4 v0 = *(const float4*)srcp;
        float4 v1 = *(const float4*)(srcp + 4);
        tmp.h[0] = f2b(v0.x); tmp.h[1] = f2b(v0.y); tmp.h[2] = f2b(v0.z); tmp.h[3] = f2b(v0.w);
        tmp.h[4] = f2b(v1.x); tmp.h[5] = f2b(v1.y); tmp.h[6] = f2b(v1.z); tmp.h[7] = f2b(v1.w);
      } else {
        tmp.v = make_uint4(0, 0, 0, 0);
      }
      *(uint4*)&As[rs + p * 32][k8] = tmp.v;
    }
    #pragma unroll
    for (int p = 0; p < 4; ++p)
      *(uint4*)&Bs[rs + p * 32][k8] =
          *(const uint4*)&W[(size_t)(rs + p * 32) * 1664 + k0 + k8];
    __syncthreads();
    #pragma unroll
    for (int ks = 0; ks < 2; ++ks) {
      bf16x8 av[4], bv_[4];
      #pragma unroll
      for (int m = 0; m < 4; ++m)
        av[m] = *(const bf16x8*)&As[wr + m * 16 + fr][ks * 32 + fk];
      #pragma unroll
      for (int n = 0; n < 4; ++n)
        bv_[n] = *(const bf16x8*)&Bs[wc + n * 16 + fr][ks * 32 + fk];
      #pragma unroll
      for (int m = 0; m < 4; ++m)
        #pragma unroll
        for (int n = 0; n < 4; ++n)
          acc[m][n] = __builtin_amdgcn_mfma_f32_16x16x32_bf16(av[m], bv_[n], acc[m][n], 0, 0, 0);
    }
    __syncthreads();
  }

  const int crow = (lane >> 4) * 4;
  #pragma unroll
  for (int m = 0; m < 4; ++m) {
    #pragma unroll
    for (int n = 0; n < 4; ++n) {
      const int gm = m0 + wr + m * 16 + crow;
      const int gn = wc + n * 16 + fr;
      const float bval = bias[gn];
      #pragma unroll
      for (int j = 0; j < 4; ++j)
        out[(size_t)(gm + j) * DM + gn] = f2b(acc[m][n][j] + bval);
    }
  }
}

// ---------------- universal NT MFMA GEMM: C[m][n] = alpha*sum_k A[m][k]*B[n][k] (+bias) ----
template <bool OUT_BF16, bool BIAS>
__global__ __launch_bounds__(256) void gemm_nt(
    const u16* __restrict__ Aw, const u16* __restrict__ Bw,
    void* __restrict__ Cptr, const float* __restrict__ bias,
    int lda, int ldb, int ldc, int K, float alpha, int zdiv,
    long sA1, long sA0, long sB1, long sB0, long sC1, long sC0)
{
  __shared__ __align__(16) u16 As[128][72];
  __shared__ __align__(16) u16 Bs[128][72];
  const int tid = threadIdx.x;
  const int z = blockIdx.z;
  const int z1 = z / zdiv, z0 = z % zdiv;
  const int m0 = blockIdx.x * 128, n0 = blockIdx.y * 128;
  const u16* Ab = Aw + z1 * sA1 + z0 * sA0;
  const u16* Bz = Bw + z1 * sB1 + z0 * sB0;

  f32x4 acc[4][4];
  const f32x4 zero4 = {0.f, 0.f, 0.f, 0.f};
  #pragma unroll
  for (int m = 0; m < 4; ++m)
    #pragma unroll
    for (int n = 0; n < 4; ++n) acc[m][n] = zero4;

  const int rs = tid >> 3;
  const int k8 = (tid & 7) * 8;
  const int wv_ = tid >> 6, lane = tid & 63;
  const int wr = (wv_ >> 1) * 64, wc = (wv_ & 1) * 64;
  const int fr = lane & 15, fk = (lane >> 4) * 8;

  for (int k0 = 0; k0 < K; k0 += 64) {
    #pragma unroll
    for (int p = 0; p < 4; ++p)
      *(uint4*)&As[rs + p * 32][k8] =
          *(const uint4*)&Ab[(size_t)(m0 + rs + p * 32) * lda + k0 + k8];
    #pragma unroll
    for (int p = 0; p < 4; ++p)
      *(uint4*)&Bs[rs + p * 32][k8] =
          *(const uint4*)&Bz[(size_t)(n0 + rs + p * 32) * ldb + k0 + k8];
    __syncthreads();
    #pragma unroll
    for (int ks = 0; ks < 2; ++ks) {
      bf16x8 av[4], bv_[4];
      #pragma unroll
      for (int m = 0; m < 4; ++m)
        av[m] = *(const bf16x8*)&As[wr + m * 16 + fr][ks * 32 + fk];
      #pragma unroll
      for (int n = 0; n < 4; ++n)
        bv_[n] = *(const bf16x8*)&Bs[wc + n * 16 + fr][ks * 32 + fk];
      #pragma unroll
      for (int m = 0; m < 4; ++m)
        #pragma unroll
        for (int n = 0; n < 4; ++n)
          acc[m][n] = __builtin_amdgcn_mfma_f32_16x16x32_bf16(av[m], bv_[n], acc[m][n], 0, 0, 0);
    }
    __syncthreads();
  }

  const int crow = (lane >> 4) * 4;
  const long cbase = z1 * sC1 + z0 * sC0;
  #pragma unroll
  for (int m = 0; m < 4; ++m) {
    #pragma unroll
    for (int n = 0; n < 4; ++n) {
      const int gm = m0 + wr + m * 16 + crow;
      const int gn = n0 + wc + n * 16 + fr;
      float bval = 0.f;
      if constexpr (BIAS) bval = bias[gn];
      #pragma unroll
      for (int j = 0; j < 4; ++j) {
        float vv = acc[m][n][j] * alpha + bval;
        if constexpr (OUT_BF16)
          ((u16*)Cptr)[cbase + (size_t)(gm + j) * ldc + gn] = f2b(vv);
        else
          ((float*)Cptr)[cbase + (size_t)(gm + j) * ldc + gn] = vv;
      }
    }
  }
}

// ---------------- per-row max + 1/sum(exp) over k=1024 ----------------
__global__ __launch_bounds__(256) void rowmaxsum(const float* __restrict__ e,
                                                 float* __restrict__ ms) {
  const float* p = e + (size_t)blockIdx.x * KL;
  const int tid = threadIdx.x;
  float4 v = *(const float4*)&p[tid * 4];
  float m = fmaxf(fmaxf(v.x, v.y), fmaxf(v.z, v.w));
  #pragma unroll
  for (int off = 32; off; off >>= 1) m = fmaxf(m, __shfl_xor(m, off));
  __shared__ float redm[4], reds[4];
  const int wid = tid >> 6, lane = tid & 63;
  if (lane == 0) redm[wid] = m;
  __syncthreads();
  m = fmaxf(fmaxf(redm[0], redm[1]), fmaxf(redm[2], redm[3]));
  float s = expf(v.x - m) + expf(v.y - m) + expf(v.z - m) + expf(v.w - m);
  #pragma unroll
  for (int off = 32; off; off >>= 1) s += __shfl_xor(s, off);
  if (lane == 0) reds[wid] = s;
  __syncthreads();
  if (tid == 0) {
    ms[2 * blockIdx.x] = m;
    ms[2 * blockIdx.x + 1] = 1.f / (reds[0] + reds[1] + reds[2] + reds[3]);
  }
}

// ---------------- colmax partials: max over 64 q rows of alpha, per (z, qc, k) ----------------
__global__ __launch_bounds__(1024) void colmax_part(const float* __restrict__ e,
                                                    const float* __restrict__ ms,
                                                    float* __restrict__ cpart) {
  const int z = blockIdx.x, qc = blockIdx.y, kk = threadIdx.x;
  __shared__ float mq[64], iq[64];
  if (kk < 64) {
    mq[kk] = ms[2 * ((size_t)z * QL + qc * 64 + kk)];
    iq[kk] = ms[2 * ((size_t)z * QL + qc * 64 + kk) + 1];
  }
  __syncthreads();
  const float* base = e + (size_t)z * QL * KL + (size_t)qc * 64 * KL + kk;
  float cm = 0.f;
  #pragma unroll 8
  for (int qq = 0; qq < 64; ++qq)
    cm = fmaxf(cm, expf(base[(size_t)qq * KL] - mq[qq]) * iq[qq]);
  cpart[((size_t)z * 8 + qc) * KL + kk] = cm;
}

// ---------------- fr per (h,b): sum_k max over 8 q-chunks ----------------
__global__ __launch_bounds__(256) void head_fr(const float* __restrict__ cpart,
                                               float* __restrict__ frr) {
  const int z = blockIdx.x, tid = threadIdx.x;
  float s = 0.f;
  for (int k = tid; k < KL; k += 256) {
    float m = 0.f;
    #pragma unroll
    for (int c = 0; c < 8; ++c) m = fmaxf(m, cpart[((size_t)z * 8 + c) * KL + k]);
    s += m;
  }
  #pragma unroll
  for (int off = 32; off; off >>= 1) s += __shfl_xor(s, off);
  __shared__ float red[4];
  if ((tid & 63) == 0) red[tid >> 6] = s;
  __syncthreads();
  if (tid == 0) frr[z] = red[0] + red[1] + red[2] + red[3];
}

// ---------------- head select ----------------
__global__ void select_head(const float* __restrict__ frr, const int* __restrict__ mel,
                            int* __restrict__ hidx, float* __restrict__ fr_out) {
  __shared__ float bf[16];
  const int b = threadIdx.x;
  if (b < 16) {
    float best = -1e30f; int bh = 0;
    for (int h = 0; h < NH; ++h) {
      float fr = frr[h * 16 + b] / (float)mel[b];
      if (fr > best) { best = fr; bh = h; }
    }
    hidx[b] = bh;
    bf[b] = best;
  }
  __syncthreads();
  if (threadIdx.x == 0) {
    float s = 0.f;
    for (int i = 0; i < 16; ++i) s += bf[i];
    *fr_out = s / 16.f;
  }
}

// ---------------- gather selected head: alpha -> d_out; sigmoid(alpha)^T -> pT ----------------
__global__ __launch_bounds__(256) void gather_fused(
    const float* __restrict__ e, const float* __restrict__ ms,
    const int* __restrict__ hidx, float* __restrict__ afc, float* __restrict__ pT)
{
  __shared__ float tile[32][33];
  const int b = blockIdx.z, k0 = blockIdx.x * 32, q0 = blockIdx.y * 32;
  const int hb = hidx[b];
  const float* src = e + (size_t)(hb * 16 + b) * QL * KL;
  const float* msb = ms + 2 * ((size_t)(hb * 16 + b) * QL + q0);
  const int tx = threadIdx.x, ty = threadIdx.y;
  #pragma unroll
  for (int yy = 0; yy < 4; ++yy) {
    int r = ty + 8 * yy;
    float m = msb[2 * r], inv = msb[2 * r + 1];
    float v = expf(src[(size_t)(q0 + r) * KL + k0 + tx] - m) * inv;
    afc[((size_t)b * QL + q0 + r) * KL + k0 + tx] = v;
    tile[r][tx] = v;
  }
  __syncthreads();
  #pragma unroll
  for (int yy = 0; yy < 4; ++yy) {
    int c = ty + 8 * yy;
    float v = tile[tx][c];
    pT[((size_t)b * KL + k0 + c) * QL + q0 + tx] = 1.f / (1.f + expf(-v));
  }
}

// ---------------- wave-per-batch monotonic scan, f32 out, single shfl/step ----------------
#define DPF 16
__global__ __launch_bounds__(64) void smma_scan_wave(const float* __restrict__ pT,
                                                     float* __restrict__ ame) {
  const int b = blockIdx.x, lane = threadIdx.x;
  const float* P = pT + (size_t)b * KL * QL + lane * 8;
  float* outp = ame + (size_t)b * KL * QL + lane * 8;
  float aw[8];
  #pragma unroll
  for (int i = 0; i < 8; ++i) aw[i] = 0.f;
  if (lane == 0) aw[0] = 1.f;
  float4 pa[DPF], pb[DPF];
  #pragma unroll
  for (int j = 0; j < DPF; ++j) {
    pa[j] = *(const float4*)(P + (size_t)j * QL);
    pb[j] = *(const float4*)(P + (size_t)j * QL + 4);
  }
  for (int kb = 0; kb < KL; kb += DPF) {
    #pragma unroll
    for (int j = 0; j < DPF; ++j) {
      float p[8] = {pa[j].x, pa[j].y, pa[j].z, pa[j].w,
                    pb[j].x, pb[j].y, pb[j].z, pb[j].w};
      // prefetch (over-reads <= DPF rows past end: slack allocated after pT)
      pa[j] = *(const float4*)(P + (size_t)(kb + DPF + j) * QL);
      pb[j] = *(const float4*)(P + (size_t)(kb + DPF + j) * QL + 4);
      float tmp[8], c[8];
      #pragma unroll
      for (int i = 0; i < 8; ++i) { tmp[i] = aw[i] * p[i]; c[i] = aw[i] - tmp[i]; }
      float cL = __shfl_up(c[7], 1);
      aw[0] = tmp[0] + (lane ? cL : 0.f);
      #pragma unroll
      for (int i = 1; i < 8; ++i) aw[i] = tmp[i] + c[i - 1];
      *(float4*)(outp + (size_t)(kb + j) * QL) = make_float4(aw[0], aw[1], aw[2], aw[3]);
      *(float4*)(outp + (size_t)(kb + j) * QL + 4) = make_float4(aw[4], aw[5], aw[6], aw[7]);
    }
  }
}

// ---------------- transpose + convert: f32 [R][C] -> bf16 [C][R] ----------------
__global__ __launch_bounds__(256) void transpose_cvt(
    const float* __restrict__ src, u16* __restrict__ dst, int R, int C) {
  __shared__ float tile[64][65];
  src += (size_t)blockIdx.z * R * C;
  dst += (size_t)blockIdx.z * R * C;
  const int r0 = blockIdx.x * 64, c0 = blockIdx.y * 64;
  {
    const int rr = threadIdx.x >> 4, cc = (threadIdx.x & 15) * 4;
    #pragma unroll
    for (int p = 0; p < 4; ++p) {
      float4 v = *(const float4*)&src[(size_t)(r0 + rr + p * 16) * C + c0 + cc];
      tile[rr + p * 16][cc] = v.x; tile[rr + p * 16][cc + 1] = v.y;
      tile[rr + p * 16][cc + 2] = v.z; tile[rr + p * 16][cc + 3] = v.w;
    }
  }
  __syncthreads();
  {
    const int oc = threadIdx.x >> 2, r8 = (threadIdx.x & 3) * 16;
    #pragma unroll
    for (int p = 0; p < 2; ++p) {
      union { u16 h[8]; uint4 u; } o;
      #pragma unroll
      for (int j = 0; j < 8; ++j) o.h[j] = f2b(tile[r8 + p * 8 + j][oc]);
      *(uint4*)&dst[(size_t)(c0 + oc) * R + r0 + r8 + p * 8] = o.u;
    }
  }
}

// ---------------- batched bf16 transpose: dst[c][r] = src[r][c] ----------------
__global__ __launch_bounds__(256) void transpose_bf16(
    const u16* __restrict__ src, u16* __restrict__ dst, int R, int C, long sz)
{
  __shared__ __align__(16) u16 tile[64][72];
  src += (size_t)blockIdx.z * sz;
  dst += (size_t)blockIdx.z * sz;
  const int r0 = blockIdx.x * 64, c0 = blockIdx.y * 64;
  {
    const int rr = threadIdx.x >> 3, c8 = (threadIdx.x & 7) * 8;
    #pragma unroll
    for (int p = 0; p < 2; ++p)
      *(uint4*)&tile[rr + p * 32][c8] =
          *(const uint4*)&src[(size_t)(r0 + rr + p * 32) * C + c0 + c8];
  }
  __syncthreads();
  {
    const int cc = threadIdx.x & 31, r8 = (threadIdx.x >> 5) * 8;
    #pragma unroll
    for (int p = 0; p < 2; ++p) {
      union { u16 h[8]; uint4 v; } o;
      #pragma unroll
      for (int j = 0; j < 8; ++j) o.h[j] = tile[r8 + j][cc + p * 32];
      *(uint4*)&dst[(size_t)(c0 + cc + p * 32) * R + r0 + r8] = o.v;
    }
  }
}

extern "C" void kernel_launch(void* const* d_in, const int* in_sizes, int n_in,
                              void* d_out, int out_size, void* d_ws, size_t ws_size,
                              hipStream_t stream) {
  const float* q      = (const float*)d_in[0];
  const float* k      = (const float*)d_in[1];
  const float* v      = (const float*)d_in[2];
  const int*   mel    = (const int*)d_in[3];
  const float* w_qs   = (const float*)d_in[4];
  const float* b_qs   = (const float*)d_in[5];
  const float* w_ks   = (const float*)d_in[6];
  const float* b_ks   = (const float*)d_in[7];
  const float* w_vs   = (const float*)d_in[8];
  const float* b_vs   = (const float*)d_in[9];
  const float* w_last = (const float*)d_in[10];
  const float* b_last = (const float*)d_in[11];

  char* ws = (char*)d_ws;
  float* out = (float*)d_out;

  u16* WT3Q = (u16*)(ws + B_WT3Q);
  u16* WT3K = (u16*)(ws + B_WT3K);
  u16* WT3V = (u16*)(ws + B_WT3V);
  u16* WLB  = (u16*)(ws + B_WLB);
  u16* QH   = (u16*)(ws + B_QH);
  u16* KH   = (u16*)(ws + B_KH);
  u16* VH   = (u16*)(ws + B_VH);
  u16* VHT  = (u16*)(ws + B_VHT);
  float* MS = (float*)(ws + B_MS);
  float* CPART = (float*)(ws + B_CPART);
  float* FRR = (float*)(ws + B_FRR);
  int* HIDX = (int*)(ws + B_HIDX);
  float* E  = (float*)(ws + B_E);
  float* AME = (float*)(ws + B_AME);
  u16* AMT  = (u16*)(ws + B_AMT);
  float* PT = (float*)(ws + B_PT);
  u16* CVP  = (u16*)(ws + B_CVP);

  // 1. repack conv weights + w_last to bf16 (one launch)
  repack_all<<<dim3(2496, 1, 4), 256, 0, stream>>>(w_qs, w_ks, w_vs, w_last,
                                                   WT3Q, WT3K, WT3V, WLB);

  // 2. all grouped convs, one launch (z: tensor*3 + group)
  conv_mfma<<<dim3(128, 1, 9), 256, 0, stream>>>(q, k, v, WT3Q, WT3K, WT3V,
                                                 b_qs, b_ks, b_vs, QH, KH, VH);

  // 3. e[h,b,q,k] = qh . kh / sqrt(128)   (z = h*16 + b)
  gemm_nt<false, false><<<dim3(4, 8, 48), 256, 0, stream>>>(
      QH, KH, E, nullptr, DM, DM, KL, DK, 0.08838834764831845f, 16,
      128, 512L * DM, 128, 1024L * DM, 8388608L, 524288L);

  // 4. per-row max + 1/sum
  rowmaxsum<<<NH * NB * QL, 256, 0, stream>>>(E, MS);

  // 5. colmax partials + fr + head select
  colmax_part<<<dim3(NH * NB, 8), 1024, 0, stream>>>(E, MS, CPART);
  head_fr<<<NH * NB, 256, 0, stream>>>(CPART, FRR);
  select_head<<<1, 64, 0, stream>>>(FRR, mel, HIDX, out + OUT_FR);

  // 6. gather alpha_fc -> d_out, sigmoid -> pT [b][k][q]
  gather_fused<<<dim3(KL / 32, QL / 32, NB), dim3(32, 8), 0, stream>>>(
      E, MS, HIDX, out + OUT_ALPHA, PT);

  // 7. register scan -> ame f32 [b][k][q]
  smma_scan_wave<<<NB, 64, 0, stream>>>(PT, AME);

  // 8. transposes: ame f32 -> amT bf16 [b][q][k]; vh -> vhT [b][d][k]
  transpose_cvt<<<dim3(16, 8, NB), 256, 0, stream>>>(AME, AMT, KL, QL);
  transpose_bf16<<<dim3(16, 6, NB), 256, 0, stream>>>(VH, VHT, KL, DM, 393216);

  // 9. cv_pre[b][q][d] = sum_k amT[q][k] * vhT[d][k]
  gemm_nt<true, false><<<dim3(4, 3, NB), 256, 0, stream>>>(
      AMT, VHT, CVP, nullptr, KL, KL, DM, KL, 1.f, 1,
      524288L, 0, 393216L, 0, 196608L, 0);

  // 10. out = cv_pre @ w_last^T + b_last
  gemm_nt<false, true><<<dim3(64, 3, 1), 256, 0, stream>>>(
      CVP, WLB, out + OUT_CV, b_last, DM, DM, DM, DM, 1.f, 1,
      0, 0, 0, 0, 0, 0);
}

// Round 4
// 375.380 us; speedup vs baseline: 5.9848x; 1.1537x over previous
//
#include <hip/hip_runtime.h>

#define NB 16
#define QL 512
#define KL 1024
#define DM 384
#define NH 3
#define DK 128

typedef unsigned short u16;
typedef __attribute__((ext_vector_type(8))) short bf16x8;
typedef __attribute__((ext_vector_type(4))) float f32x4;

// ---------------- workspace byte offsets ----------------
static const size_t B_W2Q = 0;            // bf16 [384][1664]
static const size_t B_W2K = 1277952;
static const size_t B_W2V = 2555904;
static const size_t B_WLB = 3833856;      // bf16 [384][384]
static const size_t B_QH  = 4128768;      // bf16 [16*512][384]
static const size_t B_KH  = 10420224;     // bf16 [16*1024][384]
static const size_t B_VH  = 23003136;     // bf16 [16*1024][384]
static const size_t B_XBQ = 35586048;     // bf16 q input
static const size_t B_XBK = 41877504;     // bf16 k input
static const size_t B_XBV = 54460416;     // bf16 v input
static const size_t B_E   = 67043328;     // bf16 [48][512][1024]
static const size_t B_AME = 67043328;     // f32 [16][1024][512]  (aliases dead E-low)
static const size_t B_AMT = 100597760;    // bf16 [16][512][1024] (aliases dead E-high)
static const size_t B_MS  = 117374976;    // f32 [48*512][2] {rowmax, inv}
static const size_t B_CPART = 117571584;  // f32 [48][8][1024]
static const size_t B_FRR = 119144448;    // f32 [48]
static const size_t B_HIDX = 119144704;   // int [16]
static const size_t B_PT  = 119144960;    // f32 [16][1024][512] (+64KB slack after)
static const size_t B_VHT = 152764928;    // bf16 [16][384][1024]
static const size_t B_CVP = 165347840;    // bf16 [16][512][384]

// d_out offsets (floats)
static const size_t OUT_CV    = 0;
static const size_t OUT_ALPHA = 3145728;
static const size_t OUT_FR    = 11534336;

__device__ __forceinline__ u16 f2b(float x) {
  union { float f; unsigned u; } q; q.f = x;
  unsigned r = q.u + 0x7fffu + ((q.u >> 16) & 1u);
  return (u16)(r >> 16);
}
__device__ __forceinline__ float b2f(u16 h) {
  union { unsigned u; float f; } q; q.u = ((unsigned)h) << 16;
  return q.f;
}

// ---------------- weight repacks: conv w[oc][ic][t] -> bf16 [oc][t*128+ic]; z==3: w_last ----
__global__ __launch_bounds__(256) void repack_all(
    const float* __restrict__ wq, const float* __restrict__ wk,
    const float* __restrict__ wv, const float* __restrict__ wl,
    u16* __restrict__ dq, u16* __restrict__ dk, u16* __restrict__ dv,
    u16* __restrict__ dl) {
  const int z = blockIdx.z;
  const int tid = blockIdx.x * 256 + threadIdx.x;
  if (z < 3) {
    if (tid >= 384 * 1664) return;
    const float* src = (z == 0) ? wq : (z == 1) ? wk : wv;
    u16* dst = (z == 0) ? dq : (z == 1) ? dk : dv;
    int oc = tid / 1664, kk = tid % 1664;
    int t = kk >> 7, ic = kk & 127;
    dst[tid] = f2b(src[(size_t)oc * 1664 + ic * 13 + t]);
  } else {
    if (tid < 384 * 384) dl[tid] = f2b(wl[tid]);
  }
}

// ---------------- f32 -> bf16 convert, 8 elems/thread ----------------
__global__ __launch_bounds__(256) void cvt8(const float* __restrict__ src,
                                            u16* __restrict__ dst, int n8) {
  int i = blockIdx.x * 256 + threadIdx.x;
  if (i >= n8) return;
  const float4 a = *(const float4*)&src[i * 8];
  const float4 b = *(const float4*)&src[i * 8 + 4];
  union { u16 h[8]; uint4 v; } o;
  o.h[0] = f2b(a.x); o.h[1] = f2b(a.y); o.h[2] = f2b(a.z); o.h[3] = f2b(a.w);
  o.h[4] = f2b(b.x); o.h[5] = f2b(b.y); o.h[6] = f2b(b.z); o.h[7] = f2b(b.w);
  *(uint4*)&dst[i * 8] = o.v;
}

// ---------------- grouped conv1d: x-window resident in LDS, weights staged per K-step ------
// z/3 selects tensor (0=q L=512, 1=k, 2=v L=1024); z%3 = group
__global__ __launch_bounds__(256) void conv_mfma(
    const u16* __restrict__ xq, const u16* __restrict__ xk, const u16* __restrict__ xv,
    const u16* __restrict__ wq, const u16* __restrict__ wk, const u16* __restrict__ wv,
    const float* __restrict__ bq, const float* __restrict__ bk, const float* __restrict__ bv,
    u16* __restrict__ oq, u16* __restrict__ ok, u16* __restrict__ ov)
{
  __shared__ __align__(16) u16 xw[140][136];
  __shared__ __align__(16) u16 Bs[128][72];
  const int z = blockIdx.z;
  const int which = z / 3, g = z % 3;
  const u16* X; const u16* W; const float* bias; u16* out; int Lmask;
  if (which == 0)      { X = xq; W = wq; bias = bq; out = oq; Lmask = 511; }
  else if (which == 1) { X = xk; W = wk; bias = bk; out = ok; Lmask = 1023; }
  else                 { X = xv; W = wv; bias = bv; out = ov; Lmask = 1023; }
  const int m0 = blockIdx.x * 128;
  if (m0 >= NB * (Lmask + 1)) return;
  X += g * DK; W += (size_t)g * DK * 1664; bias += g * DK; out += g * DK;

  const int tid = threadIdx.x;
  const int l0 = m0 & Lmask, bbase = m0 & ~Lmask;

  // stage the 140-row x-window once
  for (int i = tid; i < 140 * 16; i += 256) {
    const int r = i >> 4, s = i & 15;
    const int l = l0 - 6 + r;
    uint4 v = make_uint4(0, 0, 0, 0);
    if ((unsigned)l <= (unsigned)Lmask)
      v = *(const uint4*)&X[(size_t)(bbase + l) * DM + s * 8];
    *(uint4*)&xw[r][s * 8] = v;
  }

  const int rs = tid >> 3, k8 = (tid & 7) * 8;
  const int wv_ = tid >> 6, lane = tid & 63;
  const int wr = (wv_ >> 1) * 64, wc = (wv_ & 1) * 64;
  const int fr = lane & 15, fk = (lane >> 4) * 8;

  f32x4 acc[4][4];
  const f32x4 zero4 = {0.f, 0.f, 0.f, 0.f};
  #pragma unroll
  for (int m = 0; m < 4; ++m)
    #pragma unroll
    for (int n = 0; n < 4; ++n) acc[m][n] = zero4;

  for (int k0 = 0; k0 < 1664; k0 += 64) {
    __syncthreads();   // xw ready (first iter) / Bs reads done (later iters)
    #pragma unroll
    for (int p = 0; p < 4; ++p)
      *(uint4*)&Bs[rs + p * 32][k8] =
          *(const uint4*)&W[(size_t)(rs + p * 32) * 1664 + k0 + k8];
    __syncthreads();
    const int t = k0 >> 7;
    const int ic0 = k0 & 64;
    #pragma unroll
    for (int ks = 0; ks < 2; ++ks) {
      bf16x8 av[4], bv_[4];
      #pragma unroll
      for (int m = 0; m < 4; ++m)
        av[m] = *(const bf16x8*)&xw[t + wr + m * 16 + fr][ic0 + ks * 32 + fk];
      #pragma unroll
      for (int n = 0; n < 4; ++n)
        bv_[n] = *(const bf16x8*)&Bs[wc + n * 16 + fr][ks * 32 + fk];
      #pragma unroll
      for (int m = 0; m < 4; ++m)
        #pragma unroll
        for (int n = 0; n < 4; ++n)
          acc[m][n] = __builtin_amdgcn_mfma_f32_16x16x32_bf16(av[m], bv_[n], acc[m][n], 0, 0, 0);
    }
  }

  const int crow = (lane >> 4) * 4;
  #pragma unroll
  for (int m = 0; m < 4; ++m) {
    #pragma unroll
    for (int n = 0; n < 4; ++n) {
      const int gm = m0 + wr + m * 16 + crow;
      const int gn = wc + n * 16 + fr;
      const float bval = bias[gn];
      #pragma unroll
      for (int j = 0; j < 4; ++j)
        out[(size_t)(gm + j) * DM + gn] = f2b(acc[m][n][j] + bval);
    }
  }
}

// ---------------- qk: E[z][q][k] = qh.kh/sqrt(128) (bf16 out) + fused row-max ----------------
__global__ __launch_bounds__(256) void qk_flash(
    const u16* __restrict__ QH, const u16* __restrict__ KH,
    u16* __restrict__ E, float* __restrict__ MS)
{
  __shared__ __align__(16) u16 As[128][136];
  __shared__ __align__(16) u16 Bs[128][136];
  __shared__ float rmx[2][128];
  const int tid = threadIdx.x;
  const int z = blockIdx.z, h = z >> 4, b = z & 15;
  const int m0 = blockIdx.x * 128;
  const u16* Ag = QH + ((size_t)b * QL + m0) * DM + h * DK;
  const u16* Bg = KH + (size_t)b * KL * DM + h * DK;
  u16* Ez = E + (size_t)z * QL * KL;

  for (int i = tid; i < 128 * 16; i += 256) {
    const int r = i >> 4, s = i & 15;
    *(uint4*)&As[r][s * 8] = *(const uint4*)&Ag[(size_t)r * DM + s * 8];
  }

  const int wv_ = tid >> 6, lane = tid & 63;
  const int wr = (wv_ >> 1) * 64, wc = (wv_ & 1) * 64;
  const int fr = lane & 15, fk = (lane >> 4) * 8;
  const int crow = (lane >> 4) * 4;
  const float sc = 0.08838834764831845f;

  float mx[4][4];
  #pragma unroll
  for (int m = 0; m < 4; ++m)
    #pragma unroll
    for (int j = 0; j < 4; ++j) mx[m][j] = -1e30f;

  for (int nt = 0; nt < 8; ++nt) {
    if (nt) __syncthreads();
    for (int i = tid; i < 128 * 16; i += 256) {
      const int r = i >> 4, s = i & 15;
      *(uint4*)&Bs[r][s * 8] = *(const uint4*)&Bg[(size_t)(nt * 128 + r) * DM + s * 8];
    }
    __syncthreads();

    f32x4 acc[4][4];
    const f32x4 zero4 = {0.f, 0.f, 0.f, 0.f};
    #pragma unroll
    for (int m = 0; m < 4; ++m)
      #pragma unroll
      for (int n = 0; n < 4; ++n) acc[m][n] = zero4;
    #pragma unroll
    for (int ks = 0; ks < 4; ++ks) {
      bf16x8 av[4], bv_[4];
      #pragma unroll
      for (int m = 0; m < 4; ++m)
        av[m] = *(const bf16x8*)&As[wr + m * 16 + fr][ks * 32 + fk];
      #pragma unroll
      for (int n = 0; n < 4; ++n)
        bv_[n] = *(const bf16x8*)&Bs[wc + n * 16 + fr][ks * 32 + fk];
      #pragma unroll
      for (int m = 0; m < 4; ++m)
        #pragma unroll
        for (int n = 0; n < 4; ++n)
          acc[m][n] = __builtin_amdgcn_mfma_f32_16x16x32_bf16(av[m], bv_[n], acc[m][n], 0, 0, 0);
    }
    #pragma unroll
    for (int m = 0; m < 4; ++m) {
      #pragma unroll
      for (int n = 0; n < 4; ++n) {
        const int gm = m0 + wr + m * 16 + crow;
        const int gn = nt * 128 + wc + n * 16 + fr;
        #pragma unroll
        for (int j = 0; j < 4; ++j) {
          const float vv = acc[m][n][j] * sc;
          mx[m][j] = fmaxf(mx[m][j], vv);
          Ez[(size_t)(gm + j) * KL + gn] = f2b(vv);
        }
      }
    }
  }

  #pragma unroll
  for (int m = 0; m < 4; ++m)
    #pragma unroll
    for (int j = 0; j < 4; ++j) {
      #pragma unroll
      for (int off = 1; off < 16; off <<= 1)
        mx[m][j] = fmaxf(mx[m][j], __shfl_xor(mx[m][j], off));
    }
  if ((lane & 15) == 0) {
    #pragma unroll
    for (int m = 0; m < 4; ++m)
      #pragma unroll
      for (int j = 0; j < 4; ++j)
        rmx[wv_ & 1][wr + m * 16 + crow + j] = mx[m][j];
  }
  __syncthreads();
  if (tid < 128)
    MS[2 * ((size_t)z * QL + m0 + tid)] = fmaxf(rmx[0][tid], rmx[1][tid]);
}

// ---------------- per (z,qc): softmax denominators + column-max partials, one E read ----------
__global__ __launch_bounds__(1024) void colsum_colmax(
    const u16* __restrict__ E, float* __restrict__ MS, float* __restrict__ cpart)
{
  const int z = blockIdx.x, qc = blockIdx.y, kk = threadIdx.x;
  __shared__ float mq[64], wsum[64][17], invs[64];
  if (kk < 64) mq[kk] = MS[2 * ((size_t)z * QL + qc * 64 + kk)];
  __syncthreads();
  const u16* base = E + ((size_t)z * QL + qc * 64) * KL + kk;
  float ex[64];
  #pragma unroll
  for (int qq = 0; qq < 64; ++qq)
    ex[qq] = expf(b2f(base[(size_t)qq * KL]) - mq[qq]);
  const int wid = kk >> 6, lane = kk & 63;
  #pragma unroll
  for (int qq = 0; qq < 64; ++qq) {
    float s = ex[qq];
    #pragma unroll
    for (int off = 1; off < 64; off <<= 1) s += __shfl_xor(s, off);
    if (lane == 0) wsum[qq][wid] = s;
  }
  __syncthreads();
  if (kk < 64) {
    float s = 0.f;
    #pragma unroll
    for (int w = 0; w < 16; ++w) s += wsum[kk][w];
    const float inv = 1.f / s;
    invs[kk] = inv;
    MS[2 * ((size_t)z * QL + qc * 64 + kk) + 1] = inv;
  }
  __syncthreads();
  float cm = 0.f;
  #pragma unroll
  for (int qq = 0; qq < 64; ++qq) cm = fmaxf(cm, ex[qq] * invs[qq]);
  cpart[((size_t)z * 8 + qc) * KL + kk] = cm;
}

// ---------------- fr per (h,b): sum_k max over 8 q-chunks ----------------
__global__ __launch_bounds__(256) void head_fr(const float* __restrict__ cpart,
                                               float* __restrict__ frr) {
  const int z = blockIdx.x, tid = threadIdx.x;
  float s = 0.f;
  for (int k = tid; k < KL; k += 256) {
    float m = 0.f;
    #pragma unroll
    for (int c = 0; c < 8; ++c) m = fmaxf(m, cpart[((size_t)z * 8 + c) * KL + k]);
    s += m;
  }
  #pragma unroll
  for (int off = 32; off; off >>= 1) s += __shfl_xor(s, off);
  __shared__ float red[4];
  if ((tid & 63) == 0) red[tid >> 6] = s;
  __syncthreads();
  if (tid == 0) frr[z] = red[0] + red[1] + red[2] + red[3];
}

// ---------------- head select ----------------
__global__ void select_head(const float* __restrict__ frr, const int* __restrict__ mel,
                            int* __restrict__ hidx, float* __restrict__ fr_out) {
  __shared__ float bf[16];
  const int b = threadIdx.x;
  if (b < 16) {
    float best = -1e30f; int bh = 0;
    for (int h = 0; h < NH; ++h) {
      float fr = frr[h * 16 + b] / (float)mel[b];
      if (fr > best) { best = fr; bh = h; }
    }
    hidx[b] = bh;
    bf[b] = best;
  }
  __syncthreads();
  if (threadIdx.x == 0) {
    float s = 0.f;
    for (int i = 0; i < 16; ++i) s += bf[i];
    *fr_out = s / 16.f;
  }
}

// ---------------- gather selected head: alpha -> d_out; sigmoid(alpha)^T -> pT ----------------
__global__ __launch_bounds__(256) void gather_fused(
    const u16* __restrict__ E, const float* __restrict__ ms,
    const int* __restrict__ hidx, float* __restrict__ afc, float* __restrict__ pT)
{
  __shared__ float tile[32][33];
  const int b = blockIdx.z, k0 = blockIdx.x * 32, q0 = blockIdx.y * 32;
  const int hb = hidx[b];
  const u16* src = E + (size_t)(hb * 16 + b) * QL * KL;
  const float* msb = ms + 2 * ((size_t)(hb * 16 + b) * QL + q0);
  const int tx = threadIdx.x, ty = threadIdx.y;
  #pragma unroll
  for (int yy = 0; yy < 4; ++yy) {
    int r = ty + 8 * yy;
    float m = msb[2 * r], inv = msb[2 * r + 1];
    float v = expf(b2f(src[(size_t)(q0 + r) * KL + k0 + tx]) - m) * inv;
    afc[((size_t)b * QL + q0 + r) * KL + k0 + tx] = v;
    tile[r][tx] = v;
  }
  __syncthreads();
  #pragma unroll
  for (int yy = 0; yy < 4; ++yy) {
    int c = ty + 8 * yy;
    float v = tile[tx][c];
    pT[((size_t)b * KL + k0 + c) * QL + q0 + tx] = 1.f / (1.f + expf(-v));
  }
}

// ---------------- wave-per-batch monotonic scan, f32 out, single shfl/step ----------------
#define DPF 16
__global__ __launch_bounds__(64) void smma_scan_wave(const float* __restrict__ pT,
                                                     float* __restrict__ ame) {
  const int b = blockIdx.x, lane = threadIdx.x;
  const float* P = pT + (size_t)b * KL * QL + lane * 8;
  float* outp = ame + (size_t)b * KL * QL + lane * 8;
  float aw[8];
  #pragma unroll
  for (int i = 0; i < 8; ++i) aw[i] = 0.f;
  if (lane == 0) aw[0] = 1.f;
  float4 pa[DPF], pb[DPF];
  #pragma unroll
  for (int j = 0; j < DPF; ++j) {
    pa[j] = *(const float4*)(P + (size_t)j * QL);
    pb[j] = *(const float4*)(P + (size_t)j * QL + 4);
  }
  for (int kb = 0; kb < KL; kb += DPF) {
    #pragma unroll
    for (int j = 0; j < DPF; ++j) {
      float p[8] = {pa[j].x, pa[j].y, pa[j].z, pa[j].w,
                    pb[j].x, pb[j].y, pb[j].z, pb[j].w};
      pa[j] = *(const float4*)(P + (size_t)(kb + DPF + j) * QL);
      pb[j] = *(const float4*)(P + (size_t)(kb + DPF + j) * QL + 4);
      float tmp[8], c[8];
      #pragma unroll
      for (int i = 0; i < 8; ++i) { tmp[i] = aw[i] * p[i]; c[i] = aw[i] - tmp[i]; }
      float cL = __shfl_up(c[7], 1);
      aw[0] = tmp[0] + (lane ? cL : 0.f);
      #pragma unroll
      for (int i = 1; i < 8; ++i) aw[i] = tmp[i] + c[i - 1];
      *(float4*)(outp + (size_t)(kb + j) * QL) = make_float4(aw[0], aw[1], aw[2], aw[3]);
      *(float4*)(outp + (size_t)(kb + j) * QL + 4) = make_float4(aw[4], aw[5], aw[6], aw[7]);
    }
  }
}

// ---------------- transpose + convert: f32 [R][C] -> bf16 [C][R] ----------------
__global__ __launch_bounds__(256) void transpose_cvt(
    const float* __restrict__ src, u16* __restrict__ dst, int R, int C) {
  __shared__ float tile[64][65];
  src += (size_t)blockIdx.z * R * C;
  dst += (size_t)blockIdx.z * R * C;
  const int r0 = blockIdx.x * 64, c0 = blockIdx.y * 64;
  {
    const int rr = threadIdx.x >> 4, cc = (threadIdx.x & 15) * 4;
    #pragma unroll
    for (int p = 0; p < 4; ++p) {
      float4 v = *(const float4*)&src[(size_t)(r0 + rr + p * 16) * C + c0 + cc];
      tile[rr + p * 16][cc] = v.x; tile[rr + p * 16][cc + 1] = v.y;
      tile[rr + p * 16][cc + 2] = v.z; tile[rr + p * 16][cc + 3] = v.w;
    }
  }
  __syncthreads();
  {
    const int oc = threadIdx.x >> 2, r8 = (threadIdx.x & 3) * 16;
    #pragma unroll
    for (int p = 0; p < 2; ++p) {
      union { u16 h[8]; uint4 u; } o;
      #pragma unroll
      for (int j = 0; j < 8; ++j) o.h[j] = f2b(tile[r8 + p * 8 + j][oc]);
      *(uint4*)&dst[(size_t)(c0 + oc) * R + r0 + r8 + p * 8] = o.u;
    }
  }
}

// ---------------- batched bf16 transpose: dst[c][r] = src[r][c] ----------------
__global__ __launch_bounds__(256) void transpose_bf16(
    const u16* __restrict__ src, u16* __restrict__ dst, int R, int C, long sz)
{
  __shared__ __align__(16) u16 tile[64][72];
  src += (size_t)blockIdx.z * sz;
  dst += (size_t)blockIdx.z * sz;
  const int r0 = blockIdx.x * 64, c0 = blockIdx.y * 64;
  {
    const int rr = threadIdx.x >> 3, c8 = (threadIdx.x & 7) * 8;
    #pragma unroll
    for (int p = 0; p < 2; ++p)
      *(uint4*)&tile[rr + p * 32][c8] =
          *(const uint4*)&src[(size_t)(r0 + rr + p * 32) * C + c0 + c8];
  }
  __syncthreads();
  {
    const int cc = threadIdx.x & 31, r8 = (threadIdx.x >> 5) * 8;
    #pragma unroll
    for (int p = 0; p < 2; ++p) {
      union { u16 h[8]; uint4 v; } o;
      #pragma unroll
      for (int j = 0; j < 8; ++j) o.h[j] = tile[r8 + j][cc + p * 32];
      *(uint4*)&dst[(size_t)(c0 + cc + p * 32) * R + r0 + r8] = o.v;
    }
  }
}

// ---------------- universal NT MFMA GEMM ----------------
template <bool OUT_BF16, bool BIAS>
__global__ __launch_bounds__(256) void gemm_nt(
    const u16* __restrict__ Aw, const u16* __restrict__ Bw,
    void* __restrict__ Cptr, const float* __restrict__ bias,
    int lda, int ldb, int ldc, int K, float alpha, int zdiv,
    long sA1, long sA0, long sB1, long sB0, long sC1, long sC0)
{
  __shared__ __align__(16) u16 As[128][72];
  __shared__ __align__(16) u16 Bs[128][72];
  const int tid = threadIdx.x;
  const int z = blockIdx.z;
  const int z1 = z / zdiv, z0 = z % zdiv;
  const int m0 = blockIdx.x * 128, n0 = blockIdx.y * 128;
  const u16* Ab = Aw + z1 * sA1 + z0 * sA0;
  const u16* Bz = Bw + z1 * sB1 + z0 * sB0;

  f32x4 acc[4][4];
  const f32x4 zero4 = {0.f, 0.f, 0.f, 0.f};
  #pragma unroll
  for (int m = 0; m < 4; ++m)
    #pragma unroll
    for (int n = 0; n < 4; ++n) acc[m][n] = zero4;

  const int rs = tid >> 3;
  const int k8 = (tid & 7) * 8;
  const int wv_ = tid >> 6, lane = tid & 63;
  const int wr = (wv_ >> 1) * 64, wc = (wv_ & 1) * 64;
  const int fr = lane & 15, fk = (lane >> 4) * 8;

  for (int k0 = 0; k0 < K; k0 += 64) {
    #pragma unroll
    for (int p = 0; p < 4; ++p)
      *(uint4*)&As[rs + p * 32][k8] =
          *(const uint4*)&Ab[(size_t)(m0 + rs + p * 32) * lda + k0 + k8];
    #pragma unroll
    for (int p = 0; p < 4; ++p)
      *(uint4*)&Bs[rs + p * 32][k8] =
          *(const uint4*)&Bz[(size_t)(n0 + rs + p * 32) * ldb + k0 + k8];
    __syncthreads();
    #pragma unroll
    for (int ks = 0; ks < 2; ++ks) {
      bf16x8 av[4], bv_[4];
      #pragma unroll
      for (int m = 0; m < 4; ++m)
        av[m] = *(const bf16x8*)&As[wr + m * 16 + fr][ks * 32 + fk];
      #pragma unroll
      for (int n = 0; n < 4; ++n)
        bv_[n] = *(const bf16x8*)&Bs[wc + n * 16 + fr][ks * 32 + fk];
      #pragma unroll
      for (int m = 0; m < 4; ++m)
        #pragma unroll
        for (int n = 0; n < 4; ++n)
          acc[m][n] = __builtin_amdgcn_mfma_f32_16x16x32_bf16(av[m], bv_[n], acc[m][n], 0, 0, 0);
    }
    __syncthreads();
  }

  const int crow = (lane >> 4) * 4;
  const long cbase = z1 * sC1 + z0 * sC0;
  #pragma unroll
  for (int m = 0; m < 4; ++m) {
    #pragma unroll
    for (int n = 0; n < 4; ++n) {
      const int gm = m0 + wr + m * 16 + crow;
      const int gn = n0 + wc + n * 16 + fr;
      float bval = 0.f;
      if constexpr (BIAS) bval = bias[gn];
      #pragma unroll
      for (int j = 0; j < 4; ++j) {
        float vv = acc[m][n][j] * alpha + bval;
        if constexpr (OUT_BF16)
          ((u16*)Cptr)[cbase + (size_t)(gm + j) * ldc + gn] = f2b(vv);
        else
          ((float*)Cptr)[cbase + (size_t)(gm + j) * ldc + gn] = vv;
      }
    }
  }
}

extern "C" void kernel_launch(void* const* d_in, const int* in_sizes, int n_in,
                              void* d_out, int out_size, void* d_ws, size_t ws_size,
                              hipStream_t stream) {
  const float* q      = (const float*)d_in[0];
  const float* k      = (const float*)d_in[1];
  const float* v      = (const float*)d_in[2];
  const int*   mel    = (const int*)d_in[3];
  const float* w_qs   = (const float*)d_in[4];
  const float* b_qs   = (const float*)d_in[5];
  const float* w_ks   = (const float*)d_in[6];
  const float* b_ks   = (const float*)d_in[7];
  const float* w_vs   = (const float*)d_in[8];
  const float* b_vs   = (const float*)d_in[9];
  const float* w_last = (const float*)d_in[10];
  const float* b_last = (const float*)d_in[11];

  char* ws = (char*)d_ws;
  float* out = (float*)d_out;

  u16* W2Q = (u16*)(ws + B_W2Q);
  u16* W2K = (u16*)(ws + B_W2K);
  u16* W2V = (u16*)(ws + B_W2V);
  u16* WLB = (u16*)(ws + B_WLB);
  u16* QH  = (u16*)(ws + B_QH);
  u16* KH  = (u16*)(ws + B_KH);
  u16* VH  = (u16*)(ws + B_VH);
  u16* XBQ = (u16*)(ws + B_XBQ);
  u16* XBK = (u16*)(ws + B_XBK);
  u16* XBV = (u16*)(ws + B_XBV);
  u16* E   = (u16*)(ws + B_E);
  float* AME = (float*)(ws + B_AME);
  u16* AMT = (u16*)(ws + B_AMT);
  float* MS = (float*)(ws + B_MS);
  float* CPART = (float*)(ws + B_CPART);
  float* FRR = (float*)(ws + B_FRR);
  int* HIDX = (int*)(ws + B_HIDX);
  float* PT = (float*)(ws + B_PT);
  u16* VHT = (u16*)(ws + B_VHT);
  u16* CVP = (u16*)(ws + B_CVP);

  // 1. weight repacks + input bf16 conversion
  repack_all<<<dim3(2496, 1, 4), 256, 0, stream>>>(w_qs, w_ks, w_vs, w_last,
                                                   W2Q, W2K, W2V, WLB);
  cvt8<<<1536, 256, 0, stream>>>(q, XBQ, 393216);
  cvt8<<<3072, 256, 0, stream>>>(k, XBK, 786432);
  cvt8<<<3072, 256, 0, stream>>>(v, XBV, 786432);

  // 2. grouped convs: x-window LDS-resident
  conv_mfma<<<dim3(128, 1, 9), 256, 0, stream>>>(XBQ, XBK, XBV, W2Q, W2K, W2V,
                                                 b_qs, b_ks, b_vs, QH, KH, VH);

  // 3. e (bf16) + fused row-max
  qk_flash<<<dim3(4, 1, 48), 256, 0, stream>>>(QH, KH, E, MS);

  // 4. softmax denominators + colmax partials (single E read)
  colsum_colmax<<<dim3(48, 8), 1024, 0, stream>>>(E, MS, CPART);

  // 5. fr + head select
  head_fr<<<NH * NB, 256, 0, stream>>>(CPART, FRR);
  select_head<<<1, 64, 0, stream>>>(FRR, mel, HIDX, out + OUT_FR);

  // 6. gather alpha_fc -> d_out, sigmoid -> pT [b][k][q]
  gather_fused<<<dim3(KL / 32, QL / 32, NB), dim3(32, 8), 0, stream>>>(
      E, MS, HIDX, out + OUT_ALPHA, PT);

  // 7. register scan -> ame f32 [b][k][q]  (overwrites dead E-low)
  smma_scan_wave<<<NB, 64, 0, stream>>>(PT, AME);

  // 8. transposes: ame f32 -> amT bf16 [b][q][k]; vh -> vhT [b][d][k]
  transpose_cvt<<<dim3(16, 8, NB), 256, 0, stream>>>(AME, AMT, KL, QL);
  transpose_bf16<<<dim3(16, 6, NB), 256, 0, stream>>>(VH, VHT, KL, DM, 393216);

  // 9. cv_pre[b][q][d] = sum_k amT[q][k] * vhT[d][k]
  gemm_nt<true, false><<<dim3(4, 3, NB), 256, 0, stream>>>(
      AMT, VHT, CVP, nullptr, KL, KL, DM, KL, 1.f, 1,
      524288L, 0, 393216L, 0, 196608L, 0);

  // 10. out = cv_pre @ w_last^T + b_last
  gemm_nt<false, true><<<dim3(64, 3, 1), 256, 0, stream>>>(
      CVP, WLB, out + OUT_CV, b_last, DM, DM, DM, DM, 1.f, 1,
      0, 0, 0, 0, 0, 0);
}

// Round 5
// 359.985 us; speedup vs baseline: 6.2407x; 1.0428x over previous
//
#include <hip/hip_runtime.h>

#define NB 16
#define QL 512
#define KL 1024
#define DM 384
#define NH 3
#define DK 128

typedef unsigned short u16;
typedef __attribute__((ext_vector_type(8))) short bf16x8;
typedef __attribute__((ext_vector_type(4))) float f32x4;

// ---------------- workspace byte offsets ----------------
static const size_t B_W2Q = 0;            // bf16 [384][1664] (granule-swizzled)
static const size_t B_W2K = 1277952;
static const size_t B_W2V = 2555904;
static const size_t B_WLB = 3833856;      // bf16 [384][384]
static const size_t B_QH  = 4128768;      // bf16 [16*512][384]
static const size_t B_KH  = 10420224;     // bf16 [16*1024][384]
static const size_t B_VH  = 23003136;     // bf16 [16*1024][384]
static const size_t B_XBQ = 35586048;     // bf16 q input
static const size_t B_XBK = 41877504;     // bf16 k input
static const size_t B_XBV = 54460416;     // bf16 v input
static const size_t B_E   = 67043328;     // bf16 [48][512][1024]
static const size_t B_AME = 67043328;     // f32 [16][1024][512]  (aliases dead E-low)
static const size_t B_AMT = 100597760;    // bf16 [16][512][1024] (aliases dead E-high)
static const size_t B_MS  = 117374976;    // f32 [48*512][2] {rowmax, inv}
static const size_t B_CPART = 117571584;  // f32 [48][8][1024]
static const size_t B_FRR = 119144448;    // f32 [48]
static const size_t B_HIDX = 119144704;   // int [16]
static const size_t B_PT  = 119144960;    // f32 [16][1024][512] (+64KB slack after)
static const size_t B_VHT = 152764928;    // bf16 [16][384][1024]
static const size_t B_CVP = 165347840;    // bf16 [16][512][384]

// d_out offsets (floats)
static const size_t OUT_CV    = 0;
static const size_t OUT_ALPHA = 3145728;
static const size_t OUT_FR    = 11534336;

__device__ __forceinline__ u16 f2b(float x) {
  union { float f; unsigned u; } q; q.f = x;
  unsigned r = q.u + 0x7fffu + ((q.u >> 16) & 1u);
  return (u16)(r >> 16);
}
__device__ __forceinline__ float b2f(u16 h) {
  union { unsigned u; float f; } q; q.u = ((unsigned)h) << 16;
  return q.f;
}

typedef __attribute__((address_space(3))) void lds_void;
typedef __attribute__((address_space(1))) const void g_void;
__device__ __forceinline__ void gload_lds16(const void* g, void* l) {
  __builtin_amdgcn_global_load_lds((g_void*)g, (lds_void*)l, 16, 0, 0);
}

// ---------------- weight repacks ----------------
// conv w[oc][ic][t] -> bf16 W2[oc][kb*64 + (g^(oc&7))*8 + e]  (k = t*128+ic, granule-swizzled)
// z==3: w_last f32 -> bf16 (plain)
__global__ __launch_bounds__(256) void repack_all(
    const float* __restrict__ wq, const float* __restrict__ wk,
    const float* __restrict__ wv, const float* __restrict__ wl,
    u16* __restrict__ dq, u16* __restrict__ dk, u16* __restrict__ dv,
    u16* __restrict__ dl) {
  const int z = blockIdx.z;
  const int tid = blockIdx.x * 256 + threadIdx.x;
  if (z < 3) {
    if (tid >= 384 * 1664) return;
    const float* src = (z == 0) ? wq : (z == 1) ? wk : wv;
    u16* dst = (z == 0) ? dq : (z == 1) ? dk : dv;
    const int oc = tid / 1664, k = tid % 1664;     // logical k
    const int t = k >> 7, ic = k & 127;
    const int g = (k >> 3) & 7, e = k & 7;
    const int pcol = (k & ~63) + (((g ^ (oc & 7))) << 3) + e;
    dst[(size_t)oc * 1664 + pcol] = f2b(src[(size_t)oc * 1664 + ic * 13 + t]);
  } else {
    if (tid < 384 * 384) dl[tid] = f2b(wl[tid]);
  }
}

// ---------------- f32 -> bf16 convert, all three inputs in one launch ----------------
__global__ __launch_bounds__(256) void cvt8_all(
    const float* __restrict__ q, const float* __restrict__ k, const float* __restrict__ v,
    u16* __restrict__ dq, u16* __restrict__ dk, u16* __restrict__ dv) {
  const int z = blockIdx.z;
  const int n8 = (z == 0) ? 393216 : 786432;
  const int i = blockIdx.x * 256 + threadIdx.x;
  if (i >= n8) return;
  const float* src = (z == 0) ? q : (z == 1) ? k : v;
  u16* dst = (z == 0) ? dq : (z == 1) ? dk : dv;
  const float4 a = *(const float4*)&src[(size_t)i * 8];
  const float4 b = *(const float4*)&src[(size_t)i * 8 + 4];
  union { u16 h[8]; uint4 u; } o;
  o.h[0] = f2b(a.x); o.h[1] = f2b(a.y); o.h[2] = f2b(a.z); o.h[3] = f2b(a.w);
  o.h[4] = f2b(b.x); o.h[5] = f2b(b.y); o.h[6] = f2b(b.z); o.h[7] = f2b(b.w);
  *(uint4*)&dst[(size_t)i * 8] = o.u;
}

// ---------------- grouped conv1d: LDS-resident x-window; Bs via global_load_lds ----------
// z/3 selects tensor (0=q L=512, 1=k, 2=v L=1024); z%3 = group
__global__ __launch_bounds__(256) void conv_mfma(
    const u16* __restrict__ xq, const u16* __restrict__ xk, const u16* __restrict__ xv,
    const u16* __restrict__ wq, const u16* __restrict__ wk, const u16* __restrict__ wv,
    const float* __restrict__ bq, const float* __restrict__ bk, const float* __restrict__ bv,
    u16* __restrict__ oq, u16* __restrict__ ok, u16* __restrict__ ov)
{
  __shared__ __align__(16) u16 xw[140][136];
  __shared__ __align__(16) u16 Bs[128 * 64];    // unpadded, granule-swizzled content
  const int z = blockIdx.z;
  const int which = z / 3, g = z % 3;
  const u16* X; const u16* W; const float* bias; u16* out; int Lmask;
  if (which == 0)      { X = xq; W = wq; bias = bq; out = oq; Lmask = 511; }
  else if (which == 1) { X = xk; W = wk; bias = bk; out = ok; Lmask = 1023; }
  else                 { X = xv; W = wv; bias = bv; out = ov; Lmask = 1023; }
  const int m0 = blockIdx.x * 128;
  if (m0 >= NB * (Lmask + 1)) return;
  X += g * DK; W += (size_t)g * DK * 1664; bias += g * DK; out += g * DK;

  const int tid = threadIdx.x;
  const int l0 = m0 & Lmask, bbase = m0 & ~Lmask;

  // stage the 140-row x-window once (bounds-checked, via VGPRs)
  for (int i = tid; i < 140 * 16; i += 256) {
    const int r = i >> 4, s = i & 15;
    const int l = l0 - 6 + r;
    uint4 v = make_uint4(0, 0, 0, 0);
    if ((unsigned)l <= (unsigned)Lmask)
      v = *(const uint4*)&X[(size_t)(bbase + l) * DM + s * 8];
    *(uint4*)&xw[r][s * 8] = v;
  }

  const int wv_ = tid >> 6, lane = tid & 63;
  const int wr = (wv_ >> 1) * 64, wc = (wv_ & 1) * 64;
  const int fr = lane & 15, fk8 = (lane >> 4);   // fk8 = granule 0..3

  f32x4 acc[4][4];
  const f32x4 zero4 = {0.f, 0.f, 0.f, 0.f};
  #pragma unroll
  for (int m = 0; m < 4; ++m)
    #pragma unroll
    for (int n = 0; n < 4; ++n) acc[m][n] = zero4;

  // per-lane global source offset pattern for Bs staging: rows 8i+(lane>>3), granule lane&7
  const int srow = lane >> 3, sg = lane & 7;

  for (int k0 = 0; k0 < 1664; k0 += 64) {
    __syncthreads();   // prior Bs reads done
    #pragma unroll
    for (int i = 0; i < 4; ++i) {
      const int ii = wv_ + i * 4;   // 0..15, each wave 4 chunks of 1KB
      gload_lds16(&W[(size_t)(8 * ii + srow) * 1664 + k0 + sg * 8],
                  (char*)Bs + ii * 1024);
    }
    __syncthreads();   // compiler drains vmcnt before barrier
    const int t = k0 >> 7;
    const int ic0 = k0 & 64;
    #pragma unroll
    for (int ks = 0; ks < 2; ++ks) {
      bf16x8 av[4], bv_[4];
      #pragma unroll
      for (int m = 0; m < 4; ++m)
        av[m] = *(const bf16x8*)&xw[t + wr + m * 16 + fr][ic0 + ks * 32 + fk8 * 8];
      #pragma unroll
      for (int n = 0; n < 4; ++n) {
        const int r = wc + n * 16 + fr;
        const int pg = (ks * 4 + fk8) ^ (fr & 7);   // phys granule (matches repack swizzle)
        bv_[n] = *(const bf16x8*)&Bs[r * 64 + pg * 8];
      }
      #pragma unroll
      for (int m = 0; m < 4; ++m)
        #pragma unroll
        for (int n = 0; n < 4; ++n)
          acc[m][n] = __builtin_amdgcn_mfma_f32_16x16x32_bf16(av[m], bv_[n], acc[m][n], 0, 0, 0);
    }
  }

  const int crow = (lane >> 4) * 4;
  #pragma unroll
  for (int m = 0; m < 4; ++m) {
    #pragma unroll
    for (int n = 0; n < 4; ++n) {
      const int gm = m0 + wr + m * 16 + crow;
      const int gn = wc + n * 16 + fr;
      const float bval = bias[gn];
      #pragma unroll
      for (int j = 0; j < 4; ++j)
        out[(size_t)(gm + j) * DM + gn] = f2b(acc[m][n][j] + bval);
    }
  }
}

// ---------------- qk: E[z][q][k] = qh.kh/sqrt(128) (bf16 out) + fused row-max ----------------
__global__ __launch_bounds__(256) void qk_flash(
    const u16* __restrict__ QH, const u16* __restrict__ KH,
    u16* __restrict__ E, float* __restrict__ MS)
{
  __shared__ __align__(16) u16 As[128][136];
  __shared__ __align__(16) u16 Bs[128][136];
  __shared__ float rmx[2][128];
  const int tid = threadIdx.x;
  const int z = blockIdx.z, h = z >> 4, b = z & 15;
  const int m0 = blockIdx.x * 128;
  const u16* Ag = QH + ((size_t)b * QL + m0) * DM + h * DK;
  const u16* Bg = KH + (size_t)b * KL * DM + h * DK;
  u16* Ez = E + (size_t)z * QL * KL;

  for (int i = tid; i < 128 * 16; i += 256) {
    const int r = i >> 4, s = i & 15;
    *(uint4*)&As[r][s * 8] = *(const uint4*)&Ag[(size_t)r * DM + s * 8];
  }

  const int wv_ = tid >> 6, lane = tid & 63;
  const int wr = (wv_ >> 1) * 64, wc = (wv_ & 1) * 64;
  const int fr = lane & 15, fk = (lane >> 4) * 8;
  const int crow = (lane >> 4) * 4;
  const float sc = 0.08838834764831845f;

  float mx[4][4];
  #pragma unroll
  for (int m = 0; m < 4; ++m)
    #pragma unroll
    for (int j = 0; j < 4; ++j) mx[m][j] = -1e30f;

  for (int nt = 0; nt < 8; ++nt) {
    if (nt) __syncthreads();
    for (int i = tid; i < 128 * 16; i += 256) {
      const int r = i >> 4, s = i & 15;
      *(uint4*)&Bs[r][s * 8] = *(const uint4*)&Bg[(size_t)(nt * 128 + r) * DM + s * 8];
    }
    __syncthreads();

    f32x4 acc[4][4];
    const f32x4 zero4 = {0.f, 0.f, 0.f, 0.f};
    #pragma unroll
    for (int m = 0; m < 4; ++m)
      #pragma unroll
      for (int n = 0; n < 4; ++n) acc[m][n] = zero4;
    #pragma unroll
    for (int ks = 0; ks < 4; ++ks) {
      bf16x8 av[4], bv_[4];
      #pragma unroll
      for (int m = 0; m < 4; ++m)
        av[m] = *(const bf16x8*)&As[wr + m * 16 + fr][ks * 32 + fk];
      #pragma unroll
      for (int n = 0; n < 4; ++n)
        bv_[n] = *(const bf16x8*)&Bs[wc + n * 16 + fr][ks * 32 + fk];
      #pragma unroll
      for (int m = 0; m < 4; ++m)
        #pragma unroll
        for (int n = 0; n < 4; ++n)
          acc[m][n] = __builtin_amdgcn_mfma_f32_16x16x32_bf16(av[m], bv_[n], acc[m][n], 0, 0, 0);
    }
    #pragma unroll
    for (int m = 0; m < 4; ++m) {
      #pragma unroll
      for (int n = 0; n < 4; ++n) {
        const int gm = m0 + wr + m * 16 + crow;
        const int gn = nt * 128 + wc + n * 16 + fr;
        #pragma unroll
        for (int j = 0; j < 4; ++j) {
          const float vv = acc[m][n][j] * sc;
          mx[m][j] = fmaxf(mx[m][j], vv);
          Ez[(size_t)(gm + j) * KL + gn] = f2b(vv);
        }
      }
    }
  }

  #pragma unroll
  for (int m = 0; m < 4; ++m)
    #pragma unroll
    for (int j = 0; j < 4; ++j) {
      #pragma unroll
      for (int off = 1; off < 16; off <<= 1)
        mx[m][j] = fmaxf(mx[m][j], __shfl_xor(mx[m][j], off));
    }
  if ((lane & 15) == 0) {
    #pragma unroll
    for (int m = 0; m < 4; ++m)
      #pragma unroll
      for (int j = 0; j < 4; ++j)
        rmx[wv_ & 1][wr + m * 16 + crow + j] = mx[m][j];
  }
  __syncthreads();
  if (tid < 128)
    MS[2 * ((size_t)z * QL + m0 + tid)] = fmaxf(rmx[0][tid], rmx[1][tid]);
}

// ---------------- per (z,qc): softmax denominators + column-max partials ----------
__global__ __launch_bounds__(1024) void colsum_colmax(
    const u16* __restrict__ E, float* __restrict__ MS, float* __restrict__ cpart)
{
  const int z = blockIdx.x, qc = blockIdx.y, kk = threadIdx.x;
  __shared__ float mq[64], wsum[64][17], invs[64];
  if (kk < 64) mq[kk] = MS[2 * ((size_t)z * QL + qc * 64 + kk)];
  __syncthreads();
  const u16* base = E + ((size_t)z * QL + qc * 64) * KL + kk;
  float ex[64];
  #pragma unroll
  for (int qq = 0; qq < 64; ++qq)
    ex[qq] = expf(b2f(base[(size_t)qq * KL]) - mq[qq]);
  const int wid = kk >> 6, lane = kk & 63;
  #pragma unroll
  for (int qq = 0; qq < 64; ++qq) {
    float s = ex[qq];
    #pragma unroll
    for (int off = 1; off < 64; off <<= 1) s += __shfl_xor(s, off);
    if (lane == 0) wsum[qq][wid] = s;
  }
  __syncthreads();
  if (kk < 64) {
    float s = 0.f;
    #pragma unroll
    for (int w = 0; w < 16; ++w) s += wsum[kk][w];
    const float inv = 1.f / s;
    invs[kk] = inv;
    MS[2 * ((size_t)z * QL + qc * 64 + kk) + 1] = inv;
  }
  __syncthreads();
  float cm = 0.f;
  #pragma unroll
  for (int qq = 0; qq < 64; ++qq) cm = fmaxf(cm, ex[qq] * invs[qq]);
  cpart[((size_t)z * 8 + qc) * KL + kk] = cm;
}

// ---------------- fr per (h,b): sum_k max over 8 q-chunks ----------------
__global__ __launch_bounds__(256) void head_fr(const float* __restrict__ cpart,
                                               float* __restrict__ frr) {
  const int z = blockIdx.x, tid = threadIdx.x;
  float s = 0.f;
  for (int k = tid; k < KL; k += 256) {
    float m = 0.f;
    #pragma unroll
    for (int c = 0; c < 8; ++c) m = fmaxf(m, cpart[((size_t)z * 8 + c) * KL + k]);
    s += m;
  }
  #pragma unroll
  for (int off = 32; off; off >>= 1) s += __shfl_xor(s, off);
  __shared__ float red[4];
  if ((tid & 63) == 0) red[tid >> 6] = s;
  __syncthreads();
  if (tid == 0) frr[z] = red[0] + red[1] + red[2] + red[3];
}

// ---------------- head select ----------------
__global__ void select_head(const float* __restrict__ frr, const int* __restrict__ mel,
                            int* __restrict__ hidx, float* __restrict__ fr_out) {
  __shared__ float bf[16];
  const int b = threadIdx.x;
  if (b < 16) {
    float best = -1e30f; int bh = 0;
    for (int h = 0; h < NH; ++h) {
      float fr = frr[h * 16 + b] / (float)mel[b];
      if (fr > best) { best = fr; bh = h; }
    }
    hidx[b] = bh;
    bf[b] = best;
  }
  __syncthreads();
  if (threadIdx.x == 0) {
    float s = 0.f;
    for (int i = 0; i < 16; ++i) s += bf[i];
    *fr_out = s / 16.f;
  }
}

// ---------------- gather selected head: alpha -> d_out; sigmoid(alpha)^T -> pT ----------------
__global__ __launch_bounds__(256) void gather_fused(
    const u16* __restrict__ E, const float* __restrict__ ms,
    const int* __restrict__ hidx, float* __restrict__ afc, float* __restrict__ pT)
{
  __shared__ float tile[32][33];
  const int b = blockIdx.z, k0 = blockIdx.x * 32, q0 = blockIdx.y * 32;
  const int hb = hidx[b];
  const u16* src = E + (size_t)(hb * 16 + b) * QL * KL;
  const float* msb = ms + 2 * ((size_t)(hb * 16 + b) * QL + q0);
  const int tx = threadIdx.x, ty = threadIdx.y;
  #pragma unroll
  for (int yy = 0; yy < 4; ++yy) {
    int r = ty + 8 * yy;
    float m = msb[2 * r], inv = msb[2 * r + 1];
    float v = expf(b2f(src[(size_t)(q0 + r) * KL + k0 + tx]) - m) * inv;
    afc[((size_t)b * QL + q0 + r) * KL + k0 + tx] = v;
    tile[r][tx] = v;
  }
  __syncthreads();
  #pragma unroll
  for (int yy = 0; yy < 4; ++yy) {
    int c = ty + 8 * yy;
    float v = tile[tx][c];
    pT[((size_t)b * KL + k0 + c) * QL + q0 + tx] = 1.f / (1.f + expf(-v));
  }
}

// ---------------- wave-per-batch monotonic scan: 16-step double-buffered register chunks ----
#define LDP0(ROW) (*(const float4*)(P + (size_t)(ROW) * QL))
#define LDP1(ROW) (*(const float4*)(P + (size_t)(ROW) * QL + 4))
#define SCAN_STEP(V0, V1, ROW)                                                  \
  {                                                                             \
    float pp[8] = {(V0).x, (V0).y, (V0).z, (V0).w,                              \
                   (V1).x, (V1).y, (V1).z, (V1).w};                             \
    float tmp[8], cc[8];                                                        \
    _Pragma("unroll") for (int i = 0; i < 8; ++i) {                             \
      tmp[i] = aw[i] * pp[i]; cc[i] = aw[i] - tmp[i];                           \
    }                                                                           \
    float cL = __shfl_up(cc[7], 1);                                             \
    aw[0] = tmp[0] + cL * m0f;                                                  \
    _Pragma("unroll") for (int i = 1; i < 8; ++i) aw[i] = tmp[i] + cc[i - 1];   \
    *(float4*)(outp + (size_t)(ROW) * QL) = make_float4(aw[0], aw[1], aw[2], aw[3]); \
    *(float4*)(outp + (size_t)(ROW) * QL + 4) = make_float4(aw[4], aw[5], aw[6], aw[7]); \
  }

__global__ __launch_bounds__(64, 1) void smma_scan_wave(const float* __restrict__ pT,
                                                        float* __restrict__ ame) {
  const int b = blockIdx.x, lane = threadIdx.x;
  const float* P = pT + (size_t)b * KL * QL + lane * 8;
  float* outp = ame + (size_t)b * KL * QL + lane * 8;
  const float m0f = (lane == 0) ? 0.f : 1.f;
  float aw[8];
  #pragma unroll
  for (int i = 0; i < 8; ++i) aw[i] = 0.f;
  if (lane == 0) aw[0] = 1.f;

  float4 A0[16], A1[16], B0[16], B1[16];
  #pragma unroll
  for (int j = 0; j < 16; ++j) { A0[j] = LDP0(j); A1[j] = LDP1(j); }

  for (int kb = 0; kb < KL; kb += 32) {
    #pragma unroll
    for (int j = 0; j < 16; ++j) { B0[j] = LDP0(kb + 16 + j); B1[j] = LDP1(kb + 16 + j); }
    #pragma unroll
    for (int j = 0; j < 16; ++j) SCAN_STEP(A0[j], A1[j], kb + j);
    #pragma unroll
    for (int j = 0; j < 16; ++j) { A0[j] = LDP0(kb + 32 + j); A1[j] = LDP1(kb + 32 + j); }
    #pragma unroll
    for (int j = 0; j < 16; ++j) SCAN_STEP(B0[j], B1[j], kb + 16 + j);
  }
}

// ---------------- transpose + convert: f32 [R][C] -> bf16 [C][R] ----------------
__global__ __launch_bounds__(256) void transpose_cvt(
    const float* __restrict__ src, u16* __restrict__ dst, int R, int C) {
  __shared__ float tile[64][65];
  src += (size_t)blockIdx.z * R * C;
  dst += (size_t)blockIdx.z * R * C;
  const int r0 = blockIdx.x * 64, c0 = blockIdx.y * 64;
  {
    const int rr = threadIdx.x >> 4, cc = (threadIdx.x & 15) * 4;
    #pragma unroll
    for (int p = 0; p < 4; ++p) {
      float4 v = *(const float4*)&src[(size_t)(r0 + rr + p * 16) * C + c0 + cc];
      tile[rr + p * 16][cc] = v.x; tile[rr + p * 16][cc + 1] = v.y;
      tile[rr + p * 16][cc + 2] = v.z; tile[rr + p * 16][cc + 3] = v.w;
    }
  }
  __syncthreads();
  {
    const int oc = threadIdx.x >> 2, r8 = (threadIdx.x & 3) * 16;
    #pragma unroll
    for (int p = 0; p < 2; ++p) {
      union { u16 h[8]; uint4 u; } o;
      #pragma unroll
      for (int j = 0; j < 8; ++j) o.h[j] = f2b(tile[r8 + p * 8 + j][oc]);
      *(uint4*)&dst[(size_t)(c0 + oc) * R + r0 + r8 + p * 8] = o.u;
    }
  }
}

// ---------------- batched bf16 transpose: dst[c][r] = src[r][c] ----------------
__global__ __launch_bounds__(256) void transpose_bf16(
    const u16* __restrict__ src, u16* __restrict__ dst, int R, int C, long sz)
{
  __shared__ __align__(16) u16 tile[64][72];
  src += (size_t)blockIdx.z * sz;
  dst += (size_t)blockIdx.z * sz;
  const int r0 = blockIdx.x * 64, c0 = blockIdx.y * 64;
  {
    const int rr = threadIdx.x >> 3, c8 = (threadIdx.x & 7) * 8;
    #pragma unroll
    for (int p = 0; p < 2; ++p)
      *(uint4*)&tile[rr + p * 32][c8] =
          *(const uint4*)&src[(size_t)(r0 + rr + p * 32) * C + c0 + c8];
  }
  __syncthreads();
  {
    const int cc = threadIdx.x & 31, r8 = (threadIdx.x >> 5) * 8;
    #pragma unroll
    for (int p = 0; p < 2; ++p) {
      union { u16 h[8]; uint4 v; } o;
      #pragma unroll
      for (int j = 0; j < 8; ++j) o.h[j] = tile[r8 + j][cc + p * 32];
      *(uint4*)&dst[(size_t)(c0 + cc + p * 32) * R + r0 + r8] = o.v;
    }
  }
}

// ---------------- universal NT MFMA GEMM ----------------
template <bool OUT_BF16, bool BIAS>
__global__ __launch_bounds__(256) void gemm_nt(
    const u16* __restrict__ Aw, const u16* __restrict__ Bw,
    void* __restrict__ Cptr, const float* __restrict__ bias,
    int lda, int ldb, int ldc, int K, float alpha, int zdiv,
    long sA1, long sA0, long sB1, long sB0, long sC1, long sC0)
{
  __shared__ __align__(16) u16 As[128][72];
  __shared__ __align__(16) u16 Bs[128][72];
  const int tid = threadIdx.x;
  const int z = blockIdx.z;
  const int z1 = z / zdiv, z0 = z % zdiv;
  const int m0 = blockIdx.x * 128, n0 = blockIdx.y * 128;
  const u16* Ab = Aw + z1 * sA1 + z0 * sA0;
  const u16* Bz = Bw + z1 * sB1 + z0 * sB0;

  f32x4 acc[4][4];
  const f32x4 zero4 = {0.f, 0.f, 0.f, 0.f};
  #pragma unroll
  for (int m = 0; m < 4; ++m)
    #pragma unroll
    for (int n = 0; n < 4; ++n) acc[m][n] = zero4;

  const int rs = tid >> 3;
  const int k8 = (tid & 7) * 8;
  const int wv_ = tid >> 6, lane = tid & 63;
  const int wr = (wv_ >> 1) * 64, wc = (wv_ & 1) * 64;
  const int fr = lane & 15, fk = (lane >> 4) * 8;

  for (int k0 = 0; k0 < K; k0 += 64) {
    #pragma unroll
    for (int p = 0; p < 4; ++p)
      *(uint4*)&As[rs + p * 32][k8] =
          *(const uint4*)&Ab[(size_t)(m0 + rs + p * 32) * lda + k0 + k8];
    #pragma unroll
    for (int p = 0; p < 4; ++p)
      *(uint4*)&Bs[rs + p * 32][k8] =
          *(const uint4*)&Bz[(size_t)(n0 + rs + p * 32) * ldb + k0 + k8];
    __syncthreads();
    #pragma unroll
    for (int ks = 0; ks < 2; ++ks) {
      bf16x8 av[4], bv_[4];
      #pragma unroll
      for (int m = 0; m < 4; ++m)
        av[m] = *(const bf16x8*)&As[wr + m * 16 + fr][ks * 32 + fk];
      #pragma unroll
      for (int n = 0; n < 4; ++n)
        bv_[n] = *(const bf16x8*)&Bs[wc + n * 16 + fr][ks * 32 + fk];
      #pragma unroll
      for (int m = 0; m < 4; ++m)
        #pragma unroll
        for (int n = 0; n < 4; ++n)
          acc[m][n] = __builtin_amdgcn_mfma_f32_16x16x32_bf16(av[m], bv_[n], acc[m][n], 0, 0, 0);
    }
    __syncthreads();
  }

  const int crow = (lane >> 4) * 4;
  const long cbase = z1 * sC1 + z0 * sC0;
  #pragma unroll
  for (int m = 0; m < 4; ++m) {
    #pragma unroll
    for (int n = 0; n < 4; ++n) {
      const int gm = m0 + wr + m * 16 + crow;
      const int gn = n0 + wc + n * 16 + fr;
      float bval = 0.f;
      if constexpr (BIAS) bval = bias[gn];
      #pragma unroll
      for (int j = 0; j < 4; ++j) {
        float vv = acc[m][n][j] * alpha + bval;
        if constexpr (OUT_BF16)
          ((u16*)Cptr)[cbase + (size_t)(gm + j) * ldc + gn] = f2b(vv);
        else
          ((float*)Cptr)[cbase + (size_t)(gm + j) * ldc + gn] = vv;
      }
    }
  }
}

extern "C" void kernel_launch(void* const* d_in, const int* in_sizes, int n_in,
                              void* d_out, int out_size, void* d_ws, size_t ws_size,
                              hipStream_t stream) {
  const float* q      = (const float*)d_in[0];
  const float* k      = (const float*)d_in[1];
  const float* v      = (const float*)d_in[2];
  const int*   mel    = (const int*)d_in[3];
  const float* w_qs   = (const float*)d_in[4];
  const float* b_qs   = (const float*)d_in[5];
  const float* w_ks   = (const float*)d_in[6];
  const float* b_ks   = (const float*)d_in[7];
  const float* w_vs   = (const float*)d_in[8];
  const float* b_vs   = (const float*)d_in[9];
  const float* w_last = (const float*)d_in[10];
  const float* b_last = (const float*)d_in[11];

  char* ws = (char*)d_ws;
  float* out = (float*)d_out;

  u16* W2Q = (u16*)(ws + B_W2Q);
  u16* W2K = (u16*)(ws + B_W2K);
  u16* W2V = (u16*)(ws + B_W2V);
  u16* WLB = (u16*)(ws + B_WLB);
  u16* QH  = (u16*)(ws + B_QH);
  u16* KH  = (u16*)(ws + B_KH);
  u16* VH  = (u16*)(ws + B_VH);
  u16* XBQ = (u16*)(ws + B_XBQ);
  u16* XBK = (u16*)(ws + B_XBK);
  u16* XBV = (u16*)(ws + B_XBV);
  u16* E   = (u16*)(ws + B_E);
  float* AME = (float*)(ws + B_AME);
  u16* AMT = (u16*)(ws + B_AMT);
  float* MS = (float*)(ws + B_MS);
  float* CPART = (float*)(ws + B_CPART);
  float* FRR = (float*)(ws + B_FRR);
  int* HIDX = (int*)(ws + B_HIDX);
  float* PT = (float*)(ws + B_PT);
  u16* VHT = (u16*)(ws + B_VHT);
  u16* CVP = (u16*)(ws + B_CVP);

  // 1. weight repacks (swizzled) + input bf16 conversion (one launch)
  repack_all<<<dim3(2496, 1, 4), 256, 0, stream>>>(w_qs, w_ks, w_vs, w_last,
                                                   W2Q, W2K, W2V, WLB);
  cvt8_all<<<dim3(3072, 1, 3), 256, 0, stream>>>(q, k, v, XBQ, XBK, XBV);

  // 2. grouped convs: x-window LDS-resident, Bs via global_load_lds
  conv_mfma<<<dim3(128, 1, 9), 256, 0, stream>>>(XBQ, XBK, XBV, W2Q, W2K, W2V,
                                                 b_qs, b_ks, b_vs, QH, KH, VH);

  // 3. e (bf16) + fused row-max
  qk_flash<<<dim3(4, 1, 48), 256, 0, stream>>>(QH, KH, E, MS);

  // 4. softmax denominators + colmax partials (single E read)
  colsum_colmax<<<dim3(48, 8), 1024, 0, stream>>>(E, MS, CPART);

  // 5. fr + head select
  head_fr<<<NH * NB, 256, 0, stream>>>(CPART, FRR);
  select_head<<<1, 64, 0, stream>>>(FRR, mel, HIDX, out + OUT_FR);

  // 6. gather alpha_fc -> d_out, sigmoid -> pT [b][k][q]
  gather_fused<<<dim3(KL / 32, QL / 32, NB), dim3(32, 8), 0, stream>>>(
      E, MS, HIDX, out + OUT_ALPHA, PT);

  // 7. register scan -> ame f32 [b][k][q]  (overwrites dead E-low)
  smma_scan_wave<<<NB, 64, 0, stream>>>(PT, AME);

  // 8. transposes: ame f32 -> amT bf16 [b][q][k]; vh -> vhT [b][d][k]
  transpose_cvt<<<dim3(16, 8, NB), 256, 0, stream>>>(AME, AMT, KL, QL);
  transpose_bf16<<<dim3(16, 6, NB), 256, 0, stream>>>(VH, VHT, KL, DM, 393216);

  // 9. cv_pre[b][q][d] = sum_k amT[q][k] * vhT[d][k]
  gemm_nt<true, false><<<dim3(4, 3, NB), 256, 0, stream>>>(
      AMT, VHT, CVP, nullptr, KL, KL, DM, KL, 1.f, 1,
      524288L, 0, 393216L, 0, 196608L, 0);

  // 10. out = cv_pre @ w_last^T + b_last
  gemm_nt<false, true><<<dim3(64, 3, 1), 256, 0, stream>>>(
      CVP, WLB, out + OUT_CV, b_last, DM, DM, DM, DM, 1.f, 1,
      0, 0, 0, 0, 0, 0);
}

// Round 7
// 323.476 us; speedup vs baseline: 6.9450x; 1.1129x over previous
//
#include <hip/hip_runtime.h>

#define NB 16
#define QL 512
#define KL 1024
#define DM 384
#define NH 3
#define DK 128

typedef unsigned short u16;
typedef __attribute__((ext_vector_type(8))) short bf16x8;
typedef __attribute__((ext_vector_type(4))) float f32x4;

// ---------------- workspace byte offsets ----------------
static const size_t B_W2Q = 0;            // bf16 [384][1664] (granule-swizzled)
static const size_t B_W2K = 1277952;
static const size_t B_W2V = 2555904;
static const size_t B_WLB = 3833856;      // bf16 [384][384]
static const size_t B_QH  = 4128768;      // bf16 [16*512][384]
static const size_t B_KH  = 10420224;     // bf16 [16*1024][384]
static const size_t B_VH  = 23003136;     // bf16 [16*1024][384]
static const size_t B_XBQ = 35586048;     // bf16 q input
static const size_t B_XBK = 41877504;     // bf16 k input
static const size_t B_XBV = 54460416;     // bf16 v input
static const size_t B_E   = 67043328;     // bf16 [48][512][1024]
static const size_t B_AME = 67043328;     // f32 [16][1024][512]  (aliases dead E-low)
static const size_t B_AMT = 100597760;    // bf16 [16][512][1024] (aliases dead E-high)
static const size_t B_MS  = 117374976;    // f32 [48*512][2] {rowmax, inv}
static const size_t B_CPART = 117571584;  // f32 [48][8][1024]
static const size_t B_FRR = 119144448;    // f32 [48]
static const size_t B_HIDX = 119144704;   // int [16]
static const size_t B_PT  = 119144960;    // f32 [16][1024][512] (+64KB slack after)
static const size_t B_VHT = 152764928;    // bf16 [16][384][1024]
static const size_t B_CVP = 165347840;    // bf16 [16][512][384]

// d_out offsets (floats)
static const size_t OUT_CV    = 0;
static const size_t OUT_ALPHA = 3145728;
static const size_t OUT_FR    = 11534336;

__device__ __forceinline__ u16 f2b(float x) {
  union { float f; unsigned u; } q; q.f = x;
  unsigned r = q.u + 0x7fffu + ((q.u >> 16) & 1u);
  return (u16)(r >> 16);
}
__device__ __forceinline__ float b2f(u16 h) {
  union { unsigned u; float f; } q; q.u = ((unsigned)h) << 16;
  return q.f;
}

typedef __attribute__((address_space(3))) void lds_void;
typedef __attribute__((address_space(1))) const void g_void;
__device__ __forceinline__ void gload_lds16(const void* g, void* l) {
  __builtin_amdgcn_global_load_lds((g_void*)g, (lds_void*)l, 16, 0, 0);
}

// ---------------- weight repacks ----------------
__global__ __launch_bounds__(256) void repack_all(
    const float* __restrict__ wq, const float* __restrict__ wk,
    const float* __restrict__ wv, const float* __restrict__ wl,
    u16* __restrict__ dq, u16* __restrict__ dk, u16* __restrict__ dv,
    u16* __restrict__ dl) {
  const int z = blockIdx.z;
  const int tid = blockIdx.x * 256 + threadIdx.x;
  if (z < 3) {
    if (tid >= 384 * 1664) return;
    const float* src = (z == 0) ? wq : (z == 1) ? wk : wv;
    u16* dst = (z == 0) ? dq : (z == 1) ? dk : dv;
    const int oc = tid / 1664, k = tid % 1664;     // logical k
    const int t = k >> 7, ic = k & 127;
    const int g = (k >> 3) & 7, e = k & 7;
    const int pcol = (k & ~63) + (((g ^ (oc & 7))) << 3) + e;
    dst[(size_t)oc * 1664 + pcol] = f2b(src[(size_t)oc * 1664 + ic * 13 + t]);
  } else {
    if (tid < 384 * 384) dl[tid] = f2b(wl[tid]);
  }
}

// ---------------- f32 -> bf16 convert, all three inputs in one launch ----------------
__global__ __launch_bounds__(256) void cvt8_all(
    const float* __restrict__ q, const float* __restrict__ k, const float* __restrict__ v,
    u16* __restrict__ dq, u16* __restrict__ dk, u16* __restrict__ dv) {
  const int z = blockIdx.z;
  const int n8 = (z == 0) ? 393216 : 786432;
  const int i = blockIdx.x * 256 + threadIdx.x;
  if (i >= n8) return;
  const float* src = (z == 0) ? q : (z == 1) ? k : v;
  u16* dst = (z == 0) ? dq : (z == 1) ? dk : dv;
  const float4 a = *(const float4*)&src[(size_t)i * 8];
  const float4 b = *(const float4*)&src[(size_t)i * 8 + 4];
  union { u16 h[8]; uint4 u; } o;
  o.h[0] = f2b(a.x); o.h[1] = f2b(a.y); o.h[2] = f2b(a.z); o.h[3] = f2b(a.w);
  o.h[4] = f2b(b.x); o.h[5] = f2b(b.y); o.h[6] = f2b(b.z); o.h[7] = f2b(b.w);
  *(uint4*)&dst[(size_t)i * 8] = o.u;
}

// ---------------- grouped conv1d: LDS-resident x-window; Bs via global_load_lds ----------
__global__ __launch_bounds__(256) void conv_mfma(
    const u16* __restrict__ xq, const u16* __restrict__ xk, const u16* __restrict__ xv,
    const u16* __restrict__ wq, const u16* __restrict__ wk, const u16* __restrict__ wv,
    const float* __restrict__ bq, const float* __restrict__ bk, const float* __restrict__ bv,
    u16* __restrict__ oq, u16* __restrict__ ok, u16* __restrict__ ov)
{
  __shared__ __align__(16) u16 xw[140][136];
  __shared__ __align__(16) u16 Bs[128 * 64];    // unpadded, granule-swizzled content
  const int z = blockIdx.z;
  const int which = z / 3, g = z % 3;
  const u16* X; const u16* W; const float* bias; u16* out; int Lmask;
  if (which == 0)      { X = xq; W = wq; bias = bq; out = oq; Lmask = 511; }
  else if (which == 1) { X = xk; W = wk; bias = bk; out = ok; Lmask = 1023; }
  else                 { X = xv; W = wv; bias = bv; out = ov; Lmask = 1023; }
  const int m0 = blockIdx.x * 128;
  if (m0 >= NB * (Lmask + 1)) return;
  X += g * DK; W += (size_t)g * DK * 1664; bias += g * DK; out += g * DK;

  const int tid = threadIdx.x;
  const int l0 = m0 & Lmask, bbase = m0 & ~Lmask;

  for (int i = tid; i < 140 * 16; i += 256) {
    const int r = i >> 4, s = i & 15;
    const int l = l0 - 6 + r;
    uint4 v = make_uint4(0, 0, 0, 0);
    if ((unsigned)l <= (unsigned)Lmask)
      v = *(const uint4*)&X[(size_t)(bbase + l) * DM + s * 8];
    *(uint4*)&xw[r][s * 8] = v;
  }

  const int wv_ = tid >> 6, lane = tid & 63;
  const int wr = (wv_ >> 1) * 64, wc = (wv_ & 1) * 64;
  const int fr = lane & 15, fk8 = (lane >> 4);

  f32x4 acc[4][4];
  const f32x4 zero4 = {0.f, 0.f, 0.f, 0.f};
  #pragma unroll
  for (int m = 0; m < 4; ++m)
    #pragma unroll
    for (int n = 0; n < 4; ++n) acc[m][n] = zero4;

  const int srow = lane >> 3, sg = lane & 7;

  for (int k0 = 0; k0 < 1664; k0 += 64) {
    __syncthreads();
    #pragma unroll
    for (int i = 0; i < 4; ++i) {
      const int ii = wv_ + i * 4;
      gload_lds16(&W[(size_t)(8 * ii + srow) * 1664 + k0 + sg * 8],
                  (char*)Bs + ii * 1024);
    }
    __syncthreads();
    const int t = k0 >> 7;
    const int ic0 = k0 & 64;
    #pragma unroll
    for (int ks = 0; ks < 2; ++ks) {
      bf16x8 av[4], bv_[4];
      #pragma unroll
      for (int m = 0; m < 4; ++m)
        av[m] = *(const bf16x8*)&xw[t + wr + m * 16 + fr][ic0 + ks * 32 + fk8 * 8];
      #pragma unroll
      for (int n = 0; n < 4; ++n) {
        const int r = wc + n * 16 + fr;
        const int pg = (ks * 4 + fk8) ^ (fr & 7);
        bv_[n] = *(const bf16x8*)&Bs[r * 64 + pg * 8];
      }
      #pragma unroll
      for (int m = 0; m < 4; ++m)
        #pragma unroll
        for (int n = 0; n < 4; ++n)
          acc[m][n] = __builtin_amdgcn_mfma_f32_16x16x32_bf16(av[m], bv_[n], acc[m][n], 0, 0, 0);
    }
  }

  const int crow = (lane >> 4) * 4;
  #pragma unroll
  for (int m = 0; m < 4; ++m) {
    #pragma unroll
    for (int n = 0; n < 4; ++n) {
      const int gm = m0 + wr + m * 16 + crow;
      const int gn = wc + n * 16 + fr;
      const float bval = bias[gn];
      #pragma unroll
      for (int j = 0; j < 4; ++j)
        out[(size_t)(gm + j) * DM + gn] = f2b(acc[m][n][j] + bval);
    }
  }
}

// ---------------- qk: E[z][q][k] = qh.kh/sqrt(128) (bf16 out) + fused row-max ----------------
__global__ __launch_bounds__(256) void qk_flash(
    const u16* __restrict__ QH, const u16* __restrict__ KH,
    u16* __restrict__ E, float* __restrict__ MS)
{
  __shared__ __align__(16) u16 As[128][136];
  __shared__ __align__(16) u16 Bs[128][136];
  __shared__ float rmx[2][128];
  const int tid = threadIdx.x;
  const int z = blockIdx.z, h = z >> 4, b = z & 15;
  const int m0 = blockIdx.x * 128;
  const u16* Ag = QH + ((size_t)b * QL + m0) * DM + h * DK;
  const u16* Bg = KH + (size_t)b * KL * DM + h * DK;
  u16* Ez = E + (size_t)z * QL * KL;

  for (int i = tid; i < 128 * 16; i += 256) {
    const int r = i >> 4, s = i & 15;
    *(uint4*)&As[r][s * 8] = *(const uint4*)&Ag[(size_t)r * DM + s * 8];
  }

  const int wv_ = tid >> 6, lane = tid & 63;
  const int wr = (wv_ >> 1) * 64, wc = (wv_ & 1) * 64;
  const int fr = lane & 15, fk = (lane >> 4) * 8;
  const int crow = (lane >> 4) * 4;
  const float sc = 0.08838834764831845f;

  float mx[4][4];
  #pragma unroll
  for (int m = 0; m < 4; ++m)
    #pragma unroll
    for (int j = 0; j < 4; ++j) mx[m][j] = -1e30f;

  for (int nt = 0; nt < 8; ++nt) {
    if (nt) __syncthreads();
    for (int i = tid; i < 128 * 16; i += 256) {
      const int r = i >> 4, s = i & 15;
      *(uint4*)&Bs[r][s * 8] = *(const uint4*)&Bg[(size_t)(nt * 128 + r) * DM + s * 8];
    }
    __syncthreads();

    f32x4 acc[4][4];
    const f32x4 zero4 = {0.f, 0.f, 0.f, 0.f};
    #pragma unroll
    for (int m = 0; m < 4; ++m)
      #pragma unroll
      for (int n = 0; n < 4; ++n) acc[m][n] = zero4;
    #pragma unroll
    for (int ks = 0; ks < 4; ++ks) {
      bf16x8 av[4], bv_[4];
      #pragma unroll
      for (int m = 0; m < 4; ++m)
        av[m] = *(const bf16x8*)&As[wr + m * 16 + fr][ks * 32 + fk];
      #pragma unroll
      for (int n = 0; n < 4; ++n)
        bv_[n] = *(const bf16x8*)&Bs[wc + n * 16 + fr][ks * 32 + fk];
      #pragma unroll
      for (int m = 0; m < 4; ++m)
        #pragma unroll
        for (int n = 0; n < 4; ++n)
          acc[m][n] = __builtin_amdgcn_mfma_f32_16x16x32_bf16(av[m], bv_[n], acc[m][n], 0, 0, 0);
    }
    #pragma unroll
    for (int m = 0; m < 4; ++m) {
      #pragma unroll
      for (int n = 0; n < 4; ++n) {
        const int gm = m0 + wr + m * 16 + crow;
        const int gn = nt * 128 + wc + n * 16 + fr;
        #pragma unroll
        for (int j = 0; j < 4; ++j) {
          const float vv = acc[m][n][j] * sc;
          mx[m][j] = fmaxf(mx[m][j], vv);
          Ez[(size_t)(gm + j) * KL + gn] = f2b(vv);
        }
      }
    }
  }

  #pragma unroll
  for (int m = 0; m < 4; ++m)
    #pragma unroll
    for (int j = 0; j < 4; ++j) {
      #pragma unroll
      for (int off = 1; off < 16; off <<= 1)
        mx[m][j] = fmaxf(mx[m][j], __shfl_xor(mx[m][j], off));
    }
  if ((lane & 15) == 0) {
    #pragma unroll
    for (int m = 0; m < 4; ++m)
      #pragma unroll
      for (int j = 0; j < 4; ++j)
        rmx[wv_ & 1][wr + m * 16 + crow + j] = mx[m][j];
  }
  __syncthreads();
  if (tid < 128)
    MS[2 * ((size_t)z * QL + m0 + tid)] = fmaxf(rmx[0][tid], rmx[1][tid]);
}

// ---------------- per (z,qc): softmax denominators + column-max partials ----------
__global__ __launch_bounds__(1024) void colsum_colmax(
    const u16* __restrict__ E, float* __restrict__ MS, float* __restrict__ cpart)
{
  const int z = blockIdx.x, qc = blockIdx.y, kk = threadIdx.x;
  __shared__ float mq[64], wsum[64][17], invs[64];
  if (kk < 64) mq[kk] = MS[2 * ((size_t)z * QL + qc * 64 + kk)];
  __syncthreads();
  const u16* base = E + ((size_t)z * QL + qc * 64) * KL + kk;
  float ex[64];
  #pragma unroll
  for (int qq = 0; qq < 64; ++qq)
    ex[qq] = expf(b2f(base[(size_t)qq * KL]) - mq[qq]);
  const int wid = kk >> 6, lane = kk & 63;
  #pragma unroll
  for (int qq = 0; qq < 64; ++qq) {
    float s = ex[qq];
    #pragma unroll
    for (int off = 1; off < 64; off <<= 1) s += __shfl_xor(s, off);
    if (lane == 0) wsum[qq][wid] = s;
  }
  __syncthreads();
  if (kk < 64) {
    float s = 0.f;
    #pragma unroll
    for (int w = 0; w < 16; ++w) s += wsum[kk][w];
    const float inv = 1.f / s;
    invs[kk] = inv;
    MS[2 * ((size_t)z * QL + qc * 64 + kk) + 1] = inv;
  }
  __syncthreads();
  float cm = 0.f;
  #pragma unroll
  for (int qq = 0; qq < 64; ++qq) cm = fmaxf(cm, ex[qq] * invs[qq]);
  cpart[((size_t)z * 8 + qc) * KL + kk] = cm;
}

// ---------------- fr per (h,b): sum_k max over 8 q-chunks ----------------
__global__ __launch_bounds__(256) void head_fr(const float* __restrict__ cpart,
                                               float* __restrict__ frr) {
  const int z = blockIdx.x, tid = threadIdx.x;
  float s = 0.f;
  for (int k = tid; k < KL; k += 256) {
    float m = 0.f;
    #pragma unroll
    for (int c = 0; c < 8; ++c) m = fmaxf(m, cpart[((size_t)z * 8 + c) * KL + k]);
    s += m;
  }
  #pragma unroll
  for (int off = 32; off; off >>= 1) s += __shfl_xor(s, off);
  __shared__ float red[4];
  if ((tid & 63) == 0) red[tid >> 6] = s;
  __syncthreads();
  if (tid == 0) frr[z] = red[0] + red[1] + red[2] + red[3];
}

// ---------------- head select ----------------
__global__ void select_head(const float* __restrict__ frr, const int* __restrict__ mel,
                            int* __restrict__ hidx, float* __restrict__ fr_out) {
  __shared__ float bf[16];
  const int b = threadIdx.x;
  if (b < 16) {
    float best = -1e30f; int bh = 0;
    for (int h = 0; h < NH; ++h) {
      float fr = frr[h * 16 + b] / (float)mel[b];
      if (fr > best) { best = fr; bh = h; }
    }
    hidx[b] = bh;
    bf[b] = best;
  }
  __syncthreads();
  if (threadIdx.x == 0) {
    float s = 0.f;
    for (int i = 0; i < 16; ++i) s += bf[i];
    *fr_out = s / 16.f;
  }
}

// ---------------- gather selected head: alpha -> d_out; sigmoid(alpha)^T -> pT ----------------
__global__ __launch_bounds__(256) void gather_fused(
    const u16* __restrict__ E, const float* __restrict__ ms,
    const int* __restrict__ hidx, float* __restrict__ afc, float* __restrict__ pT)
{
  __shared__ float tile[32][33];
  const int b = blockIdx.z, k0 = blockIdx.x * 32, q0 = blockIdx.y * 32;
  const int hb = hidx[b];
  const u16* src = E + (size_t)(hb * 16 + b) * QL * KL;
  const float* msb = ms + 2 * ((size_t)(hb * 16 + b) * QL + q0);
  const int tx = threadIdx.x, ty = threadIdx.y;
  #pragma unroll
  for (int yy = 0; yy < 4; ++yy) {
    int r = ty + 8 * yy;
    float m = msb[2 * r], inv = msb[2 * r + 1];
    float v = expf(b2f(src[(size_t)(q0 + r) * KL + k0 + tx]) - m) * inv;
    afc[((size_t)b * QL + q0 + r) * KL + k0 + tx] = v;
    tile[r][tx] = v;
  }
  __syncthreads();
  #pragma unroll
  for (int yy = 0; yy < 4; ++yy) {
    int c = ty + 8 * yy;
    float v = tile[tx][c];
    pT[((size_t)b * KL + k0 + c) * QL + q0 + tx] = 1.f / (1.f + expf(-v));
  }
}

// ================= wave-per-batch monotonic scan: asm prefetch + counted vmcnt =============
// All VMEM uses volatile asm (ext_vector types only!) so vmcnt counts are exact.
#define ALOAD(dst, base, OFF) \
  asm volatile("global_load_dwordx4 %0, %1, off offset:" OFF : "=v"(dst) : "v"(base))
#define ASTORE(base, OFF, val) \
  asm volatile("global_store_dwordx4 %0, %1, off offset:" OFF :: "v"(base), "v"(val) : "memory")
#define WAITVM(N) do { \
  asm volatile("s_waitcnt vmcnt(" N ")" ::: "memory"); \
  __builtin_amdgcn_sched_barrier(0); } while (0)

// load 8 rows (16 dwordx4) starting at LD into BUF[8][2]
#define LOAD_CHUNK(BUF, LD) do { \
  const float* b0_ = (LD); \
  const float* b1_ = (LD) + 1024; \
  const float* b2_ = (LD) + 2048; \
  const float* b3_ = (LD) + 3072; \
  ALOAD(BUF[0][0], b0_, "0");    ALOAD(BUF[0][1], b0_, "16"); \
  ALOAD(BUF[1][0], b0_, "2048"); ALOAD(BUF[1][1], b0_, "2064"); \
  ALOAD(BUF[2][0], b1_, "0");    ALOAD(BUF[2][1], b1_, "16"); \
  ALOAD(BUF[3][0], b1_, "2048"); ALOAD(BUF[3][1], b1_, "2064"); \
  ALOAD(BUF[4][0], b2_, "0");    ALOAD(BUF[4][1], b2_, "16"); \
  ALOAD(BUF[5][0], b2_, "2048"); ALOAD(BUF[5][1], b2_, "2064"); \
  ALOAD(BUF[6][0], b3_, "0");    ALOAD(BUF[6][1], b3_, "16"); \
  ALOAD(BUF[7][0], b3_, "2048"); ALOAD(BUF[7][1], b3_, "2064"); } while (0)

// one scan step: p in (V0,V1); updates aw[8]; stores to SB at byte offsets O0/O1
#define STEP(V0, V1, SB, O0, O1) do { \
  float pp[8] = {(V0)[0], (V0)[1], (V0)[2], (V0)[3], (V1)[0], (V1)[1], (V1)[2], (V1)[3]}; \
  float cc[8]; \
  _Pragma("unroll") for (int i_ = 0; i_ < 8; ++i_) \
    cc[i_] = __builtin_fmaf(-aw[i_], pp[i_], aw[i_]); \
  float cL_ = __shfl_up(cc[7], 1); \
  float nw0_ = __builtin_fmaf(aw[0], pp[0], cL_ * m0f); \
  _Pragma("unroll") for (int i_ = 7; i_ >= 1; --i_) \
    aw[i_] = __builtin_fmaf(aw[i_], pp[i_], cc[i_ - 1]); \
  aw[0] = nw0_; \
  f32x4 s0_, s1_; \
  s0_[0] = aw[0]; s0_[1] = aw[1]; s0_[2] = aw[2]; s0_[3] = aw[3]; \
  s1_[0] = aw[4]; s1_[1] = aw[5]; s1_[2] = aw[6]; s1_[3] = aw[7]; \
  ASTORE(SB, O0, s0_); ASTORE(SB, O1, s1_); } while (0)

// compute+store 8 steps of BUF, outputs at OS (16 stores)
#define COMPUTE_CHUNK(BUF, OS) do { \
  float* o0_ = (OS); \
  float* o1_ = (OS) + 1024; \
  float* o2_ = (OS) + 2048; \
  float* o3_ = (OS) + 3072; \
  STEP(BUF[0][0], BUF[0][1], o0_, "0", "16"); \
  STEP(BUF[1][0], BUF[1][1], o0_, "2048", "2064"); \
  STEP(BUF[2][0], BUF[2][1], o1_, "0", "16"); \
  STEP(BUF[3][0], BUF[3][1], o1_, "2048", "2064"); \
  STEP(BUF[4][0], BUF[4][1], o2_, "0", "16"); \
  STEP(BUF[5][0], BUF[5][1], o2_, "2048", "2064"); \
  STEP(BUF[6][0], BUF[6][1], o3_, "0", "16"); \
  STEP(BUF[7][0], BUF[7][1], o3_, "2048", "2064"); } while (0)

__global__ __launch_bounds__(64, 1) void smma_scan_wave(const float* __restrict__ pT,
                                                        float* __restrict__ ame) {
  const int b = blockIdx.x, lane = threadIdx.x;
  const float* ld = pT + (size_t)b * KL * QL + lane * 8;
  float* os = ame + (size_t)b * KL * QL + lane * 8;
  const float m0f = (lane == 0) ? 0.f : 1.f;
  float aw[8];
  #pragma unroll
  for (int i = 0; i < 8; ++i) aw[i] = 0.f;
  if (lane == 0) aw[0] = 1.f;

  f32x4 A[8][2], B[8][2];
  LOAD_CHUNK(A, ld); ld += 8 * QL;      // chunk 0
  LOAD_CHUNK(B, ld); ld += 8 * QL;      // chunk 1

  // peeled first double-chunk (first wait sees only 2 chunks outstanding)
  WAITVM("16");
  COMPUTE_CHUNK(A, os); os += 8 * QL;
  LOAD_CHUNK(A, ld); ld += 8 * QL;      // chunk 2
  WAITVM("32");
  COMPUTE_CHUNK(B, os); os += 8 * QL;
  LOAD_CHUNK(B, ld); ld += 8 * QL;      // chunk 3

  for (int t = 1; t < 64; ++t) {
    WAITVM("32");
    COMPUTE_CHUNK(A, os); os += 8 * QL;
    LOAD_CHUNK(A, ld); ld += 8 * QL;    // over-reads <=16 rows past end: slack after PT
    WAITVM("32");
    COMPUTE_CHUNK(B, os); os += 8 * QL;
    LOAD_CHUNK(B, ld); ld += 8 * QL;
  }
}

// ---------------- transpose + convert: f32 [R][C] -> bf16 [C][R] ----------------
__global__ __launch_bounds__(256) void transpose_cvt(
    const float* __restrict__ src, u16* __restrict__ dst, int R, int C) {
  __shared__ float tile[64][65];
  src += (size_t)blockIdx.z * R * C;
  dst += (size_t)blockIdx.z * R * C;
  const int r0 = blockIdx.x * 64, c0 = blockIdx.y * 64;
  {
    const int rr = threadIdx.x >> 4, cc = (threadIdx.x & 15) * 4;
    #pragma unroll
    for (int p = 0; p < 4; ++p) {
      float4 v = *(const float4*)&src[(size_t)(r0 + rr + p * 16) * C + c0 + cc];
      tile[rr + p * 16][cc] = v.x; tile[rr + p * 16][cc + 1] = v.y;
      tile[rr + p * 16][cc + 2] = v.z; tile[rr + p * 16][cc + 3] = v.w;
    }
  }
  __syncthreads();
  {
    const int oc = threadIdx.x >> 2, r8 = (threadIdx.x & 3) * 16;
    #pragma unroll
    for (int p = 0; p < 2; ++p) {
      union { u16 h[8]; uint4 u; } o;
      #pragma unroll
      for (int j = 0; j < 8; ++j) o.h[j] = f2b(tile[r8 + p * 8 + j][oc]);
      *(uint4*)&dst[(size_t)(c0 + oc) * R + r0 + r8 + p * 8] = o.u;
    }
  }
}

// ---------------- batched bf16 transpose: dst[c][r] = src[r][c] ----------------
__global__ __launch_bounds__(256) void transpose_bf16(
    const u16* __restrict__ src, u16* __restrict__ dst, int R, int C, long sz)
{
  __shared__ __align__(16) u16 tile[64][72];
  src += (size_t)blockIdx.z * sz;
  dst += (size_t)blockIdx.z * sz;
  const int r0 = blockIdx.x * 64, c0 = blockIdx.y * 64;
  {
    const int rr = threadIdx.x >> 3, c8 = (threadIdx.x & 7) * 8;
    #pragma unroll
    for (int p = 0; p < 2; ++p)
      *(uint4*)&tile[rr + p * 32][c8] =
          *(const uint4*)&src[(size_t)(r0 + rr + p * 32) * C + c0 + c8];
  }
  __syncthreads();
  {
    const int cc = threadIdx.x & 31, r8 = (threadIdx.x >> 5) * 8;
    #pragma unroll
    for (int p = 0; p < 2; ++p) {
      union { u16 h[8]; uint4 v; } o;
      #pragma unroll
      for (int j = 0; j < 8; ++j) o.h[j] = tile[r8 + j][cc + p * 32];
      *(uint4*)&dst[(size_t)(c0 + cc + p * 32) * R + r0 + r8] = o.v;
    }
  }
}

// ---------------- universal NT MFMA GEMM ----------------
template <bool OUT_BF16, bool BIAS>
__global__ __launch_bounds__(256) void gemm_nt(
    const u16* __restrict__ Aw, const u16* __restrict__ Bw,
    void* __restrict__ Cptr, const float* __restrict__ bias,
    int lda, int ldb, int ldc, int K, float alpha, int zdiv,
    long sA1, long sA0, long sB1, long sB0, long sC1, long sC0)
{
  __shared__ __align__(16) u16 As[128][72];
  __shared__ __align__(16) u16 Bs[128][72];
  const int tid = threadIdx.x;
  const int z = blockIdx.z;
  const int z1 = z / zdiv, z0 = z % zdiv;
  const int m0 = blockIdx.x * 128, n0 = blockIdx.y * 128;
  const u16* Ab = Aw + z1 * sA1 + z0 * sA0;
  const u16* Bz = Bw + z1 * sB1 + z0 * sB0;

  f32x4 acc[4][4];
  const f32x4 zero4 = {0.f, 0.f, 0.f, 0.f};
  #pragma unroll
  for (int m = 0; m < 4; ++m)
    #pragma unroll
    for (int n = 0; n < 4; ++n) acc[m][n] = zero4;

  const int rs = tid >> 3;
  const int k8 = (tid & 7) * 8;
  const int wv_ = tid >> 6, lane = tid & 63;
  const int wr = (wv_ >> 1) * 64, wc = (wv_ & 1) * 64;
  const int fr = lane & 15, fk = (lane >> 4) * 8;

  for (int k0 = 0; k0 < K; k0 += 64) {
    #pragma unroll
    for (int p = 0; p < 4; ++p)
      *(uint4*)&As[rs + p * 32][k8] =
          *(const uint4*)&Ab[(size_t)(m0 + rs + p * 32) * lda + k0 + k8];
    #pragma unroll
    for (int p = 0; p < 4; ++p)
      *(uint4*)&Bs[rs + p * 32][k8] =
          *(const uint4*)&Bz[(size_t)(n0 + rs + p * 32) * ldb + k0 + k8];
    __syncthreads();
    #pragma unroll
    for (int ks = 0; ks < 2; ++ks) {
      bf16x8 av[4], bv_[4];
      #pragma unroll
      for (int m = 0; m < 4; ++m)
        av[m] = *(const bf16x8*)&As[wr + m * 16 + fr][ks * 32 + fk];
      #pragma unroll
      for (int n = 0; n < 4; ++n)
        bv_[n] = *(const bf16x8*)&Bs[wc + n * 16 + fr][ks * 32 + fk];
      #pragma unroll
      for (int m = 0; m < 4; ++m)
        #pragma unroll
        for (int n = 0; n < 4; ++n)
          acc[m][n] = __builtin_amdgcn_mfma_f32_16x16x32_bf16(av[m], bv_[n], acc[m][n], 0, 0, 0);
    }
    __syncthreads();
  }

  const int crow = (lane >> 4) * 4;
  const long cbase = z1 * sC1 + z0 * sC0;
  #pragma unroll
  for (int m = 0; m < 4; ++m) {
    #pragma unroll
    for (int n = 0; n < 4; ++n) {
      const int gm = m0 + wr + m * 16 + crow;
      const int gn = n0 + wc + n * 16 + fr;
      float bval = 0.f;
      if constexpr (BIAS) bval = bias[gn];
      #pragma unroll
      for (int j = 0; j < 4; ++j) {
        float vv = acc[m][n][j] * alpha + bval;
        if constexpr (OUT_BF16)
          ((u16*)Cptr)[cbase + (size_t)(gm + j) * ldc + gn] = f2b(vv);
        else
          ((float*)Cptr)[cbase + (size_t)(gm + j) * ldc + gn] = vv;
      }
    }
  }
}

extern "C" void kernel_launch(void* const* d_in, const int* in_sizes, int n_in,
                              void* d_out, int out_size, void* d_ws, size_t ws_size,
                              hipStream_t stream) {
  const float* q      = (const float*)d_in[0];
  const float* k      = (const float*)d_in[1];
  const float* v      = (const float*)d_in[2];
  const int*   mel    = (const int*)d_in[3];
  const float* w_qs   = (const float*)d_in[4];
  const float* b_qs   = (const float*)d_in[5];
  const float* w_ks   = (const float*)d_in[6];
  const float* b_ks   = (const float*)d_in[7];
  const float* w_vs   = (const float*)d_in[8];
  const float* b_vs   = (const float*)d_in[9];
  const float* w_last = (const float*)d_in[10];
  const float* b_last = (const float*)d_in[11];

  char* ws = (char*)d_ws;
  float* out = (float*)d_out;

  u16* W2Q = (u16*)(ws + B_W2Q);
  u16* W2K = (u16*)(ws + B_W2K);
  u16* W2V = (u16*)(ws + B_W2V);
  u16* WLB = (u16*)(ws + B_WLB);
  u16* QH  = (u16*)(ws + B_QH);
  u16* KH  = (u16*)(ws + B_KH);
  u16* VH  = (u16*)(ws + B_VH);
  u16* XBQ = (u16*)(ws + B_XBQ);
  u16* XBK = (u16*)(ws + B_XBK);
  u16* XBV = (u16*)(ws + B_XBV);
  u16* E   = (u16*)(ws + B_E);
  float* AME = (float*)(ws + B_AME);
  u16* AMT = (u16*)(ws + B_AMT);
  float* MS = (float*)(ws + B_MS);
  float* CPART = (float*)(ws + B_CPART);
  float* FRR = (float*)(ws + B_FRR);
  int* HIDX = (int*)(ws + B_HIDX);
  float* PT = (float*)(ws + B_PT);
  u16* VHT = (u16*)(ws + B_VHT);
  u16* CVP = (u16*)(ws + B_CVP);

  // 1. weight repacks (swizzled) + input bf16 conversion
  repack_all<<<dim3(2496, 1, 4), 256, 0, stream>>>(w_qs, w_ks, w_vs, w_last,
                                                   W2Q, W2K, W2V, WLB);
  cvt8_all<<<dim3(3072, 1, 3), 256, 0, stream>>>(q, k, v, XBQ, XBK, XBV);

  // 2. grouped convs
  conv_mfma<<<dim3(128, 1, 9), 256, 0, stream>>>(XBQ, XBK, XBV, W2Q, W2K, W2V,
                                                 b_qs, b_ks, b_vs, QH, KH, VH);

  // 3. e (bf16) + fused row-max
  qk_flash<<<dim3(4, 1, 48), 256, 0, stream>>>(QH, KH, E, MS);

  // 4. softmax denominators + colmax partials
  colsum_colmax<<<dim3(48, 8), 1024, 0, stream>>>(E, MS, CPART);

  // 5. fr + head select
  head_fr<<<NH * NB, 256, 0, stream>>>(CPART, FRR);
  select_head<<<1, 64, 0, stream>>>(FRR, mel, HIDX, out + OUT_FR);

  // 6. gather alpha_fc -> d_out, sigmoid -> pT [b][k][q]
  gather_fused<<<dim3(KL / 32, QL / 32, NB), dim3(32, 8), 0, stream>>>(
      E, MS, HIDX, out + OUT_ALPHA, PT);

  // 7. register scan -> ame f32 [b][k][q]
  smma_scan_wave<<<NB, 64, 0, stream>>>(PT, AME);

  // 8. transposes
  transpose_cvt<<<dim3(16, 8, NB), 256, 0, stream>>>(AME, AMT, KL, QL);
  transpose_bf16<<<dim3(16, 6, NB), 256, 0, stream>>>(VH, VHT, KL, DM, 393216);

  // 9. cv_pre[b][q][d] = sum_k amT[q][k] * vhT[d][k]
  gemm_nt<true, false><<<dim3(4, 3, NB), 256, 0, stream>>>(
      AMT, VHT, CVP, nullptr, KL, KL, DM, KL, 1.f, 1,
      524288L, 0, 393216L, 0, 196608L, 0);

  // 10. out = cv_pre @ w_last^T + b_last
  gemm_nt<false, true><<<dim3(64, 3, 1), 256, 0, stream>>>(
      CVP, WLB, out + OUT_CV, b_last, DM, DM, DM, DM, 1.f, 1,
      0, 0, 0, 0, 0, 0);
}

// Round 8
// 304.382 us; speedup vs baseline: 7.3807x; 1.0627x over previous
//
#include <hip/hip_runtime.h>

#define NB 16
#define QL 512
#define KL 1024
#define DM 384
#define NH 3
#define DK 128

typedef unsigned short u16;
typedef __attribute__((ext_vector_type(8))) short bf16x8;
typedef __attribute__((ext_vector_type(4))) float f32x4;
typedef __attribute__((ext_vector_type(4))) unsigned int u32x4;

// ---------------- workspace byte offsets ----------------
static const size_t B_W2Q = 0;            // bf16 [384][1664] (granule-swizzled)
static const size_t B_W2K = 1277952;
static const size_t B_W2V = 2555904;
static const size_t B_WLB = 3833856;      // bf16 [384][384]
static const size_t B_QH  = 4128768;      // bf16 [16*512][384]
static const size_t B_KH  = 10420224;     // bf16 [16*1024][384]
static const size_t B_VH  = 23003136;     // bf16 [16*1024][384]
static const size_t B_E   = 67043328;     // bf16 [48][512][1024]
static const size_t B_AMT = 100597760;    // bf16 [16][512][1024] (aliases dead E-high)
static const size_t B_MS  = 117374976;    // f32 [48*512][2] {rowmax, inv}
static const size_t B_CPART = 117571584;  // f32 [48][8][1024]
static const size_t B_FRR = 119144448;    // f32 [48]
static const size_t B_HIDX = 119144704;   // int [16]
static const size_t B_PT  = 119144960;    // f32 [16][1024][512] (+64KB slack after)
static const size_t B_VHT = 152764928;    // bf16 [16][384][1024]
static const size_t B_CVP = 165347840;    // bf16 [16][512][384]

// d_out offsets (floats)
static const size_t OUT_CV    = 0;
static const size_t OUT_ALPHA = 3145728;
static const size_t OUT_FR    = 11534336;

__device__ __forceinline__ u16 f2b(float x) {
  union { float f; unsigned u; } q; q.f = x;
  unsigned r = q.u + 0x7fffu + ((q.u >> 16) & 1u);
  return (u16)(r >> 16);
}
__device__ __forceinline__ float b2f(u16 h) {
  union { unsigned u; float f; } q; q.u = ((unsigned)h) << 16;
  return q.f;
}

typedef __attribute__((address_space(3))) void lds_void;
typedef __attribute__((address_space(1))) const void g_void;
__device__ __forceinline__ void gload_lds16(const void* g, void* l) {
  __builtin_amdgcn_global_load_lds((g_void*)g, (lds_void*)l, 16, 0, 0);
}

// ---------------- weight repacks ----------------
__global__ __launch_bounds__(256) void repack_all(
    const float* __restrict__ wq, const float* __restrict__ wk,
    const float* __restrict__ wv, const float* __restrict__ wl,
    u16* __restrict__ dq, u16* __restrict__ dk, u16* __restrict__ dv,
    u16* __restrict__ dl) {
  const int z = blockIdx.z;
  const int tid = blockIdx.x * 256 + threadIdx.x;
  if (z < 3) {
    if (tid >= 384 * 1664) return;
    const float* src = (z == 0) ? wq : (z == 1) ? wk : wv;
    u16* dst = (z == 0) ? dq : (z == 1) ? dk : dv;
    const int oc = tid / 1664, k = tid % 1664;     // logical k
    const int t = k >> 7, ic = k & 127;
    const int g = (k >> 3) & 7, e = k & 7;
    const int pcol = (k & ~63) + (((g ^ (oc & 7))) << 3) + e;
    dst[(size_t)oc * 1664 + pcol] = f2b(src[(size_t)oc * 1664 + ic * 13 + t]);
  } else {
    if (tid < 384 * 384) dl[tid] = f2b(wl[tid]);
  }
}

// ---------------- grouped conv1d: 2-pass ic-split, LDS x-window; Bs via global_load_lds ----
// z/3 selects tensor (0=q L=512, 1=k, 2=v L=1024); z%3 = group
__global__ __launch_bounds__(256, 4) void conv_mfma(
    const float* __restrict__ xq, const float* __restrict__ xk, const float* __restrict__ xv,
    const u16* __restrict__ wq, const u16* __restrict__ wk, const u16* __restrict__ wv,
    const float* __restrict__ bq, const float* __restrict__ bk, const float* __restrict__ bv,
    u16* __restrict__ oq, u16* __restrict__ ok, u16* __restrict__ ov)
{
  __shared__ __align__(16) u16 xw[140][72];
  __shared__ __align__(16) u16 Bs[128 * 64];    // unpadded, granule-swizzled content
  const int z = blockIdx.z;
  const int which = z / 3, g = z % 3;
  const float* X; const u16* W; const float* bias; u16* out; int Lmask;
  if (which == 0)      { X = xq; W = wq; bias = bq; out = oq; Lmask = 511; }
  else if (which == 1) { X = xk; W = wk; bias = bk; out = ok; Lmask = 1023; }
  else                 { X = xv; W = wv; bias = bv; out = ov; Lmask = 1023; }
  const int m0 = blockIdx.x * 128;
  if (m0 >= NB * (Lmask + 1)) return;
  X += g * DK; W += (size_t)g * DK * 1664; bias += g * DK; out += g * DK;

  const int tid = threadIdx.x;
  const int l0 = m0 & Lmask, bbase = m0 & ~Lmask;

  const int wv_ = tid >> 6, lane = tid & 63;
  const int wr = (wv_ >> 1) * 64, wc = (wv_ & 1) * 64;
  const int fr = lane & 15, fk8 = (lane >> 4);
  const int srow = lane >> 3, sg = lane & 7;

  f32x4 acc[4][4];
  const f32x4 zero4 = {0.f, 0.f, 0.f, 0.f};
  #pragma unroll
  for (int m = 0; m < 4; ++m)
    #pragma unroll
    for (int n = 0; n < 4; ++n) acc[m][n] = zero4;

  for (int h = 0; h < 2; ++h) {
    __syncthreads();   // all reads of xw (prev pass) + Bs done
    // stage this pass's 140-row x 64-ic window, f32 -> bf16 in flight
    for (int i = tid; i < 140 * 16; i += 256) {
      const int r = i >> 4, c4 = (i & 15) * 4;
      const int l = l0 - 6 + r;
      float4 v = make_float4(0.f, 0.f, 0.f, 0.f);
      if ((unsigned)l <= (unsigned)Lmask)
        v = *(const float4*)&X[(size_t)(bbase + l) * DM + h * 64 + c4];
      union { u16 u[4]; uint2 d; } o;
      o.u[0] = f2b(v.x); o.u[1] = f2b(v.y); o.u[2] = f2b(v.z); o.u[3] = f2b(v.w);
      *(uint2*)&xw[r][c4] = o.d;
    }
    for (int t = 0; t < 13; ++t) {
      const int k0 = t * 128 + h * 64;
      __syncthreads();   // xw ready (t==0) / prior Bs reads done
      #pragma unroll
      for (int i = 0; i < 4; ++i) {
        const int ii = wv_ + i * 4;
        gload_lds16(&W[(size_t)(8 * ii + srow) * 1664 + k0 + sg * 8],
                    (char*)Bs + ii * 1024);
      }
      __syncthreads();   // compiler drains vmcnt before barrier
      #pragma unroll
      for (int ks = 0; ks < 2; ++ks) {
        bf16x8 av[4], bv_[4];
        #pragma unroll
        for (int m = 0; m < 4; ++m)
          av[m] = *(const bf16x8*)&xw[t + wr + m * 16 + fr][ks * 32 + fk8 * 8];
        #pragma unroll
        for (int n = 0; n < 4; ++n) {
          const int r = wc + n * 16 + fr;
          const int pg = (ks * 4 + fk8) ^ (fr & 7);
          bv_[n] = *(const bf16x8*)&Bs[r * 64 + pg * 8];
        }
        #pragma unroll
        for (int m = 0; m < 4; ++m)
          #pragma unroll
          for (int n = 0; n < 4; ++n)
            acc[m][n] = __builtin_amdgcn_mfma_f32_16x16x32_bf16(av[m], bv_[n], acc[m][n], 0, 0, 0);
      }
    }
  }

  const int crow = (lane >> 4) * 4;
  #pragma unroll
  for (int m = 0; m < 4; ++m) {
    #pragma unroll
    for (int n = 0; n < 4; ++n) {
      const int gm = m0 + wr + m * 16 + crow;
      const int gn = wc + n * 16 + fr;
      const float bval = bias[gn];
      #pragma unroll
      for (int j = 0; j < 4; ++j)
        out[(size_t)(gm + j) * DM + gn] = f2b(acc[m][n][j] + bval);
    }
  }
}

// ---------------- qk: E[z][q][k] = qh.kh/sqrt(128) (bf16 out) + fused row-max ----------------
__global__ __launch_bounds__(256) void qk_flash(
    const u16* __restrict__ QH, const u16* __restrict__ KH,
    u16* __restrict__ E, float* __restrict__ MS)
{
  __shared__ __align__(16) u16 As[128][136];
  __shared__ __align__(16) u16 Bs[128][136];
  __shared__ float rmx[2][128];
  const int tid = threadIdx.x;
  const int z = blockIdx.z, h = z >> 4, b = z & 15;
  const int m0 = blockIdx.x * 128;
  const u16* Ag = QH + ((size_t)b * QL + m0) * DM + h * DK;
  const u16* Bg = KH + (size_t)b * KL * DM + h * DK;
  u16* Ez = E + (size_t)z * QL * KL;

  for (int i = tid; i < 128 * 16; i += 256) {
    const int r = i >> 4, s = i & 15;
    *(uint4*)&As[r][s * 8] = *(const uint4*)&Ag[(size_t)r * DM + s * 8];
  }

  const int wv_ = tid >> 6, lane = tid & 63;
  const int wr = (wv_ >> 1) * 64, wc = (wv_ & 1) * 64;
  const int fr = lane & 15, fk = (lane >> 4) * 8;
  const int crow = (lane >> 4) * 4;
  const float sc = 0.08838834764831845f;

  float mx[4][4];
  #pragma unroll
  for (int m = 0; m < 4; ++m)
    #pragma unroll
    for (int j = 0; j < 4; ++j) mx[m][j] = -1e30f;

  for (int nt = 0; nt < 8; ++nt) {
    if (nt) __syncthreads();
    for (int i = tid; i < 128 * 16; i += 256) {
      const int r = i >> 4, s = i & 15;
      *(uint4*)&Bs[r][s * 8] = *(const uint4*)&Bg[(size_t)(nt * 128 + r) * DM + s * 8];
    }
    __syncthreads();

    f32x4 acc[4][4];
    const f32x4 zero4 = {0.f, 0.f, 0.f, 0.f};
    #pragma unroll
    for (int m = 0; m < 4; ++m)
      #pragma unroll
      for (int n = 0; n < 4; ++n) acc[m][n] = zero4;
    #pragma unroll
    for (int ks = 0; ks < 4; ++ks) {
      bf16x8 av[4], bv_[4];
      #pragma unroll
      for (int m = 0; m < 4; ++m)
        av[m] = *(const bf16x8*)&As[wr + m * 16 + fr][ks * 32 + fk];
      #pragma unroll
      for (int n = 0; n < 4; ++n)
        bv_[n] = *(const bf16x8*)&Bs[wc + n * 16 + fr][ks * 32 + fk];
      #pragma unroll
      for (int m = 0; m < 4; ++m)
        #pragma unroll
        for (int n = 0; n < 4; ++n)
          acc[m][n] = __builtin_amdgcn_mfma_f32_16x16x32_bf16(av[m], bv_[n], acc[m][n], 0, 0, 0);
    }
    #pragma unroll
    for (int m = 0; m < 4; ++m) {
      #pragma unroll
      for (int n = 0; n < 4; ++n) {
        const int gm = m0 + wr + m * 16 + crow;
        const int gn = nt * 128 + wc + n * 16 + fr;
        #pragma unroll
        for (int j = 0; j < 4; ++j) {
          const float vv = acc[m][n][j] * sc;
          mx[m][j] = fmaxf(mx[m][j], vv);
          Ez[(size_t)(gm + j) * KL + gn] = f2b(vv);
        }
      }
    }
  }

  #pragma unroll
  for (int m = 0; m < 4; ++m)
    #pragma unroll
    for (int j = 0; j < 4; ++j) {
      #pragma unroll
      for (int off = 1; off < 16; off <<= 1)
        mx[m][j] = fmaxf(mx[m][j], __shfl_xor(mx[m][j], off));
    }
  if ((lane & 15) == 0) {
    #pragma unroll
    for (int m = 0; m < 4; ++m)
      #pragma unroll
      for (int j = 0; j < 4; ++j)
        rmx[wv_ & 1][wr + m * 16 + crow + j] = mx[m][j];
  }
  __syncthreads();
  if (tid < 128)
    MS[2 * ((size_t)z * QL + m0 + tid)] = fmaxf(rmx[0][tid], rmx[1][tid]);
}

// ---------------- per (z,qc): softmax denominators + column-max partials ----------
__global__ __launch_bounds__(1024) void colsum_colmax(
    const u16* __restrict__ E, float* __restrict__ MS, float* __restrict__ cpart)
{
  const int z = blockIdx.x, qc = blockIdx.y, kk = threadIdx.x;
  __shared__ float mq[64], wsum[64][17], invs[64];
  if (kk < 64) mq[kk] = MS[2 * ((size_t)z * QL + qc * 64 + kk)];
  __syncthreads();
  const u16* base = E + ((size_t)z * QL + qc * 64) * KL + kk;
  float ex[64];
  #pragma unroll
  for (int qq = 0; qq < 64; ++qq)
    ex[qq] = expf(b2f(base[(size_t)qq * KL]) - mq[qq]);
  const int wid = kk >> 6, lane = kk & 63;
  #pragma unroll
  for (int qq = 0; qq < 64; ++qq) {
    float s = ex[qq];
    #pragma unroll
    for (int off = 1; off < 64; off <<= 1) s += __shfl_xor(s, off);
    if (lane == 0) wsum[qq][wid] = s;
  }
  __syncthreads();
  if (kk < 64) {
    float s = 0.f;
    #pragma unroll
    for (int w = 0; w < 16; ++w) s += wsum[kk][w];
    const float inv = 1.f / s;
    invs[kk] = inv;
    MS[2 * ((size_t)z * QL + qc * 64 + kk) + 1] = inv;
  }
  __syncthreads();
  float cm = 0.f;
  #pragma unroll
  for (int qq = 0; qq < 64; ++qq) cm = fmaxf(cm, ex[qq] * invs[qq]);
  cpart[((size_t)z * 8 + qc) * KL + kk] = cm;
}

// ---------------- fr per (h,b): sum_k max over 8 q-chunks ----------------
__global__ __launch_bounds__(256) void head_fr(const float* __restrict__ cpart,
                                               float* __restrict__ frr) {
  const int z = blockIdx.x, tid = threadIdx.x;
  float s = 0.f;
  for (int k = tid; k < KL; k += 256) {
    float m = 0.f;
    #pragma unroll
    for (int c = 0; c < 8; ++c) m = fmaxf(m, cpart[((size_t)z * 8 + c) * KL + k]);
    s += m;
  }
  #pragma unroll
  for (int off = 32; off; off >>= 1) s += __shfl_xor(s, off);
  __shared__ float red[4];
  if ((tid & 63) == 0) red[tid >> 6] = s;
  __syncthreads();
  if (tid == 0) frr[z] = red[0] + red[1] + red[2] + red[3];
}

// ---------------- head select ----------------
__global__ void select_head(const float* __restrict__ frr, const int* __restrict__ mel,
                            int* __restrict__ hidx, float* __restrict__ fr_out) {
  __shared__ float bf[16];
  const int b = threadIdx.x;
  if (b < 16) {
    float best = -1e30f; int bh = 0;
    for (int h = 0; h < NH; ++h) {
      float fr = frr[h * 16 + b] / (float)mel[b];
      if (fr > best) { best = fr; bh = h; }
    }
    hidx[b] = bh;
    bf[b] = best;
  }
  __syncthreads();
  if (threadIdx.x == 0) {
    float s = 0.f;
    for (int i = 0; i < 16; ++i) s += bf[i];
    *fr_out = s / 16.f;
  }
}

// ---------------- gather selected head: alpha -> d_out; sigmoid(alpha)^T -> pT ----------------
__global__ __launch_bounds__(256) void gather_fused(
    const u16* __restrict__ E, const float* __restrict__ ms,
    const int* __restrict__ hidx, float* __restrict__ afc, float* __restrict__ pT)
{
  __shared__ float tile[32][33];
  const int b = blockIdx.z, k0 = blockIdx.x * 32, q0 = blockIdx.y * 32;
  const int hb = hidx[b];
  const u16* src = E + (size_t)(hb * 16 + b) * QL * KL;
  const float* msb = ms + 2 * ((size_t)(hb * 16 + b) * QL + q0);
  const int tx = threadIdx.x, ty = threadIdx.y;
  #pragma unroll
  for (int yy = 0; yy < 4; ++yy) {
    int r = ty + 8 * yy;
    float m = msb[2 * r], inv = msb[2 * r + 1];
    float v = expf(b2f(src[(size_t)(q0 + r) * KL + k0 + tx]) - m) * inv;
    afc[((size_t)b * QL + q0 + r) * KL + k0 + tx] = v;
    tile[r][tx] = v;
  }
  __syncthreads();
  #pragma unroll
  for (int yy = 0; yy < 4; ++yy) {
    int c = ty + 8 * yy;
    float v = tile[tx][c];
    pT[((size_t)b * KL + k0 + c) * QL + q0 + tx] = 1.f / (1.f + expf(-v));
  }
}

// ================= scan: asm prefetch + counted vmcnt + in-register transpose to bf16 ======
#define ALOAD(dst, base, OFF) \
  asm volatile("global_load_dwordx4 %0, %1, off offset:" OFF : "=v"(dst) : "v"(base))
#define ASTORE16(base, OFF, val) \
  asm volatile("global_store_dwordx4 %0, %1, off offset:" OFF :: "v"(base), "v"(val) : "memory")
#define WAITVM(N) do { \
  asm volatile("s_waitcnt vmcnt(" N ")" ::: "memory"); \
  __builtin_amdgcn_sched_barrier(0); } while (0)
#define CVTPK(d, lo, hi) \
  asm("v_cvt_pk_bf16_f32 %0, %1, %2" : "=v"(d) : "v"(lo), "v"(hi))

// load 8 rows (16 dwordx4) starting at LD into BUF[8][2]
#define LOAD_CHUNK(BUF, LD) do { \
  const float* b0_ = (LD); \
  const float* b1_ = (LD) + 1024; \
  const float* b2_ = (LD) + 2048; \
  const float* b3_ = (LD) + 3072; \
  ALOAD(BUF[0][0], b0_, "0");    ALOAD(BUF[0][1], b0_, "16"); \
  ALOAD(BUF[1][0], b0_, "2048"); ALOAD(BUF[1][1], b0_, "2064"); \
  ALOAD(BUF[2][0], b1_, "0");    ALOAD(BUF[2][1], b1_, "16"); \
  ALOAD(BUF[3][0], b1_, "2048"); ALOAD(BUF[3][1], b1_, "2064"); \
  ALOAD(BUF[4][0], b2_, "0");    ALOAD(BUF[4][1], b2_, "16"); \
  ALOAD(BUF[5][0], b2_, "2048"); ALOAD(BUF[5][1], b2_, "2064"); \
  ALOAD(BUF[6][0], b3_, "0");    ALOAD(BUF[6][1], b3_, "16"); \
  ALOAD(BUF[7][0], b3_, "2048"); ALOAD(BUF[7][1], b3_, "2064"); } while (0)

// even step: update aw in place
#define STEP_E(V0, V1) do { \
  float pp[8] = {(V0)[0], (V0)[1], (V0)[2], (V0)[3], (V1)[0], (V1)[1], (V1)[2], (V1)[3]}; \
  float cc[8]; \
  _Pragma("unroll") for (int i_ = 0; i_ < 8; ++i_) \
    cc[i_] = __builtin_fmaf(-aw[i_], pp[i_], aw[i_]); \
  float cL_ = __shfl_up(cc[7], 1); \
  float nw0_ = __builtin_fmaf(aw[0], pp[0], cL_ * m0f); \
  _Pragma("unroll") for (int i_ = 7; i_ >= 1; --i_) \
    aw[i_] = __builtin_fmaf(aw[i_], pp[i_], cc[i_ - 1]); \
  aw[0] = nw0_; } while (0)

// odd step: compute into nw, pack pairs (aw=even result, nw=odd result) into dw[q][X]
#define STEP_O(V0, V1, X) do { \
  float pp[8] = {(V0)[0], (V0)[1], (V0)[2], (V0)[3], (V1)[0], (V1)[1], (V1)[2], (V1)[3]}; \
  float cc[8], nw[8]; \
  _Pragma("unroll") for (int i_ = 0; i_ < 8; ++i_) \
    cc[i_] = __builtin_fmaf(-aw[i_], pp[i_], aw[i_]); \
  float cL_ = __shfl_up(cc[7], 1); \
  nw[0] = __builtin_fmaf(aw[0], pp[0], cL_ * m0f); \
  _Pragma("unroll") for (int i_ = 1; i_ < 8; ++i_) \
    nw[i_] = __builtin_fmaf(aw[i_], pp[i_], cc[i_ - 1]); \
  _Pragma("unroll") for (int i_ = 0; i_ < 8; ++i_) { \
    CVTPK(dw[i_][X], aw[i_], nw[i_]); aw[i_] = nw[i_]; } } while (0)

// 8 steps + 8 transposed b128 stores (rows = this lane's 8 q's, cols = 8 k's)
#define COMPUTE_CHUNK(BUF, OB0, OB1, OB2, OB3) do { \
  unsigned dw[8][4]; \
  STEP_E(BUF[0][0], BUF[0][1]); STEP_O(BUF[1][0], BUF[1][1], 0); \
  STEP_E(BUF[2][0], BUF[2][1]); STEP_O(BUF[3][0], BUF[3][1], 1); \
  STEP_E(BUF[4][0], BUF[4][1]); STEP_O(BUF[5][0], BUF[5][1], 2); \
  STEP_E(BUF[6][0], BUF[6][1]); STEP_O(BUF[7][0], BUF[7][1], 3); \
  u32x4 s_; \
  s_[0] = dw[0][0]; s_[1] = dw[0][1]; s_[2] = dw[0][2]; s_[3] = dw[0][3]; \
  ASTORE16(OB0, "0", s_); \
  s_[0] = dw[1][0]; s_[1] = dw[1][1]; s_[2] = dw[1][2]; s_[3] = dw[1][3]; \
  ASTORE16(OB0, "2048", s_); \
  s_[0] = dw[2][0]; s_[1] = dw[2][1]; s_[2] = dw[2][2]; s_[3] = dw[2][3]; \
  ASTORE16(OB1, "0", s_); \
  s_[0] = dw[3][0]; s_[1] = dw[3][1]; s_[2] = dw[3][2]; s_[3] = dw[3][3]; \
  ASTORE16(OB1, "2048", s_); \
  s_[0] = dw[4][0]; s_[1] = dw[4][1]; s_[2] = dw[4][2]; s_[3] = dw[4][3]; \
  ASTORE16(OB2, "0", s_); \
  s_[0] = dw[5][0]; s_[1] = dw[5][1]; s_[2] = dw[5][2]; s_[3] = dw[5][3]; \
  ASTORE16(OB2, "2048", s_); \
  s_[0] = dw[6][0]; s_[1] = dw[6][1]; s_[2] = dw[6][2]; s_[3] = dw[6][3]; \
  ASTORE16(OB3, "0", s_); \
  s_[0] = dw[7][0]; s_[1] = dw[7][1]; s_[2] = dw[7][2]; s_[3] = dw[7][3]; \
  ASTORE16(OB3, "2048", s_); } while (0)

__global__ __launch_bounds__(64, 1) void smma_scan_wave(const float* __restrict__ pT,
                                                        u16* __restrict__ amt) {
  const int b = blockIdx.x, lane = threadIdx.x;
  const float* ld = pT + (size_t)b * KL * QL + lane * 8;
  u16* ob0 = amt + (size_t)b * QL * KL + (size_t)(lane * 8) * KL;      // rows q=lane*8+{0,1}
  u16* ob1 = ob0 + 2 * KL;                                             // q+{2,3}
  u16* ob2 = ob0 + 4 * KL;                                             // q+{4,5}
  u16* ob3 = ob0 + 6 * KL;                                             // q+{6,7}
  const float m0f = (lane == 0) ? 0.f : 1.f;
  float aw[8];
  #pragma unroll
  for (int i = 0; i < 8; ++i) aw[i] = 0.f;
  if (lane == 0) aw[0] = 1.f;

  f32x4 A[8][2], B[8][2];
  LOAD_CHUNK(A, ld); ld += 8 * QL;      // chunk 0
  LOAD_CHUNK(B, ld); ld += 8 * QL;      // chunk 1

  // peeled first double-chunk
  WAITVM("16");
  COMPUTE_CHUNK(A, ob0, ob1, ob2, ob3);
  ob0 += 8; ob1 += 8; ob2 += 8; ob3 += 8;
  LOAD_CHUNK(A, ld); ld += 8 * QL;      // chunk 2
  WAITVM("24");
  COMPUTE_CHUNK(B, ob0, ob1, ob2, ob3);
  ob0 += 8; ob1 += 8; ob2 += 8; ob3 += 8;
  LOAD_CHUNK(B, ld); ld += 8 * QL;      // chunk 3

  for (int t = 1; t < 64; ++t) {
    WAITVM("24");
    COMPUTE_CHUNK(A, ob0, ob1, ob2, ob3);
    ob0 += 8; ob1 += 8; ob2 += 8; ob3 += 8;
    LOAD_CHUNK(A, ld); ld += 8 * QL;    // over-reads <=16 rows past end: 64KB slack after pT
    WAITVM("24");
    COMPUTE_CHUNK(B, ob0, ob1, ob2, ob3);
    ob0 += 8; ob1 += 8; ob2 += 8; ob3 += 8;
    LOAD_CHUNK(B, ld); ld += 8 * QL;
  }
}

// ---------------- batched bf16 transpose: dst[c][r] = src[r][c] ----------------
__global__ __launch_bounds__(256) void transpose_bf16(
    const u16* __restrict__ src, u16* __restrict__ dst, int R, int C, long sz)
{
  __shared__ __align__(16) u16 tile[64][72];
  src += (size_t)blockIdx.z * sz;
  dst += (size_t)blockIdx.z * sz;
  const int r0 = blockIdx.x * 64, c0 = blockIdx.y * 64;
  {
    const int rr = threadIdx.x >> 3, c8 = (threadIdx.x & 7) * 8;
    #pragma unroll
    for (int p = 0; p < 2; ++p)
      *(uint4*)&tile[rr + p * 32][c8] =
          *(const uint4*)&src[(size_t)(r0 + rr + p * 32) * C + c0 + c8];
  }
  __syncthreads();
  {
    const int cc = threadIdx.x & 31, r8 = (threadIdx.x >> 5) * 8;
    #pragma unroll
    for (int p = 0; p < 2; ++p) {
      union { u16 h[8]; uint4 v; } o;
      #pragma unroll
      for (int j = 0; j < 8; ++j) o.h[j] = tile[r8 + j][cc + p * 32];
      *(uint4*)&dst[(size_t)(c0 + cc + p * 32) * R + r0 + r8] = o.v;
    }
  }
}

// ---------------- universal NT MFMA GEMM ----------------
template <bool OUT_BF16, bool BIAS>
__global__ __launch_bounds__(256) void gemm_nt(
    const u16* __restrict__ Aw, const u16* __restrict__ Bw,
    void* __restrict__ Cptr, const float* __restrict__ bias,
    int lda, int ldb, int ldc, int K, float alpha, int zdiv,
    long sA1, long sA0, long sB1, long sB0, long sC1, long sC0)
{
  __shared__ __align__(16) u16 As[128][72];
  __shared__ __align__(16) u16 Bs[128][72];
  const int tid = threadIdx.x;
  const int z = blockIdx.z;
  const int z1 = z / zdiv, z0 = z % zdiv;
  const int m0 = blockIdx.x * 128, n0 = blockIdx.y * 128;
  const u16* Ab = Aw + z1 * sA1 + z0 * sA0;
  const u16* Bz = Bw + z1 * sB1 + z0 * sB0;

  f32x4 acc[4][4];
  const f32x4 zero4 = {0.f, 0.f, 0.f, 0.f};
  #pragma unroll
  for (int m = 0; m < 4; ++m)
    #pragma unroll
    for (int n = 0; n < 4; ++n) acc[m][n] = zero4;

  const int rs = tid >> 3;
  const int k8 = (tid & 7) * 8;
  const int wv_ = tid >> 6, lane = tid & 63;
  const int wr = (wv_ >> 1) * 64, wc = (wv_ & 1) * 64;
  const int fr = lane & 15, fk = (lane >> 4) * 8;

  for (int k0 = 0; k0 < K; k0 += 64) {
    #pragma unroll
    for (int p = 0; p < 4; ++p)
      *(uint4*)&As[rs + p * 32][k8] =
          *(const uint4*)&Ab[(size_t)(m0 + rs + p * 32) * lda + k0 + k8];
    #pragma unroll
    for (int p = 0; p < 4; ++p)
      *(uint4*)&Bs[rs + p * 32][k8] =
          *(const uint4*)&Bz[(size_t)(n0 + rs + p * 32) * ldb + k0 + k8];
    __syncthreads();
    #pragma unroll
    for (int ks = 0; ks < 2; ++ks) {
      bf16x8 av[4], bv_[4];
      #pragma unroll
      for (int m = 0; m < 4; ++m)
        av[m] = *(const bf16x8*)&As[wr + m * 16 + fr][ks * 32 + fk];
      #pragma unroll
      for (int n = 0; n < 4; ++n)
        bv_[n] = *(const bf16x8*)&Bs[wc + n * 16 + fr][ks * 32 + fk];
      #pragma unroll
      for (int m = 0; m < 4; ++m)
        #pragma unroll
        for (int n = 0; n < 4; ++n)
          acc[m][n] = __builtin_amdgcn_mfma_f32_16x16x32_bf16(av[m], bv_[n], acc[m][n], 0, 0, 0);
    }
    __syncthreads();
  }

  const int crow = (lane >> 4) * 4;
  const long cbase = z1 * sC1 + z0 * sC0;
  #pragma unroll
  for (int m = 0; m < 4; ++m) {
    #pragma unroll
    for (int n = 0; n < 4; ++n) {
      const int gm = m0 + wr + m * 16 + crow;
      const int gn = n0 + wc + n * 16 + fr;
      float bval = 0.f;
      if constexpr (BIAS) bval = bias[gn];
      #pragma unroll
      for (int j = 0; j < 4; ++j) {
        float vv = acc[m][n][j] * alpha + bval;
        if constexpr (OUT_BF16)
          ((u16*)Cptr)[cbase + (size_t)(gm + j) * ldc + gn] = f2b(vv);
        else
          ((float*)Cptr)[cbase + (size_t)(gm + j) * ldc + gn] = vv;
      }
    }
  }
}

extern "C" void kernel_launch(void* const* d_in, const int* in_sizes, int n_in,
                              void* d_out, int out_size, void* d_ws, size_t ws_size,
                              hipStream_t stream) {
  const float* q      = (const float*)d_in[0];
  const float* k      = (const float*)d_in[1];
  const float* v      = (const float*)d_in[2];
  const int*   mel    = (const int*)d_in[3];
  const float* w_qs   = (const float*)d_in[4];
  const float* b_qs   = (const float*)d_in[5];
  const float* w_ks   = (const float*)d_in[6];
  const float* b_ks   = (const float*)d_in[7];
  const float* w_vs   = (const float*)d_in[8];
  const float* b_vs   = (const float*)d_in[9];
  const float* w_last = (const float*)d_in[10];
  const float* b_last = (const float*)d_in[11];

  char* ws = (char*)d_ws;
  float* out = (float*)d_out;

  u16* W2Q = (u16*)(ws + B_W2Q);
  u16* W2K = (u16*)(ws + B_W2K);
  u16* W2V = (u16*)(ws + B_W2V);
  u16* WLB = (u16*)(ws + B_WLB);
  u16* QH  = (u16*)(ws + B_QH);
  u16* KH  = (u16*)(ws + B_KH);
  u16* VH  = (u16*)(ws + B_VH);
  u16* E   = (u16*)(ws + B_E);
  u16* AMT = (u16*)(ws + B_AMT);
  float* MS = (float*)(ws + B_MS);
  float* CPART = (float*)(ws + B_CPART);
  float* FRR = (float*)(ws + B_FRR);
  int* HIDX = (int*)(ws + B_HIDX);
  float* PT = (float*)(ws + B_PT);
  u16* VHT = (u16*)(ws + B_VHT);
  u16* CVP = (u16*)(ws + B_CVP);

  // 1. weight repacks (swizzled)
  repack_all<<<dim3(2496, 1, 4), 256, 0, stream>>>(w_qs, w_ks, w_vs, w_last,
                                                   W2Q, W2K, W2V, WLB);

  // 2. grouped convs: f32 inputs converted during single staging; 2-pass ic-split
  conv_mfma<<<dim3(128, 1, 9), 256, 0, stream>>>(q, k, v, W2Q, W2K, W2V,
                                                 b_qs, b_ks, b_vs, QH, KH, VH);

  // 3. e (bf16) + fused row-max
  qk_flash<<<dim3(4, 1, 48), 256, 0, stream>>>(QH, KH, E, MS);

  // 4. softmax denominators + colmax partials
  colsum_colmax<<<dim3(48, 8), 1024, 0, stream>>>(E, MS, CPART);

  // 5. fr + head select
  head_fr<<<NH * NB, 256, 0, stream>>>(CPART, FRR);
  select_head<<<1, 64, 0, stream>>>(FRR, mel, HIDX, out + OUT_FR);

  // 6. gather alpha_fc -> d_out, sigmoid -> pT [b][k][q]
  gather_fused<<<dim3(KL / 32, QL / 32, NB), dim3(32, 8), 0, stream>>>(
      E, MS, HIDX, out + OUT_ALPHA, PT);

  // 7. register scan -> AMT bf16 [b][q][k] directly (in-register transpose)
  smma_scan_wave<<<NB, 64, 0, stream>>>(PT, AMT);

  // 8. vh -> vhT [b][d][k]
  transpose_bf16<<<dim3(16, 6, NB), 256, 0, stream>>>(VH, VHT, KL, DM, 393216);

  // 9. cv_pre[b][q][d] = sum_k amT[q][k] * vhT[d][k]
  gemm_nt<true, false><<<dim3(4, 3, NB), 256, 0, stream>>>(
      AMT, VHT, CVP, nullptr, KL, KL, DM, KL, 1.f, 1,
      524288L, 0, 393216L, 0, 196608L, 0);

  // 10. out = cv_pre @ w_last^T + b_last
  gemm_nt<false, true><<<dim3(64, 3, 1), 256, 0, stream>>>(
      CVP, WLB, out + OUT_CV, b_last, DM, DM, DM, DM, 1.f, 1,
      0, 0, 0, 0, 0, 0);
}